// Round 15
// baseline (1173.358 us; speedup 1.0000x reference)
//
#include <hip/hip_runtime.h>
#include <math.h>

#define E 512
#define H 1024
#define B 64
#define S 32
#define SRC 256
#define L4 4      // NLEV-1 levels actually processed
#define T 31      // S-1 timesteps
#define R 256     // L4*B rows (effective batch)

typedef unsigned int uint_t;
typedef unsigned short ushort_t;
typedef float f32x4_v __attribute__((ext_vector_type(4)));
typedef short bf16x8_v __attribute__((ext_vector_type(8)));
typedef _Float16 f16x8_v __attribute__((ext_vector_type(8)));

// ---------------------------------------------------------------------------
__device__ __forceinline__ void split1(float x, uint_t& h, uint_t& l) {
    uint_t u = __float_as_uint(x);
    h = u >> 16;
    float hf = __uint_as_float(u & 0xFFFF0000u);
    l = __float_as_uint(x - hf) >> 16;
}

__device__ __forceinline__ void split_quad(float4 v, uint2& hi, uint2& lo) {
    uint_t h0, h1, h2, h3, l0, l1, l2, l3;
    split1(v.x, h0, l0); split1(v.y, h1, l1);
    split1(v.z, h2, l2); split1(v.w, h3, l3);
    hi.x = h0 | (h1 << 16); hi.y = h2 | (h3 << 16);
    lo.x = l0 | (l1 << 16); lo.y = l2 | (l3 << 16);
}

__device__ __forceinline__ ushort_t f16of(float x) {
    _Float16 h = (_Float16)x;
    return *(ushort_t*)&h;
}

__device__ __forceinline__ float2 f16x2f(uint_t u) {
    ushort_t a = (ushort_t)(u & 0xffff), b = (ushort_t)(u >> 16);
    _Float16 fa = *(_Float16*)&a, fb = *(_Float16*)&b;
    return make_float2((float)fa, (float)fb);
}

__device__ __forceinline__ void splitf16(float x, ushort_t& h, ushort_t& l) {
    _Float16 hh = (_Float16)x;
    float hf = (float)hh;
    _Float16 hl = (_Float16)(x - hf);
    h = *(ushort_t*)&hh;
    l = *(ushort_t*)&hl;
}

__device__ __forceinline__ void gl_lds16(const void* g, void* l) {
    __builtin_amdgcn_global_load_lds(
        (const __attribute__((address_space(1))) void*)g,
        (__attribute__((address_space(3))) void*)l, 16, 0, 0);
}

// ---------------------------------------------------------------------------
// Embeddings -> single fp16 plane: xs[t*R + l*B+b][e]
__global__ __launch_bounds__(128) void k_embed(const int* __restrict__ inputs,
                                               const float* __restrict__ embW,
                                               ushort_t* __restrict__ x16) {
    int blk = blockIdx.x;              // l*T*B + t*B + b
    int b = blk % B;
    int t = (blk / B) % T;
    int l = blk / (B * T);
    int tok = inputs[(l + 1) * B * S + b * S + t];
    const float4* src = (const float4*)(embW + (long long)tok * E);
    float4 v = src[threadIdx.x];
    uint_t w0 = f16of(v.x) | ((uint_t)f16of(v.y) << 16);
    uint_t w1 = f16of(v.z) | ((uint_t)f16of(v.w) << 16);
    size_t base = ((size_t)t * R + (size_t)l * B + b) * E + threadIdx.x * 4;
    uint2 pk = {w0, w1};
    *(uint2*)(x16 + base) = pk;
}

// ---------------------------------------------------------------------------
__global__ __launch_bounds__(128) void k_pe(const int* __restrict__ inputs,
                                            const int* __restrict__ lens,
                                            const float* __restrict__ embW,
                                            ushort_t* __restrict__ phi,
                                            ushort_t* __restrict__ plo) {
    int r = blockIdx.x;
    int l = r >> 6, b = r & 63;
    int plen = lens[l * B + b];
    int send = plen - 1;
    if (send > S) send = S;
    const int* toks = inputs + l * B * S + b * S;
    float4 acc = {0.f, 0.f, 0.f, 0.f};
    for (int s = 1; s < send; ++s) {
        int tok = toks[s];
        float4 v = ((const float4*)(embW + (long long)tok * E))[threadIdx.x];
        acc.x += v.x; acc.y += v.y; acc.z += v.z; acc.w += v.w;
    }
    const float inv = 1.f / 32.f;
    acc.x *= inv; acc.y *= inv; acc.z *= inv; acc.w *= inv;
    uint2 hi, lo; split_quad(acc, hi, lo);
    size_t base = (size_t)r * E + threadIdx.x * 4;
    *(uint2*)(phi + base) = hi;
    *(uint2*)(plo + base) = lo;
}

// ---------------------------------------------------------------------------
__global__ __launch_bounds__(256) void k_cm(const float* __restrict__ ctx,
                                            ushort_t* __restrict__ chi,
                                            ushort_t* __restrict__ clo) {
    int b = blockIdx.x;
    int j = threadIdx.x;
    const float4* c4 = (const float4*)(ctx + (size_t)b * SRC * H);
    float4 acc = {0.f, 0.f, 0.f, 0.f};
    for (int s = 0; s < SRC; ++s) {
        float4 v = c4[(size_t)s * (H / 4) + j];
        acc.x += v.x; acc.y += v.y; acc.z += v.z; acc.w += v.w;
    }
    const float inv = 1.f / (float)SRC;
    acc.x *= inv; acc.y *= inv; acc.z *= inv; acc.w *= inv;
    uint2 hi, lo; split_quad(acc, hi, lo);
    size_t base = (size_t)b * H + j * 4;
    *(uint2*)(chi + base) = hi;
    *(uint2*)(clo + base) = lo;
}

// ---------------------------------------------------------------------------
// Row-major plane splitter (contexts): bf16 hi/lo + optional fp16 plane.
__global__ __launch_bounds__(256) void k_wsplit(
    const float* __restrict__ src1, int ld1, int o1, int Ka,
    const float* __restrict__ src2, int ld2, int o2, int Kb,
    int rowmap, ushort_t* __restrict__ dhi, ushort_t* __restrict__ dlo,
    ushort_t* __restrict__ d16) {
    int n = blockIdx.x;
    int KT = Ka + Kb;
    long long r = rowmap ? ((long long)(n & 3) * H + (n >> 2)) : (long long)n;
    for (int k4 = threadIdx.x; k4 < (KT >> 2); k4 += 256) {
        int k = k4 << 2;
        float4 v = (k < Ka) ? *(const float4*)(src1 + r * ld1 + o1 + k)
                            : *(const float4*)(src2 + r * ld2 + o2 + (k - Ka));
        uint2 hi, lo; split_quad(v, hi, lo);
        size_t base = (size_t)n * KT + k;
        *(uint2*)(dhi + base) = hi;
        *(uint2*)(dlo + base) = lo;
        if (d16) {
            uint2 pk;
            pk.x = f16of(v.x) | ((uint_t)f16of(v.y) << 16);
            pk.y = f16of(v.z) | ((uint_t)f16of(v.w) << 16);
            *(uint2*)(d16 + base) = pk;
        }
    }
}

// ---------------------------------------------------------------------------
// bf16 tiled split panel (init weights) — 16KB/tile.
__global__ __launch_bounds__(256) void k_wtile(
    const float* __restrict__ src1, int ld1, int o1, int Ka,
    const float* __restrict__ src2, int ld2, int o2, int Kb,
    int rowmap, unsigned char* __restrict__ panel) {
    int cb = blockIdx.x, t = blockIdx.y;
    int KT = Ka + Kb;
    int NT = KT >> 6;
    size_t obase = ((size_t)cb * NT + t) * 16384;
    int k0 = t << 6;
    for (int q = threadIdx.x; q < 512; q += 256) {
        int s = q >> 6, l = q & 63;
        int n = cb * 64 + 8 * s + (l >> 3);
        long long r = rowmap ? ((long long)(n & 3) * H + (n >> 2)) : (long long)n;
        int xorc = ((l & 7) * 16) ^ ((l >> 3) << 4);
        int ke = k0 + (xorc >> 1);
        const float* sp = (ke < Ka) ? (src1 + r * ld1 + o1 + ke)
                                    : (src2 + r * ld2 + o2 + (ke - Ka));
        float4 v01 = *(const float4*)sp;
        float4 v23 = *(const float4*)(sp + 4);
        uint2 h0, l0, h1, l1;
        split_quad(v01, h0, l0);
        split_quad(v23, h1, l1);
        uint4 hi = {h0.x, h0.y, h1.x, h1.y};
        uint4 lo = {l0.x, l0.y, l1.x, l1.y};
        *(uint4*)(panel + obase + s * 1024 + l * 16) = hi;
        *(uint4*)(panel + obase + 8192 + s * 1024 + l * 16) = lo;
    }
}

// ---------------------------------------------------------------------------
// fp16 hi/lo tiled panel — 16KB/tile.
__global__ __launch_bounds__(256) void k_wtile16(
    const float* __restrict__ src1, int ld1, int Ka,
    const float* __restrict__ src2, int ld2, int Kb,
    int rowmap, unsigned char* __restrict__ panel) {
    int cb = blockIdx.x, t = blockIdx.y;
    int KT = Ka + Kb;
    int NT = KT >> 6;
    size_t obase = ((size_t)cb * NT + t) * 16384;
    int k0 = t << 6;
    for (int q = threadIdx.x; q < 512; q += 256) {
        int s = q >> 6, l = q & 63;
        int n = cb * 64 + 8 * s + (l >> 3);
        long long r = rowmap ? ((long long)(n & 3) * H + (n >> 2)) : (long long)n;
        int xorc = ((l & 7) * 16) ^ ((l >> 3) << 4);
        int ke = k0 + (xorc >> 1);
        const float* sp = (ke < Ka) ? (src1 + r * ld1 + ke)
                                    : (src2 + r * ld2 + (ke - Ka));
        ushort_t hh[8], ll[8];
#pragma unroll
        for (int e = 0; e < 8; ++e) splitf16(sp[e], hh[e], ll[e]);
        uint4 hi = {(uint_t)hh[0] | ((uint_t)hh[1] << 16),
                    (uint_t)hh[2] | ((uint_t)hh[3] << 16),
                    (uint_t)hh[4] | ((uint_t)hh[5] << 16),
                    (uint_t)hh[6] | ((uint_t)hh[7] << 16)};
        uint4 lo = {(uint_t)ll[0] | ((uint_t)ll[1] << 16),
                    (uint_t)ll[2] | ((uint_t)ll[3] << 16),
                    (uint_t)ll[4] | ((uint_t)ll[5] << 16),
                    (uint_t)ll[6] | ((uint_t)ll[7] << 16)};
        *(uint4*)(panel + obase + s * 1024 + l * 16) = hi;
        *(uint4*)(panel + obase + 8192 + s * 1024 + l * 16) = lo;
    }
}

// ---------------------------------------------------------------------------
// fp16 SINGLE tiled panel (gate weights) — 8KB/tile, gate interleave.
__global__ __launch_bounds__(256) void k_wtile16s(
    const float* __restrict__ src1, int ld1, int Ka,
    const float* __restrict__ src2, int ld2, int Kb,
    unsigned char* __restrict__ panel) {
    int cb = blockIdx.x, t = blockIdx.y;
    int KT = Ka + Kb;
    int NT = KT >> 6;
    size_t obase = ((size_t)cb * NT + t) * 8192;
    int k0 = t << 6;
    for (int q = threadIdx.x; q < 512; q += 256) {
        int s = q >> 6, l = q & 63;
        int n = cb * 64 + 8 * s + (l >> 3);
        long long r = (long long)(n & 3) * H + (n >> 2);   // gate interleave
        int xorc = ((l & 7) * 16) ^ ((l >> 3) << 4);
        int ke = k0 + (xorc >> 1);
        const float* sp = (ke < Ka) ? (src1 + r * ld1 + ke)
                                    : (src2 + r * ld2 + (ke - Ka));
        ushort_t hh[8];
#pragma unroll
        for (int e = 0; e < 8; ++e) hh[e] = f16of(sp[e]);
        uint4 hi = {(uint_t)hh[0] | ((uint_t)hh[1] << 16),
                    (uint_t)hh[2] | ((uint_t)hh[3] << 16),
                    (uint_t)hh[4] | ((uint_t)hh[5] << 16),
                    (uint_t)hh[6] | ((uint_t)hh[7] << 16)};
        *(uint4*)(panel + obase + s * 1024 + l * 16) = hi;
    }
}

// ---------------------------------------------------------------------------
// bf16 split MFMA GEMM (init projections) — unchanged.
__global__ __launch_bounds__(256) void k_g2(
    const ushort_t* __restrict__ Ah1, const ushort_t* __restrict__ Al1, int K1,
    const ushort_t* __restrict__ Ah2, const ushort_t* __restrict__ Al2, int K2,
    int a2mod,
    const unsigned char* __restrict__ Bp,
    const float* __restrict__ bias1, const float* __restrict__ bias2,
    int mode, float* __restrict__ C,
    long long strideT, long long strideL, long long strideB, int act,
    ushort_t* __restrict__ ohi, ushort_t* __restrict__ olo) {
    __shared__ __align__(16) unsigned char lds[65536];
    const int tid = threadIdx.x;
    const int lane = tid & 63;
    const int wv = tid >> 6;
    const int wm = wv & 1, wn = wv >> 1;
    const int cblk = blockIdx.x;
    const int mblk = blockIdx.y;
    const int m0 = mblk * 64;
    const int colbase = cblk * 64;
    const int KT = K1 + K2;
    const int NT = KT >> 6;
    const int n1steps = K1 >> 6;
    const size_t pbase = (size_t)cblk * NT * 16384;

    f32x4_v zero = {0.f, 0.f, 0.f, 0.f};
    f32x4_v acc[2][2] = {{zero, zero}, {zero, zero}};
    const int xorc = ((lane & 7) * 16) ^ ((lane >> 3) << 4);
    const int rsub = lane >> 3;

    auto stage = [&](int t, int buf) {
        unsigned char* dstA = lds + buf * 16384;
        unsigned char* dstB = lds + 32768 + buf * 16384;
        {
            const ushort_t *Ph, *Pl; int lda, k0, mod;
            if (t < n1steps) { Ph = Ah1; Pl = Al1; lda = K1; k0 = t << 6; mod = 0; }
            else { Ph = Ah2; Pl = Al2; lda = K2; k0 = (t - n1steps) << 6; mod = a2mod; }
#pragma unroll
            for (int cc = 0; cc < 4; ++cc) {
                int c = wv * 4 + cc;
                int p = c >> 3, s = c & 7;
                int rr = m0 + 8 * s + rsub;
                if (mod) rr &= (mod - 1);
                const ushort_t* plane = p ? Pl : Ph;
                gl_lds16((const unsigned char*)(plane + (size_t)rr * lda + k0) + xorc,
                         dstA + c * 1024);
            }
        }
        {
            const unsigned char* tb = Bp + pbase + (size_t)t * 16384;
#pragma unroll
            for (int cc = 0; cc < 4; ++cc) {
                int c = wv * 4 + cc;
                gl_lds16(tb + c * 1024 + lane * 16, dstB + c * 1024);
            }
        }
    };
    auto compute = [&](int buf) {
        const unsigned char* Ab = lds + buf * 16384;
        const unsigned char* Bb = lds + 32768 + buf * 16384;
#pragma unroll
        for (int kf = 0; kf < 2; ++kf) {
            int colA = (kf * 64 + ((lane >> 4) * 16)) ^ ((lane & 7) << 4);
            bf16x8_v ah[2], al[2], bh[2], bl[2];
#pragma unroll
            for (int i = 0; i < 2; ++i) {
                int rowm = (wm * 2 + i) * 16 + (lane & 15);
                ah[i] = *(const bf16x8_v*)(Ab + rowm * 128 + colA);
                al[i] = *(const bf16x8_v*)(Ab + 8192 + rowm * 128 + colA);
                int rj = (wn * 2 + i) * 16 + (lane & 15);
                bh[i] = *(const bf16x8_v*)(Bb + rj * 128 + colA);
                bl[i] = *(const bf16x8_v*)(Bb + 8192 + rj * 128 + colA);
            }
            __builtin_amdgcn_s_setprio(1);
#pragma unroll
            for (int i = 0; i < 2; ++i)
#pragma unroll
                for (int j = 0; j < 2; ++j) {
                    acc[i][j] = __builtin_amdgcn_mfma_f32_16x16x32_bf16(al[i], bh[j], acc[i][j], 0, 0, 0);
                    acc[i][j] = __builtin_amdgcn_mfma_f32_16x16x32_bf16(ah[i], bl[j], acc[i][j], 0, 0, 0);
                    acc[i][j] = __builtin_amdgcn_mfma_f32_16x16x32_bf16(ah[i], bh[j], acc[i][j], 0, 0, 0);
                }
            __builtin_amdgcn_s_setprio(0);
        }
    };

    stage(0, 0);
    int cur = 0;
    for (int tt = 0; tt < NT; ++tt) {
        if (tt + 1 < NT) {
            stage(tt + 1, cur ^ 1);
            asm volatile("s_waitcnt vmcnt(8)" ::: "memory");
        } else {
            asm volatile("s_waitcnt vmcnt(0)" ::: "memory");
        }
        __builtin_amdgcn_s_barrier();
        __builtin_amdgcn_sched_barrier(0);
        compute(cur);
        __builtin_amdgcn_sched_barrier(0);
        __builtin_amdgcn_s_barrier();
        cur ^= 1;
    }

    const int l16 = lane & 15, g4 = (lane >> 4) * 4;
#pragma unroll
    for (int i = 0; i < 2; ++i) {
#pragma unroll
        for (int r = 0; r < 4; ++r) {
            int m = m0 + wm * 32 + i * 16 + g4 + r;
            long long rowoff = (long long)(m >> 8) * strideT
                             + (long long)((m >> 6) & 3) * strideL
                             + (long long)(m & 63) * strideB;
#pragma unroll
            for (int jj = 0; jj < 2; ++jj) {
                int n = colbase + wn * 32 + jj * 16 + l16;
                float v = acc[i][jj][r];
                if (mode == 0) {
                    if (bias1) v += bias1[n];
                    if (bias2) v += bias2[n];
                    if (act) v = tanhf(v);
                    C[rowoff + n] = v;
                } else {
                    uint_t hu, lu; split1(v, hu, lu);
                    ohi[rowoff + n] = (ushort_t)hu;
                    olo[rowoff + n] = (ushort_t)lu;
                }
            }
        }
    }
}

// ---------------------------------------------------------------------------
// fp16 GEMM v2: 512 thr (8 waves = 4m x 2n), tile 128m x 64n.
// A = concat fp16 single planes, B = fp16 hi/lo panel (16KB/tile).
// mode 0: C = tanh(acc + bias1), scattered. mode 2: bias + bf16 split -> ohi/olo.
__global__ __launch_bounds__(512) void k_g2h(
    const ushort_t* __restrict__ A1, int K1,
    const ushort_t* __restrict__ A2, int K2,
    const unsigned char* __restrict__ Bp,
    const float* __restrict__ bias1,
    int mode, float* __restrict__ C,
    long long strideT, long long strideL, long long strideB,
    ushort_t* __restrict__ ohi, ushort_t* __restrict__ olo) {
    __shared__ __align__(16) unsigned char lds[65536];
    const int tid = threadIdx.x;
    const int lane = tid & 63;
    const int wv = tid >> 6;            // 0..7
    const int wm = wv & 3, wn = wv >> 2;
    const int cblk = blockIdx.x;
    const int m0 = blockIdx.y * 128;
    const int colbase = cblk * 64;
    const int KT = K1 + K2;
    const int NT = KT >> 6;
    const int n1steps = K1 >> 6;
    const size_t pbase = (size_t)cblk * NT * 16384;

    f32x4_v zero = {0.f, 0.f, 0.f, 0.f};
    f32x4_v acc[2][2] = {{zero, zero}, {zero, zero}};
    const int xorc = ((lane & 7) * 16) ^ ((lane >> 3) << 4);
    const int rsub = lane >> 3;

    auto stage = [&](int t, int buf) {
        unsigned char* base = lds + buf * 32768;
        const ushort_t* Ap; int lda, k0;
        if (t < n1steps) { Ap = A1; lda = K1; k0 = t << 6; }
        else             { Ap = A2; lda = K2; k0 = (t - n1steps) << 6; }
        const unsigned char* tb = Bp + pbase + (size_t)t * 16384;
#pragma unroll
        for (int cc = 0; cc < 4; ++cc) {
            int c = wv * 4 + cc;           // 0..31
            if (c < 16) {                  // A: 16 chunks, rows m0..m0+127
                int rr = m0 + 8 * c + rsub;
                gl_lds16((const unsigned char*)(Ap + (size_t)rr * lda + k0) + xorc,
                         base + c * 1024);
            } else {                       // B hi/lo: 16 chunks, sequential panel
                int cb = c - 16;
                gl_lds16(tb + cb * 1024 + lane * 16, base + 16384 + cb * 1024);
            }
        }
    };
    auto compute = [&](int buf) {
        const unsigned char* Ab = lds + buf * 32768;
        const unsigned char* Bb = Ab + 16384;
#pragma unroll
        for (int kf = 0; kf < 2; ++kf) {
            int colA = (kf * 64 + ((lane >> 4) * 16)) ^ ((lane & 7) << 4);
            f16x8_v a[2], bh[2], bl[2];
#pragma unroll
            for (int i = 0; i < 2; ++i) {
                int rowm = wm * 32 + i * 16 + (lane & 15);     // 0..127
                a[i] = *(const f16x8_v*)(Ab + rowm * 128 + colA);
                int rj = wn * 32 + i * 16 + (lane & 15);       // 0..63
                bh[i] = *(const f16x8_v*)(Bb + rj * 128 + colA);
                bl[i] = *(const f16x8_v*)(Bb + 8192 + rj * 128 + colA);
            }
            __builtin_amdgcn_s_setprio(1);
#pragma unroll
            for (int i = 0; i < 2; ++i)
#pragma unroll
                for (int j = 0; j < 2; ++j) {
                    acc[i][j] = __builtin_amdgcn_mfma_f32_16x16x32_f16(a[i], bl[j], acc[i][j], 0, 0, 0);
                    acc[i][j] = __builtin_amdgcn_mfma_f32_16x16x32_f16(a[i], bh[j], acc[i][j], 0, 0, 0);
                }
            __builtin_amdgcn_s_setprio(0);
        }
    };

    stage(0, 0);
    int cur = 0;
    for (int tt = 0; tt < NT; ++tt) {
        if (tt + 1 < NT) {
            stage(tt + 1, cur ^ 1);
            asm volatile("s_waitcnt vmcnt(4)" ::: "memory");
        } else {
            asm volatile("s_waitcnt vmcnt(0)" ::: "memory");
        }
        __builtin_amdgcn_s_barrier();
        __builtin_amdgcn_sched_barrier(0);
        compute(cur);
        __builtin_amdgcn_sched_barrier(0);
        __builtin_amdgcn_s_barrier();
        cur ^= 1;
    }

    const int l16 = lane & 15, g4 = (lane >> 4) * 4;
#pragma unroll
    for (int i = 0; i < 2; ++i) {
#pragma unroll
        for (int r = 0; r < 4; ++r) {
            int m = m0 + wm * 32 + i * 16 + g4 + r;
            long long rowoff = (long long)(m >> 8) * strideT
                             + (long long)((m >> 6) & 3) * strideL
                             + (long long)(m & 63) * strideB;
#pragma unroll
            for (int jj = 0; jj < 2; ++jj) {
                int n = colbase + wn * 32 + jj * 16 + l16;
                float v = acc[i][jj][r] + bias1[n];
                if (mode == 0) {
                    C[rowoff + n] = tanhf(v);
                } else {
                    uint_t hu, lu; split1(v, hu, lu);
                    ohi[rowoff + n] = (ushort_t)hu;
                    olo[rowoff + n] = (ushort_t)lu;
                }
            }
        }
    }
}

// ---------------------------------------------------------------------------
// Dual-job gate GEMM + fused LSTM, fp16 single x single, 4-deep prefetch.
struct GateJob {
    const ushort_t *A1, *A2;          // fp16 planes
    const unsigned char* Bp;          // fp16 single panel
    const float *bias1, *bias2;
    float *cbuf, *hf;
    ushort_t *h16;                    // fp16 h out
    int K1, K2;
};

__global__ __launch_bounds__(256) void k_gatepair(GateJob j0, GateJob j1) {
    __shared__ __align__(16) unsigned char lds[65536];
    const bool sec = blockIdx.y >= 4;
    const ushort_t* A1v = sec ? j1.A1 : j0.A1;
    const ushort_t* A2v = sec ? j1.A2 : j0.A2;
    const unsigned char* Bp = sec ? j1.Bp : j0.Bp;
    const float* bias1  = sec ? j1.bias1 : j0.bias1;
    const float* bias2  = sec ? j1.bias2 : j0.bias2;
    float* cbuf         = sec ? j1.cbuf : j0.cbuf;
    float* hf           = sec ? j1.hf   : j0.hf;
    ushort_t* h16       = sec ? j1.h16  : j0.h16;
    const int K1        = sec ? j1.K1   : j0.K1;
    const int K2        = sec ? j1.K2   : j0.K2;

    const int tid = threadIdx.x;
    const int lane = tid & 63;
    const int wv = tid >> 6;
    const int wm = wv & 1, wn = wv >> 1;
    const int mblk = blockIdx.y & 3;
    const int cblk = blockIdx.x;
    const int m0 = mblk * 64;
    const int KT = K1 + K2;
    const int NT = KT >> 6;
    const int n1steps = K1 >> 6;
    const size_t pbase = (size_t)cblk * NT * 8192;

    f32x4_v zero = {0.f, 0.f, 0.f, 0.f};
    f32x4_v acc[2][2] = {{zero, zero}, {zero, zero}};
    const int xorc = ((lane & 7) * 16) ^ ((lane >> 3) << 4);
    const int rsub = lane >> 3;

    auto stage = [&](int t, int buf) {
        unsigned char* base = lds + buf * 16384;
        const ushort_t* Ap; int lda, k0;
        if (t < n1steps) { Ap = A1v; lda = K1; k0 = t << 6; }
        else             { Ap = A2v; lda = K2; k0 = (t - n1steps) << 6; }
        const unsigned char* tb = Bp + pbase + (size_t)t * 8192;
#pragma unroll
        for (int cc = 0; cc < 4; ++cc) {
            int c = wv * 4 + cc;           // 0..15
            if (c < 8) {
                int rr = m0 + 8 * c + rsub;
                gl_lds16((const unsigned char*)(Ap + (size_t)rr * lda + k0) + xorc,
                         base + c * 1024);
            } else {
                gl_lds16(tb + (c - 8) * 1024 + lane * 16, base + c * 1024);
            }
        }
    };
    auto compute = [&](int buf) {
        const unsigned char* Ab = lds + buf * 16384;
        const unsigned char* Bb = Ab + 8192;
#pragma unroll
        for (int kf = 0; kf < 2; ++kf) {
            int colA = (kf * 64 + ((lane >> 4) * 16)) ^ ((lane & 7) << 4);
            f16x8_v a[2], bv[2];
#pragma unroll
            for (int i = 0; i < 2; ++i) {
                int rowm = (wm * 2 + i) * 16 + (lane & 15);
                a[i] = *(const f16x8_v*)(Ab + rowm * 128 + colA);
                int rj = (wn * 2 + i) * 16 + (lane & 15);
                bv[i] = *(const f16x8_v*)(Bb + rj * 128 + colA);
            }
            __builtin_amdgcn_s_setprio(1);
#pragma unroll
            for (int i = 0; i < 2; ++i)
#pragma unroll
                for (int j = 0; j < 2; ++j)
                    acc[i][j] = __builtin_amdgcn_mfma_f32_16x16x32_f16(a[i], bv[j], acc[i][j], 0, 0, 0);
            __builtin_amdgcn_s_setprio(0);
        }
    };

    stage(0, 0);
    stage(1, 1);
    stage(2, 2);
    for (int tt = 0; tt < NT; ++tt) {
        if (tt + 3 < NT) {
            stage(tt + 3, (tt + 3) & 3);
            asm volatile("s_waitcnt vmcnt(12)" ::: "memory");
        } else if (tt + 2 < NT) {
            asm volatile("s_waitcnt vmcnt(8)" ::: "memory");
        } else if (tt + 1 < NT) {
            asm volatile("s_waitcnt vmcnt(4)" ::: "memory");
        } else {
            asm volatile("s_waitcnt vmcnt(0)" ::: "memory");
        }
        __builtin_amdgcn_s_barrier();
        __builtin_amdgcn_sched_barrier(0);
        compute(tt & 3);
        __builtin_amdgcn_sched_barrier(0);
        __builtin_amdgcn_s_barrier();
    }

    // gate tile -> LDS [64][68] f32 (overlays staging; drained)
    float* gtile = (float*)lds;
    const int l16 = lane & 15, g4 = (lane >> 4) * 4;
#pragma unroll
    for (int i = 0; i < 2; ++i)
#pragma unroll
        for (int jj = 0; jj < 2; ++jj)
#pragma unroll
            for (int r = 0; r < 4; ++r)
                gtile[(wm * 32 + i * 16 + g4 + r) * 68 + wn * 32 + jj * 16 + l16] = acc[i][jj][r];
    __syncthreads();

    int m = tid >> 2;
    int hcb = (tid & 3) * 4;
    int nh0 = cblk * 16;
#pragma unroll
    for (int e = 0; e < 4; ++e) {
        int hc = hcb + e;
        float gv[4];
#pragma unroll
        for (int q = 0; q < 4; ++q) {
            int bidx = q * H + nh0 + hc;
            gv[q] = gtile[m * 68 + hc * 4 + q] + bias1[bidx] + bias2[bidx];
        }
        size_t idx = (size_t)(m0 + m) * H + nh0 + hc;
        float cp = cbuf[idx];
        float si = 1.f / (1.f + __expf(-gv[0]));
        float sf = 1.f / (1.f + __expf(-gv[1]));
        float so = 1.f / (1.f + __expf(-gv[3]));
        float c = sf * cp + si * tanhf(gv[2]);
        float hn = so * tanhf(c);
        cbuf[idx] = c;
        hf[idx] = hn;
        h16[idx] = f16of(hn);
    }
}

// ---------------------------------------------------------------------------
// Batched score MFMA (bf16 3-term): scores[t*R+l*64+b][s] = gamma . ctx.
__global__ __launch_bounds__(256) void k_smfma(
    const ushort_t* __restrict__ gah, const ushort_t* __restrict__ gal,
    const ushort_t* __restrict__ cxh, const ushort_t* __restrict__ cxl,
    float* __restrict__ scores) {
    __shared__ __align__(16) unsigned char lds[65536];
    const int tid = threadIdx.x;
    const int lane = tid & 63;
    const int wv = tid >> 6;
    const int wm = wv & 1, wn = wv >> 1;
    const int b = blockIdx.z;
    const int m0 = blockIdx.y * 64;
    const int colbase = blockIdx.x * 64;
    const int NT = 16;

    f32x4_v zero = {0.f, 0.f, 0.f, 0.f};
    f32x4_v acc[2][2] = {{zero, zero}, {zero, zero}};
    const int xorc = ((lane & 7) * 16) ^ ((lane >> 3) << 4);
    const int rsub = lane >> 3;

    auto stage = [&](int t, int buf) {
        unsigned char* dstA = lds + buf * 16384;
        unsigned char* dstB = lds + 32768 + buf * 16384;
        int k0 = t << 6;
#pragma unroll
        for (int cc = 0; cc < 4; ++cc) {
            int c = wv * 4 + cc;
            int p = c >> 3, s = c & 7;
            int rr = m0 + 8 * s + rsub;
            int tt = rr >> 2; if (tt > 30) tt = 30;
            size_t row = (size_t)tt * R + (rr & 3) * 64 + b;
            const ushort_t* plane = p ? gal : gah;
            gl_lds16((const unsigned char*)(plane + row * H + k0) + xorc,
                     dstA + c * 1024);
        }
#pragma unroll
        for (int cc = 0; cc < 4; ++cc) {
            int c = wv * 4 + cc;
            int p = c >> 3, s = c & 7;
            int rr = colbase + 8 * s + rsub;
            const ushort_t* plane = p ? cxl : cxh;
            gl_lds16((const unsigned char*)(plane + ((size_t)b * SRC + rr) * H + k0) + xorc,
                     dstB + c * 1024);
        }
    };
    auto compute = [&](int buf) {
        const unsigned char* Ab = lds + buf * 16384;
        const unsigned char* Bb = lds + 32768 + buf * 16384;
#pragma unroll
        for (int kf = 0; kf < 2; ++kf) {
            int colA = (kf * 64 + ((lane >> 4) * 16)) ^ ((lane & 7) << 4);
            bf16x8_v ah[2], al[2], bh[2], bl[2];
#pragma unroll
            for (int i = 0; i < 2; ++i) {
                int rowm = (wm * 2 + i) * 16 + (lane & 15);
                ah[i] = *(const bf16x8_v*)(Ab + rowm * 128 + colA);
                al[i] = *(const bf16x8_v*)(Ab + 8192 + rowm * 128 + colA);
                int rj = (wn * 2 + i) * 16 + (lane & 15);
                bh[i] = *(const bf16x8_v*)(Bb + rj * 128 + colA);
                bl[i] = *(const bf16x8_v*)(Bb + 8192 + rj * 128 + colA);
            }
            __builtin_amdgcn_s_setprio(1);
#pragma unroll
            for (int i = 0; i < 2; ++i)
#pragma unroll
                for (int j = 0; j < 2; ++j) {
                    acc[i][j] = __builtin_amdgcn_mfma_f32_16x16x32_bf16(al[i], bh[j], acc[i][j], 0, 0, 0);
                    acc[i][j] = __builtin_amdgcn_mfma_f32_16x16x32_bf16(ah[i], bl[j], acc[i][j], 0, 0, 0);
                    acc[i][j] = __builtin_amdgcn_mfma_f32_16x16x32_bf16(ah[i], bh[j], acc[i][j], 0, 0, 0);
                }
            __builtin_amdgcn_s_setprio(0);
        }
    };

    stage(0, 0);
    int cur = 0;
    for (int tt = 0; tt < NT; ++tt) {
        if (tt + 1 < NT) {
            stage(tt + 1, cur ^ 1);
            asm volatile("s_waitcnt vmcnt(8)" ::: "memory");
        } else {
            asm volatile("s_waitcnt vmcnt(0)" ::: "memory");
        }
        __builtin_amdgcn_s_barrier();
        __builtin_amdgcn_sched_barrier(0);
        compute(cur);
        __builtin_amdgcn_sched_barrier(0);
        __builtin_amdgcn_s_barrier();
        cur ^= 1;
    }

    const int l16 = lane & 15, g4 = (lane >> 4) * 4;
#pragma unroll
    for (int i = 0; i < 2; ++i) {
#pragma unroll
        for (int jj = 0; jj < 2; ++jj) {
#pragma unroll
            for (int r = 0; r < 4; ++r) {
                int m = m0 + wm * 32 + i * 16 + g4 + r;
                int t = m >> 2;
                if (t < 31) {
                    size_t row = (size_t)t * R + (m & 3) * 64 + b;
                    int n = colbase + wn * 32 + jj * 16 + l16;
                    scores[row * SRC + n] = acc[i][jj][r];
                }
            }
        }
    }
}

// ---------------------------------------------------------------------------
__global__ __launch_bounds__(256) void k_smax(const float* __restrict__ scores,
                                              float* __restrict__ w) {
    int t = blockIdx.x, b = blockIdx.y;
    int l = threadIdx.x >> 6, lane = threadIdx.x & 63;
    size_t row = (size_t)t * R + l * 64 + b;
    const float* sr = scores + row * SRC;
    float v0 = sr[lane];
    float v1 = sr[lane + 64];
    float v2 = sr[lane + 128];
    float v3 = sr[lane + 192];
    float m = fmaxf(fmaxf(v0, v1), fmaxf(v2, v3));
#pragma unroll
    for (int off = 32; off >= 1; off >>= 1) m = fmaxf(m, __shfl_xor(m, off));
    float e0 = expf(v0 - m), e1 = expf(v1 - m), e2 = expf(v2 - m), e3 = expf(v3 - m);
    float sum = e0 + e1 + e2 + e3;
#pragma unroll
    for (int off = 32; off >= 1; off >>= 1) sum += __shfl_xor(sum, off);
    float inv = 1.f / sum;
    float* wr = w + row * SRC;
    wr[lane] = e0 * inv;
    wr[lane + 64] = e1 * inv;
    wr[lane + 128] = e2 * inv;
    wr[lane + 192] = e3 * inv;
}

// ---------------------------------------------------------------------------
// Batched ct from fp16 ctx plane; writes fp16 single plane.
__global__ __launch_bounds__(512) void k_ct_all(const ushort_t* __restrict__ ctx16,
                                                const float* __restrict__ w,
                                                ushort_t* __restrict__ ct16) {
    __shared__ float ws[32][260];
    const int b = blockIdx.x, tc = blockIdx.y;
    const int tid = threadIdx.x;
    for (int q = tid; q < 32 * 64; q += 512) {
        int r = q >> 6, c4 = q & 63;
        int t = tc * 8 + (r >> 2);
        float4 v = {0.f, 0.f, 0.f, 0.f};
        if (t < 31)
            v = *(const float4*)(w + ((size_t)t * R + (r & 3) * 64 + b) * SRC + c4 * 4);
        *(float4*)&ws[r][c4 * 4] = v;
    }
    __syncthreads();

    float2 acc[32];
#pragma unroll
    for (int r = 0; r < 32; ++r) acc[r] = make_float2(0.f, 0.f);
    const uint_t* base = (const uint_t*)(ctx16 + (size_t)b * SRC * H) + tid;
    for (int s = 0; s < SRC; s += 4) {
        float2 c0 = f16x2f(base[(size_t)s * (H / 2)]);
        float2 c1 = f16x2f(base[(size_t)(s + 1) * (H / 2)]);
        float2 c2 = f16x2f(base[(size_t)(s + 2) * (H / 2)]);
        float2 c3 = f16x2f(base[(size_t)(s + 3) * (H / 2)]);
#pragma unroll
        for (int r = 0; r < 32; ++r) {
            float4 wv = *(const float4*)&ws[r][s];
            acc[r].x += wv.x * c0.x + wv.y * c1.x + wv.z * c2.x + wv.w * c3.x;
            acc[r].y += wv.x * c0.y + wv.y * c1.y + wv.z * c2.y + wv.w * c3.y;
        }
    }
#pragma unroll
    for (int r = 0; r < 32; ++r) {
        int t = tc * 8 + (r >> 2);
        if (t < 31) {
            size_t obase = ((size_t)t * R + (r & 3) * 64 + b) * H + tid * 2;
            uint_t pk = f16of(acc[r].x) | ((uint_t)f16of(acc[r].y) << 16);
            *(uint_t*)(ct16 + obase) = pk;
        }
    }
}

// ---------------------------------------------------------------------------
__global__ __launch_bounds__(256) void k_init_split(const float* __restrict__ h0f,
                                                    const float* __restrict__ c0f,
                                                    float* __restrict__ h1f,
                                                    float* __restrict__ c1f,
                                                    ushort_t* __restrict__ h0_16,
                                                    ushort_t* __restrict__ h1i_16) {
    int idx = blockIdx.x * 256 + threadIdx.x;
    float h = h0f[idx], c = c0f[idx];
    h1f[idx] = h; c1f[idx] = c;
    ushort_t hv = f16of(h);
    h0_16[idx] = hv;
    h1i_16[idx] = hv;
}

// ---------------------------------------------------------------------------
extern "C" void kernel_launch(void* const* d_in, const int* in_sizes, int n_in,
                              void* d_out, int out_size, void* d_ws, size_t ws_size,
                              hipStream_t stream) {
    const int*   inputs     = (const int*)d_in[0];
    const int*   input_lens = (const int*)d_in[1];
    const float* contexts   = (const float*)d_in[2];
    const float* emb_W      = (const float*)d_in[3];
    const float* W_ih0      = (const float*)d_in[4];
    const float* W_hh0      = (const float*)d_in[5];
    const float* b_ih0      = (const float*)d_in[6];
    const float* b_hh0      = (const float*)d_in[7];
    const float* W_ih1      = (const float*)d_in[8];
    const float* W_hh1      = (const float*)d_in[9];
    const float* b_ih1      = (const float*)d_in[10];
    const float* b_hh1      = (const float*)d_in[11];
    const float* att_in_W   = (const float*)d_in[12];
    const float* att_in_b   = (const float*)d_in[13];
    const float* att_out_W  = (const float*)d_in[14];
    const float* att_out_b  = (const float*)d_in[15];
    const float* isl_in_W   = (const float*)d_in[16];
    const float* isl_in_b   = (const float*)d_in[17];
    const float* isl_out_W  = (const float*)d_in[18];
    const float* isl_out_b  = (const float*)d_in[19];

    float* out = (float*)d_out;

    // workspace carve (256B-aligned)
    char* p = (char*)d_ws;
    auto alloc = [&](size_t bytes) { char* r = p; p += (bytes + 255) & ~(size_t)255; return r; };
    ushort_t* xs16 = (ushort_t*)alloc((size_t)T * R * E * 2);     // fp16 x
    ushort_t* h016[2];
    h016[0] = (ushort_t*)alloc((size_t)R * H * 2);
    h016[1] = (ushort_t*)alloc((size_t)R * H * 2);
    ushort_t* h1i16 = (ushort_t*)alloc((size_t)R * H * 2);
    ushort_t* h116all = (ushort_t*)alloc((size_t)T * R * H * 2);  // fp16 h1 per t
    ushort_t* gamh = (ushort_t*)alloc((size_t)T * R * H * 2);     // gamma bf16 pair
    ushort_t* gaml = (ushort_t*)alloc((size_t)T * R * H * 2);
    ushort_t* pehi = (ushort_t*)alloc((size_t)R * E * 2);
    ushort_t* pelo = (ushort_t*)alloc((size_t)R * E * 2);
    ushort_t* cmhi = (ushort_t*)alloc((size_t)B * H * 2);
    ushort_t* cmlo = (ushort_t*)alloc((size_t)B * H * 2);
    // gate weight panels: fp16 single tiled (8KB/tile)
    unsigned char* wg0p = (unsigned char*)alloc((size_t)64 * 24 * 8192);
    unsigned char* wg1p = (unsigned char*)alloc((size_t)64 * 32 * 8192);
    // fp16 hi/lo panels: att_in (gamma), att_out
    unsigned char* wgip = (unsigned char*)alloc((size_t)16 * 16 * 16384);
    unsigned char* wotp = (unsigned char*)alloc((size_t)16 * 32 * 16384);
    // bf16 panels for init
    unsigned char* wiip = (unsigned char*)alloc((size_t)16 * 24 * 16384);
    unsigned char* wiop = (unsigned char*)alloc((size_t)16 * 24 * 16384);
    // ctx planes: bf16 pair (score pass) + fp16 (ct pass)
    ushort_t* cxh = (ushort_t*)alloc((size_t)B * SRC * H * 2);
    ushort_t* cxl = (ushort_t*)alloc((size_t)B * SRC * H * 2);
    ushort_t* ctx16 = (ushort_t*)alloc((size_t)B * SRC * H * 2);
    float* h0f = (float*)alloc((size_t)R * H * 4);
    float* h1f = (float*)alloc((size_t)R * H * 4);
    float* c0f = (float*)alloc((size_t)R * H * 4);
    float* c1f = (float*)alloc((size_t)R * H * 4);
    // post buffers
    float* scores = (float*)alloc((size_t)T * R * SRC * 4);
    float* wbuf   = (float*)alloc((size_t)T * R * SRC * 4);
    ushort_t* ct16 = (ushort_t*)alloc((size_t)T * R * H * 2);

    // ---- setup ----
    k_embed<<<L4 * T * B, 128, 0, stream>>>(inputs, emb_W, xs16);
    k_pe<<<R, 128, 0, stream>>>(inputs, input_lens, emb_W, pehi, pelo);
    k_cm<<<B, 256, 0, stream>>>(contexts, cmhi, cmlo);
    k_wtile16s<<<dim3(64, 24), 256, 0, stream>>>(W_ih0, 512, 512, W_hh0, 1024, 1024, wg0p);
    k_wtile16s<<<dim3(64, 32), 256, 0, stream>>>(W_ih1, 1024, 1024, W_hh1, 1024, 1024, wg1p);
    k_wtile16<<<dim3(16, 16), 256, 0, stream>>>(att_in_W, 1024, 1024, nullptr, 0, 0, 0, wgip);
    k_wtile16<<<dim3(16, 32), 256, 0, stream>>>(att_out_W, 2048, 2048, nullptr, 0, 0, 0, wotp);
    k_wtile<<<dim3(16, 24), 256, 0, stream>>>(isl_in_W, 1536, 0, 1536, nullptr, 0, 0, 0, 0, wiip);
    k_wtile<<<dim3(16, 24), 256, 0, stream>>>(isl_out_W, 1536, 1024, 512, isl_out_W, 1536, 0, 1024, 0, wiop);
    k_wsplit<<<B * SRC, 256, 0, stream>>>(contexts, 1024, 0, 1024, nullptr, 0, 0, 0, 0, cxh, cxl, ctx16);

    // init projections (bf16 path, unchanged)
    k_g2<<<dim3(16, 4), 256, 0, stream>>>(pehi, pelo, 512, cmhi, cmlo, 1024, 64,
                                          wiip, isl_in_b, nullptr, 0,
                                          h0f, 0, 64LL * H, (long long)H, 1,
                                          nullptr, nullptr);
    k_g2<<<dim3(16, 4), 256, 0, stream>>>(pehi, pelo, 512, cmhi, cmlo, 1024, 64,
                                          wiop, isl_out_b, nullptr, 0,
                                          c0f, 0, 64LL * H, (long long)H, 1,
                                          nullptr, nullptr);
    k_init_split<<<R * H / 256, 256, 0, stream>>>(h0f, c0f, h1f, c1f, h016[0], h1i16);

    // ---- recurrence: dual-job fp16-single launches, 4-deep prefetch ----
    int cur = 0;
    for (int L = 0; L <= T; ++L) {
        bool has0 = (L < T), has1 = (L > 0);
        GateJob g0 = {}, g1 = {};
        if (has0) {
            g0.A1 = xs16 + (size_t)L * R * E;
            g0.A2 = h016[cur];
            g0.Bp = wg0p;
            g0.bias1 = b_ih0;  g0.bias2 = b_hh0;
            g0.cbuf = c0f;  g0.hf = h0f;
            g0.h16 = h016[cur ^ 1];
            g0.K1 = E;  g0.K2 = H;
        }
        if (has1) {
            g1.A1 = h016[cur];
            g1.A2 = (L == 1) ? h1i16 : h116all + (size_t)(L - 2) * R * H;
            g1.Bp = wg1p;
            g1.bias1 = b_ih1;  g1.bias2 = b_hh1;
            g1.cbuf = c1f;  g1.hf = h1f;
            g1.h16 = h116all + (size_t)(L - 1) * R * H;
            g1.K1 = H;  g1.K2 = H;
        }
        if (has0 && has1)
            k_gatepair<<<dim3(64, 8), 256, 0, stream>>>(g0, g1);
        else if (has0)
            k_gatepair<<<dim3(64, 4), 256, 0, stream>>>(g0, g0);
        else
            k_gatepair<<<dim3(64, 4), 256, 0, stream>>>(g1, g1);
        if (has0) cur ^= 1;
    }

    // ---- batched attention + output over all t ----
    // gamma_all = h1_all @ att_in_W^T + b  -> bf16 pair planes (mode 2)
    k_g2h<<<dim3(16, 62), 512, 0, stream>>>(h116all, 1024, h116all, 0,
                                            wgip, att_in_b, 2,
                                            nullptr, 256LL * H, 64LL * H, (long long)H,
                                            gamh, gaml);
    k_smfma<<<dim3(4, 2, B), 256, 0, stream>>>(gamh, gaml, cxh, cxl, scores);
    k_smax<<<dim3(T, B), 256, 0, stream>>>(scores, wbuf);
    k_ct_all<<<dim3(B, 4), 512, 0, stream>>>(ctx16, wbuf, ct16);
    // out[t,l,b,:] = tanh([ct|h1] @ att_out_W^T + b)  (fp16 path)
    k_g2h<<<dim3(16, 62), 512, 0, stream>>>(ct16, 1024, h116all, 1024,
                                            wotp, att_out_b, 0,
                                            out, (long long)B * H,
                                            (long long)T * B * H, (long long)H,
                                            nullptr, nullptr);

    // ---- finals ----
    size_t OUTS = (size_t)L4 * T * B * H;
    size_t seg = (size_t)B * H;
    hipMemcpyAsync(out + OUTS,           h0f + 192 * H, seg * 4, hipMemcpyDeviceToDevice, stream);
    hipMemcpyAsync(out + OUTS + seg,     h1f + 192 * H, seg * 4, hipMemcpyDeviceToDevice, stream);
    hipMemcpyAsync(out + OUTS + 2 * seg, c0f + 192 * H, seg * 4, hipMemcpyDeviceToDevice, stream);
    hipMemcpyAsync(out + OUTS + 3 * seg, c1f + 192 * H, seg * 4, hipMemcpyDeviceToDevice, stream);
}

// Round 16
// 1136.288 us; speedup vs baseline: 1.0326x; 1.0326x over previous
//
#include <hip/hip_runtime.h>
#include <math.h>

#define E 512
#define H 1024
#define B 64
#define S 32
#define SRC 256
#define L4 4      // NLEV-1 levels actually processed
#define T 31      // S-1 timesteps
#define R 256     // L4*B rows (effective batch)

typedef unsigned int uint_t;
typedef unsigned short ushort_t;
typedef float f32x4_v __attribute__((ext_vector_type(4)));
typedef short bf16x8_v __attribute__((ext_vector_type(8)));
typedef _Float16 f16x8_v __attribute__((ext_vector_type(8)));

// ---------------------------------------------------------------------------
__device__ __forceinline__ void split1(float x, uint_t& h, uint_t& l) {
    uint_t u = __float_as_uint(x);
    h = u >> 16;
    float hf = __uint_as_float(u & 0xFFFF0000u);
    l = __float_as_uint(x - hf) >> 16;
}

__device__ __forceinline__ void split_quad(float4 v, uint2& hi, uint2& lo) {
    uint_t h0, h1, h2, h3, l0, l1, l2, l3;
    split1(v.x, h0, l0); split1(v.y, h1, l1);
    split1(v.z, h2, l2); split1(v.w, h3, l3);
    hi.x = h0 | (h1 << 16); hi.y = h2 | (h3 << 16);
    lo.x = l0 | (l1 << 16); lo.y = l2 | (l3 << 16);
}

__device__ __forceinline__ ushort_t f16of(float x) {
    _Float16 h = (_Float16)x;
    return *(ushort_t*)&h;
}

__device__ __forceinline__ void splitf16(float x, ushort_t& h, ushort_t& l) {
    _Float16 hh = (_Float16)x;
    float hf = (float)hh;
    _Float16 hl = (_Float16)(x - hf);
    h = *(ushort_t*)&hh;
    l = *(ushort_t*)&hl;
}

__device__ __forceinline__ void gl_lds16(const void* g, void* l) {
    __builtin_amdgcn_global_load_lds(
        (const __attribute__((address_space(1))) void*)g,
        (__attribute__((address_space(3))) void*)l, 16, 0, 0);
}

// ---------------------------------------------------------------------------
// Embeddings -> single fp16 plane: xs[t*R + l*B+b][e]
__global__ __launch_bounds__(128) void k_embed(const int* __restrict__ inputs,
                                               const float* __restrict__ embW,
                                               ushort_t* __restrict__ x16) {
    int blk = blockIdx.x;              // l*T*B + t*B + b
    int b = blk % B;
    int t = (blk / B) % T;
    int l = blk / (B * T);
    int tok = inputs[(l + 1) * B * S + b * S + t];
    const float4* src = (const float4*)(embW + (long long)tok * E);
    float4 v = src[threadIdx.x];
    uint_t w0 = f16of(v.x) | ((uint_t)f16of(v.y) << 16);
    uint_t w1 = f16of(v.z) | ((uint_t)f16of(v.w) << 16);
    size_t base = ((size_t)t * R + (size_t)l * B + b) * E + threadIdx.x * 4;
    uint2 pk = {w0, w1};
    *(uint2*)(x16 + base) = pk;
}

// ---------------------------------------------------------------------------
__global__ __launch_bounds__(128) void k_pe(const int* __restrict__ inputs,
                                            const int* __restrict__ lens,
                                            const float* __restrict__ embW,
                                            ushort_t* __restrict__ phi,
                                            ushort_t* __restrict__ plo) {
    int r = blockIdx.x;
    int l = r >> 6, b = r & 63;
    int plen = lens[l * B + b];
    int send = plen - 1;
    if (send > S) send = S;
    const int* toks = inputs + l * B * S + b * S;
    float4 acc = {0.f, 0.f, 0.f, 0.f};
    for (int s = 1; s < send; ++s) {
        int tok = toks[s];
        float4 v = ((const float4*)(embW + (long long)tok * E))[threadIdx.x];
        acc.x += v.x; acc.y += v.y; acc.z += v.z; acc.w += v.w;
    }
    const float inv = 1.f / 32.f;
    acc.x *= inv; acc.y *= inv; acc.z *= inv; acc.w *= inv;
    uint2 hi, lo; split_quad(acc, hi, lo);
    size_t base = (size_t)r * E + threadIdx.x * 4;
    *(uint2*)(phi + base) = hi;
    *(uint2*)(plo + base) = lo;
}

// ---------------------------------------------------------------------------
__global__ __launch_bounds__(256) void k_cm(const float* __restrict__ ctx,
                                            ushort_t* __restrict__ chi,
                                            ushort_t* __restrict__ clo) {
    int b = blockIdx.x;
    int j = threadIdx.x;
    const float4* c4 = (const float4*)(ctx + (size_t)b * SRC * H);
    float4 acc = {0.f, 0.f, 0.f, 0.f};
    for (int s = 0; s < SRC; ++s) {
        float4 v = c4[(size_t)s * (H / 4) + j];
        acc.x += v.x; acc.y += v.y; acc.z += v.z; acc.w += v.w;
    }
    const float inv = 1.f / (float)SRC;
    acc.x *= inv; acc.y *= inv; acc.z *= inv; acc.w *= inv;
    uint2 hi, lo; split_quad(acc, hi, lo);
    size_t base = (size_t)b * H + j * 4;
    *(uint2*)(chi + base) = hi;
    *(uint2*)(clo + base) = lo;
}

// ---------------------------------------------------------------------------
// Row-major plane splitter (contexts): bf16 hi/lo + optional fp16 plane.
__global__ __launch_bounds__(256) void k_wsplit(
    const float* __restrict__ src1, int ld1, int o1, int Ka,
    const float* __restrict__ src2, int ld2, int o2, int Kb,
    int rowmap, ushort_t* __restrict__ dhi, ushort_t* __restrict__ dlo,
    ushort_t* __restrict__ d16) {
    int n = blockIdx.x;
    int KT = Ka + Kb;
    long long r = rowmap ? ((long long)(n & 3) * H + (n >> 2)) : (long long)n;
    for (int k4 = threadIdx.x; k4 < (KT >> 2); k4 += 256) {
        int k = k4 << 2;
        float4 v = (k < Ka) ? *(const float4*)(src1 + r * ld1 + o1 + k)
                            : *(const float4*)(src2 + r * ld2 + o2 + (k - Ka));
        uint2 hi, lo; split_quad(v, hi, lo);
        size_t base = (size_t)n * KT + k;
        *(uint2*)(dhi + base) = hi;
        *(uint2*)(dlo + base) = lo;
        if (d16) {
            uint2 pk;
            pk.x = f16of(v.x) | ((uint_t)f16of(v.y) << 16);
            pk.y = f16of(v.z) | ((uint_t)f16of(v.w) << 16);
            *(uint2*)(d16 + base) = pk;
        }
    }
}

// ---------------------------------------------------------------------------
// fp16 transpose: ctxT[b][h][s] = ctx16[b][s][h]. LDS-tiled, coalesced.
// grid (B, H/64, SRC/64), 256 thr.
__global__ __launch_bounds__(256) void k_ctxT(const ushort_t* __restrict__ src,
                                              ushort_t* __restrict__ dst) {
    __shared__ ushort_t tile[64][66];
    const int b = blockIdx.x, h0 = blockIdx.y * 64, s0 = blockIdx.z * 64;
    const int tid = threadIdx.x;
    for (int it = tid; it < 512; it += 256) {
        int s = it >> 3, ho = (it & 7) * 8;
        uint4 v = *(const uint4*)(src + ((size_t)b * SRC + s0 + s) * H + h0 + ho);
        *(uint4*)&tile[s][ho] = v;
    }
    __syncthreads();
    for (int it = tid; it < 512; it += 256) {
        int h = it >> 3, so = (it & 7) * 8;
        ushort_t vals[8];
#pragma unroll
        for (int i = 0; i < 8; ++i) vals[i] = tile[so + i][h];
        *(uint4*)(dst + ((size_t)b * H + h0 + h) * SRC + s0 + so) = *(uint4*)vals;
    }
}

// ---------------------------------------------------------------------------
// bf16 tiled split panel (init weights) — 16KB/tile.
__global__ __launch_bounds__(256) void k_wtile(
    const float* __restrict__ src1, int ld1, int o1, int Ka,
    const float* __restrict__ src2, int ld2, int o2, int Kb,
    int rowmap, unsigned char* __restrict__ panel) {
    int cb = blockIdx.x, t = blockIdx.y;
    int KT = Ka + Kb;
    int NT = KT >> 6;
    size_t obase = ((size_t)cb * NT + t) * 16384;
    int k0 = t << 6;
    for (int q = threadIdx.x; q < 512; q += 256) {
        int s = q >> 6, l = q & 63;
        int n = cb * 64 + 8 * s + (l >> 3);
        long long r = rowmap ? ((long long)(n & 3) * H + (n >> 2)) : (long long)n;
        int xorc = ((l & 7) * 16) ^ ((l >> 3) << 4);
        int ke = k0 + (xorc >> 1);
        const float* sp = (ke < Ka) ? (src1 + r * ld1 + o1 + ke)
                                    : (src2 + r * ld2 + o2 + (ke - Ka));
        float4 v01 = *(const float4*)sp;
        float4 v23 = *(const float4*)(sp + 4);
        uint2 h0, l0, h1, l1;
        split_quad(v01, h0, l0);
        split_quad(v23, h1, l1);
        uint4 hi = {h0.x, h0.y, h1.x, h1.y};
        uint4 lo = {l0.x, l0.y, l1.x, l1.y};
        *(uint4*)(panel + obase + s * 1024 + l * 16) = hi;
        *(uint4*)(panel + obase + 8192 + s * 1024 + l * 16) = lo;
    }
}

// ---------------------------------------------------------------------------
// fp16 hi/lo tiled panel — 16KB/tile.
__global__ __launch_bounds__(256) void k_wtile16(
    const float* __restrict__ src1, int ld1, int Ka,
    const float* __restrict__ src2, int ld2, int Kb,
    int rowmap, unsigned char* __restrict__ panel) {
    int cb = blockIdx.x, t = blockIdx.y;
    int KT = Ka + Kb;
    int NT = KT >> 6;
    size_t obase = ((size_t)cb * NT + t) * 16384;
    int k0 = t << 6;
    for (int q = threadIdx.x; q < 512; q += 256) {
        int s = q >> 6, l = q & 63;
        int n = cb * 64 + 8 * s + (l >> 3);
        long long r = rowmap ? ((long long)(n & 3) * H + (n >> 2)) : (long long)n;
        int xorc = ((l & 7) * 16) ^ ((l >> 3) << 4);
        int ke = k0 + (xorc >> 1);
        const float* sp = (ke < Ka) ? (src1 + r * ld1 + ke)
                                    : (src2 + r * ld2 + (ke - Ka));
        ushort_t hh[8], ll[8];
#pragma unroll
        for (int e = 0; e < 8; ++e) splitf16(sp[e], hh[e], ll[e]);
        uint4 hi = {(uint_t)hh[0] | ((uint_t)hh[1] << 16),
                    (uint_t)hh[2] | ((uint_t)hh[3] << 16),
                    (uint_t)hh[4] | ((uint_t)hh[5] << 16),
                    (uint_t)hh[6] | ((uint_t)hh[7] << 16)};
        uint4 lo = {(uint_t)ll[0] | ((uint_t)ll[1] << 16),
                    (uint_t)ll[2] | ((uint_t)ll[3] << 16),
                    (uint_t)ll[4] | ((uint_t)ll[5] << 16),
                    (uint_t)ll[6] | ((uint_t)ll[7] << 16)};
        *(uint4*)(panel + obase + s * 1024 + l * 16) = hi;
        *(uint4*)(panel + obase + 8192 + s * 1024 + l * 16) = lo;
    }
}

// ---------------------------------------------------------------------------
// fp16 SINGLE tiled panel (gate weights) — 8KB/tile, gate interleave.
__global__ __launch_bounds__(256) void k_wtile16s(
    const float* __restrict__ src1, int ld1, int Ka,
    const float* __restrict__ src2, int ld2, int Kb,
    unsigned char* __restrict__ panel) {
    int cb = blockIdx.x, t = blockIdx.y;
    int KT = Ka + Kb;
    int NT = KT >> 6;
    size_t obase = ((size_t)cb * NT + t) * 8192;
    int k0 = t << 6;
    for (int q = threadIdx.x; q < 512; q += 256) {
        int s = q >> 6, l = q & 63;
        int n = cb * 64 + 8 * s + (l >> 3);
        long long r = (long long)(n & 3) * H + (n >> 2);   // gate interleave
        int xorc = ((l & 7) * 16) ^ ((l >> 3) << 4);
        int ke = k0 + (xorc >> 1);
        const float* sp = (ke < Ka) ? (src1 + r * ld1 + ke)
                                    : (src2 + r * ld2 + (ke - Ka));
        ushort_t hh[8];
#pragma unroll
        for (int e = 0; e < 8; ++e) hh[e] = f16of(sp[e]);
        uint4 hi = {(uint_t)hh[0] | ((uint_t)hh[1] << 16),
                    (uint_t)hh[2] | ((uint_t)hh[3] << 16),
                    (uint_t)hh[4] | ((uint_t)hh[5] << 16),
                    (uint_t)hh[6] | ((uint_t)hh[7] << 16)};
        *(uint4*)(panel + obase + s * 1024 + l * 16) = hi;
    }
}

// ---------------------------------------------------------------------------
// bf16 split MFMA GEMM (init projections) — unchanged.
__global__ __launch_bounds__(256) void k_g2(
    const ushort_t* __restrict__ Ah1, const ushort_t* __restrict__ Al1, int K1,
    const ushort_t* __restrict__ Ah2, const ushort_t* __restrict__ Al2, int K2,
    int a2mod,
    const unsigned char* __restrict__ Bp,
    const float* __restrict__ bias1, const float* __restrict__ bias2,
    int mode, float* __restrict__ C,
    long long strideT, long long strideL, long long strideB, int act,
    ushort_t* __restrict__ ohi, ushort_t* __restrict__ olo) {
    __shared__ __align__(16) unsigned char lds[65536];
    const int tid = threadIdx.x;
    const int lane = tid & 63;
    const int wv = tid >> 6;
    const int wm = wv & 1, wn = wv >> 1;
    const int cblk = blockIdx.x;
    const int mblk = blockIdx.y;
    const int m0 = mblk * 64;
    const int colbase = cblk * 64;
    const int KT = K1 + K2;
    const int NT = KT >> 6;
    const int n1steps = K1 >> 6;
    const size_t pbase = (size_t)cblk * NT * 16384;

    f32x4_v zero = {0.f, 0.f, 0.f, 0.f};
    f32x4_v acc[2][2] = {{zero, zero}, {zero, zero}};
    const int xorc = ((lane & 7) * 16) ^ ((lane >> 3) << 4);
    const int rsub = lane >> 3;

    auto stage = [&](int t, int buf) {
        unsigned char* dstA = lds + buf * 16384;
        unsigned char* dstB = lds + 32768 + buf * 16384;
        {
            const ushort_t *Ph, *Pl; int lda, k0, mod;
            if (t < n1steps) { Ph = Ah1; Pl = Al1; lda = K1; k0 = t << 6; mod = 0; }
            else { Ph = Ah2; Pl = Al2; lda = K2; k0 = (t - n1steps) << 6; mod = a2mod; }
#pragma unroll
            for (int cc = 0; cc < 4; ++cc) {
                int c = wv * 4 + cc;
                int p = c >> 3, s = c & 7;
                int rr = m0 + 8 * s + rsub;
                if (mod) rr &= (mod - 1);
                const ushort_t* plane = p ? Pl : Ph;
                gl_lds16((const unsigned char*)(plane + (size_t)rr * lda + k0) + xorc,
                         dstA + c * 1024);
            }
        }
        {
            const unsigned char* tb = Bp + pbase + (size_t)t * 16384;
#pragma unroll
            for (int cc = 0; cc < 4; ++cc) {
                int c = wv * 4 + cc;
                gl_lds16(tb + c * 1024 + lane * 16, dstB + c * 1024);
            }
        }
    };
    auto compute = [&](int buf) {
        const unsigned char* Ab = lds + buf * 16384;
        const unsigned char* Bb = lds + 32768 + buf * 16384;
#pragma unroll
        for (int kf = 0; kf < 2; ++kf) {
            int colA = (kf * 64 + ((lane >> 4) * 16)) ^ ((lane & 7) << 4);
            bf16x8_v ah[2], al[2], bh[2], bl[2];
#pragma unroll
            for (int i = 0; i < 2; ++i) {
                int rowm = (wm * 2 + i) * 16 + (lane & 15);
                ah[i] = *(const bf16x8_v*)(Ab + rowm * 128 + colA);
                al[i] = *(const bf16x8_v*)(Ab + 8192 + rowm * 128 + colA);
                int rj = (wn * 2 + i) * 16 + (lane & 15);
                bh[i] = *(const bf16x8_v*)(Bb + rj * 128 + colA);
                bl[i] = *(const bf16x8_v*)(Bb + 8192 + rj * 128 + colA);
            }
            __builtin_amdgcn_s_setprio(1);
#pragma unroll
            for (int i = 0; i < 2; ++i)
#pragma unroll
                for (int j = 0; j < 2; ++j) {
                    acc[i][j] = __builtin_amdgcn_mfma_f32_16x16x32_bf16(al[i], bh[j], acc[i][j], 0, 0, 0);
                    acc[i][j] = __builtin_amdgcn_mfma_f32_16x16x32_bf16(ah[i], bl[j], acc[i][j], 0, 0, 0);
                    acc[i][j] = __builtin_amdgcn_mfma_f32_16x16x32_bf16(ah[i], bh[j], acc[i][j], 0, 0, 0);
                }
            __builtin_amdgcn_s_setprio(0);
        }
    };

    stage(0, 0);
    int cur = 0;
    for (int tt = 0; tt < NT; ++tt) {
        if (tt + 1 < NT) {
            stage(tt + 1, cur ^ 1);
            asm volatile("s_waitcnt vmcnt(8)" ::: "memory");
        } else {
            asm volatile("s_waitcnt vmcnt(0)" ::: "memory");
        }
        __builtin_amdgcn_s_barrier();
        __builtin_amdgcn_sched_barrier(0);
        compute(cur);
        __builtin_amdgcn_sched_barrier(0);
        __builtin_amdgcn_s_barrier();
        cur ^= 1;
    }

    const int l16 = lane & 15, g4 = (lane >> 4) * 4;
#pragma unroll
    for (int i = 0; i < 2; ++i) {
#pragma unroll
        for (int r = 0; r < 4; ++r) {
            int m = m0 + wm * 32 + i * 16 + g4 + r;
            long long rowoff = (long long)(m >> 8) * strideT
                             + (long long)((m >> 6) & 3) * strideL
                             + (long long)(m & 63) * strideB;
#pragma unroll
            for (int jj = 0; jj < 2; ++jj) {
                int n = colbase + wn * 32 + jj * 16 + l16;
                float v = acc[i][jj][r];
                if (mode == 0) {
                    if (bias1) v += bias1[n];
                    if (bias2) v += bias2[n];
                    if (act) v = tanhf(v);
                    C[rowoff + n] = v;
                } else {
                    uint_t hu, lu; split1(v, hu, lu);
                    ohi[rowoff + n] = (ushort_t)hu;
                    olo[rowoff + n] = (ushort_t)lu;
                }
            }
        }
    }
}

// ---------------------------------------------------------------------------
// fp16 GEMM v2: 512 thr (8 waves = 4m x 2n), tile 128m x 64n.
// A = concat fp16 single planes, B = fp16 hi/lo panel (16KB/tile).
// mode 0: C = tanh(acc + bias1), scattered. mode 2: bias + bf16 split -> ohi/olo.
__global__ __launch_bounds__(512) void k_g2h(
    const ushort_t* __restrict__ A1, int K1,
    const ushort_t* __restrict__ A2, int K2,
    const unsigned char* __restrict__ Bp,
    const float* __restrict__ bias1,
    int mode, float* __restrict__ C,
    long long strideT, long long strideL, long long strideB,
    ushort_t* __restrict__ ohi, ushort_t* __restrict__ olo) {
    __shared__ __align__(16) unsigned char lds[65536];
    const int tid = threadIdx.x;
    const int lane = tid & 63;
    const int wv = tid >> 6;            // 0..7
    const int wm = wv & 3, wn = wv >> 2;
    const int cblk = blockIdx.x;
    const int m0 = blockIdx.y * 128;
    const int colbase = cblk * 64;
    const int KT = K1 + K2;
    const int NT = KT >> 6;
    const int n1steps = K1 >> 6;
    const size_t pbase = (size_t)cblk * NT * 16384;

    f32x4_v zero = {0.f, 0.f, 0.f, 0.f};
    f32x4_v acc[2][2] = {{zero, zero}, {zero, zero}};
    const int xorc = ((lane & 7) * 16) ^ ((lane >> 3) << 4);
    const int rsub = lane >> 3;

    auto stage = [&](int t, int buf) {
        unsigned char* base = lds + buf * 32768;
        const ushort_t* Ap; int lda, k0;
        if (t < n1steps) { Ap = A1; lda = K1; k0 = t << 6; }
        else             { Ap = A2; lda = K2; k0 = (t - n1steps) << 6; }
        const unsigned char* tb = Bp + pbase + (size_t)t * 16384;
#pragma unroll
        for (int cc = 0; cc < 4; ++cc) {
            int c = wv * 4 + cc;           // 0..31
            if (c < 16) {                  // A: 16 chunks, rows m0..m0+127
                int rr = m0 + 8 * c + rsub;
                gl_lds16((const unsigned char*)(Ap + (size_t)rr * lda + k0) + xorc,
                         base + c * 1024);
            } else {                       // B hi/lo: 16 chunks, sequential panel
                int cb = c - 16;
                gl_lds16(tb + cb * 1024 + lane * 16, base + 16384 + cb * 1024);
            }
        }
    };
    auto compute = [&](int buf) {
        const unsigned char* Ab = lds + buf * 32768;
        const unsigned char* Bb = Ab + 16384;
#pragma unroll
        for (int kf = 0; kf < 2; ++kf) {
            int colA = (kf * 64 + ((lane >> 4) * 16)) ^ ((lane & 7) << 4);
            f16x8_v a[2], bh[2], bl[2];
#pragma unroll
            for (int i = 0; i < 2; ++i) {
                int rowm = wm * 32 + i * 16 + (lane & 15);     // 0..127
                a[i] = *(const f16x8_v*)(Ab + rowm * 128 + colA);
                int rj = wn * 32 + i * 16 + (lane & 15);       // 0..63
                bh[i] = *(const f16x8_v*)(Bb + rj * 128 + colA);
                bl[i] = *(const f16x8_v*)(Bb + 8192 + rj * 128 + colA);
            }
            __builtin_amdgcn_s_setprio(1);
#pragma unroll
            for (int i = 0; i < 2; ++i)
#pragma unroll
                for (int j = 0; j < 2; ++j) {
                    acc[i][j] = __builtin_amdgcn_mfma_f32_16x16x32_f16(a[i], bl[j], acc[i][j], 0, 0, 0);
                    acc[i][j] = __builtin_amdgcn_mfma_f32_16x16x32_f16(a[i], bh[j], acc[i][j], 0, 0, 0);
                }
            __builtin_amdgcn_s_setprio(0);
        }
    };

    stage(0, 0);
    int cur = 0;
    for (int tt = 0; tt < NT; ++tt) {
        if (tt + 1 < NT) {
            stage(tt + 1, cur ^ 1);
            asm volatile("s_waitcnt vmcnt(4)" ::: "memory");
        } else {
            asm volatile("s_waitcnt vmcnt(0)" ::: "memory");
        }
        __builtin_amdgcn_s_barrier();
        __builtin_amdgcn_sched_barrier(0);
        compute(cur);
        __builtin_amdgcn_sched_barrier(0);
        __builtin_amdgcn_s_barrier();
        cur ^= 1;
    }

    const int l16 = lane & 15, g4 = (lane >> 4) * 4;
#pragma unroll
    for (int i = 0; i < 2; ++i) {
#pragma unroll
        for (int r = 0; r < 4; ++r) {
            int m = m0 + wm * 32 + i * 16 + g4 + r;
            long long rowoff = (long long)(m >> 8) * strideT
                             + (long long)((m >> 6) & 3) * strideL
                             + (long long)(m & 63) * strideB;
#pragma unroll
            for (int jj = 0; jj < 2; ++jj) {
                int n = colbase + wn * 32 + jj * 16 + l16;
                float v = acc[i][jj][r] + bias1[n];
                if (mode == 0) {
                    C[rowoff + n] = tanhf(v);
                } else {
                    uint_t hu, lu; split1(v, hu, lu);
                    ohi[rowoff + n] = (ushort_t)hu;
                    olo[rowoff + n] = (ushort_t)lu;
                }
            }
        }
    }
}

// ---------------------------------------------------------------------------
// Dual-job gate GEMM + fused LSTM, fp16 single x single, 4-deep prefetch.
struct GateJob {
    const ushort_t *A1, *A2;          // fp16 planes
    const unsigned char* Bp;          // fp16 single panel
    const float *bias1, *bias2;
    float *cbuf, *hf;
    ushort_t *h16;                    // fp16 h out
    int K1, K2;
};

__global__ __launch_bounds__(256) void k_gatepair(GateJob j0, GateJob j1) {
    __shared__ __align__(16) unsigned char lds[65536];
    const bool sec = blockIdx.y >= 4;
    const ushort_t* A1v = sec ? j1.A1 : j0.A1;
    const ushort_t* A2v = sec ? j1.A2 : j0.A2;
    const unsigned char* Bp = sec ? j1.Bp : j0.Bp;
    const float* bias1  = sec ? j1.bias1 : j0.bias1;
    const float* bias2  = sec ? j1.bias2 : j0.bias2;
    float* cbuf         = sec ? j1.cbuf : j0.cbuf;
    float* hf           = sec ? j1.hf   : j0.hf;
    ushort_t* h16       = sec ? j1.h16  : j0.h16;
    const int K1        = sec ? j1.K1   : j0.K1;
    const int K2        = sec ? j1.K2   : j0.K2;

    const int tid = threadIdx.x;
    const int lane = tid & 63;
    const int wv = tid >> 6;
    const int wm = wv & 1, wn = wv >> 1;
    const int mblk = blockIdx.y & 3;
    const int cblk = blockIdx.x;
    const int m0 = mblk * 64;
    const int KT = K1 + K2;
    const int NT = KT >> 6;
    const int n1steps = K1 >> 6;
    const size_t pbase = (size_t)cblk * NT * 8192;

    f32x4_v zero = {0.f, 0.f, 0.f, 0.f};
    f32x4_v acc[2][2] = {{zero, zero}, {zero, zero}};
    const int xorc = ((lane & 7) * 16) ^ ((lane >> 3) << 4);
    const int rsub = lane >> 3;

    auto stage = [&](int t, int buf) {
        unsigned char* base = lds + buf * 16384;
        const ushort_t* Ap; int lda, k0;
        if (t < n1steps) { Ap = A1v; lda = K1; k0 = t << 6; }
        else             { Ap = A2v; lda = K2; k0 = (t - n1steps) << 6; }
        const unsigned char* tb = Bp + pbase + (size_t)t * 8192;
#pragma unroll
        for (int cc = 0; cc < 4; ++cc) {
            int c = wv * 4 + cc;           // 0..15
            if (c < 8) {
                int rr = m0 + 8 * c + rsub;
                gl_lds16((const unsigned char*)(Ap + (size_t)rr * lda + k0) + xorc,
                         base + c * 1024);
            } else {
                gl_lds16(tb + (c - 8) * 1024 + lane * 16, base + c * 1024);
            }
        }
    };
    auto compute = [&](int buf) {
        const unsigned char* Ab = lds + buf * 16384;
        const unsigned char* Bb = Ab + 8192;
#pragma unroll
        for (int kf = 0; kf < 2; ++kf) {
            int colA = (kf * 64 + ((lane >> 4) * 16)) ^ ((lane & 7) << 4);
            f16x8_v a[2], bv[2];
#pragma unroll
            for (int i = 0; i < 2; ++i) {
                int rowm = (wm * 2 + i) * 16 + (lane & 15);
                a[i] = *(const f16x8_v*)(Ab + rowm * 128 + colA);
                int rj = (wn * 2 + i) * 16 + (lane & 15);
                bv[i] = *(const f16x8_v*)(Bb + rj * 128 + colA);
            }
            __builtin_amdgcn_s_setprio(1);
#pragma unroll
            for (int i = 0; i < 2; ++i)
#pragma unroll
                for (int j = 0; j < 2; ++j)
                    acc[i][j] = __builtin_amdgcn_mfma_f32_16x16x32_f16(a[i], bv[j], acc[i][j], 0, 0, 0);
            __builtin_amdgcn_s_setprio(0);
        }
    };

    stage(0, 0);
    stage(1, 1);
    stage(2, 2);
    for (int tt = 0; tt < NT; ++tt) {
        if (tt + 3 < NT) {
            stage(tt + 3, (tt + 3) & 3);
            asm volatile("s_waitcnt vmcnt(12)" ::: "memory");
        } else if (tt + 2 < NT) {
            asm volatile("s_waitcnt vmcnt(8)" ::: "memory");
        } else if (tt + 1 < NT) {
            asm volatile("s_waitcnt vmcnt(4)" ::: "memory");
        } else {
            asm volatile("s_waitcnt vmcnt(0)" ::: "memory");
        }
        __builtin_amdgcn_s_barrier();
        __builtin_amdgcn_sched_barrier(0);
        compute(tt & 3);
        __builtin_amdgcn_sched_barrier(0);
        __builtin_amdgcn_s_barrier();
    }

    // gate tile -> LDS [64][68] f32 (overlays staging; drained)
    float* gtile = (float*)lds;
    const int l16 = lane & 15, g4 = (lane >> 4) * 4;
#pragma unroll
    for (int i = 0; i < 2; ++i)
#pragma unroll
        for (int jj = 0; jj < 2; ++jj)
#pragma unroll
            for (int r = 0; r < 4; ++r)
                gtile[(wm * 32 + i * 16 + g4 + r) * 68 + wn * 32 + jj * 16 + l16] = acc[i][jj][r];
    __syncthreads();

    int m = tid >> 2;
    int hcb = (tid & 3) * 4;
    int nh0 = cblk * 16;
#pragma unroll
    for (int e = 0; e < 4; ++e) {
        int hc = hcb + e;
        float gv[4];
#pragma unroll
        for (int q = 0; q < 4; ++q) {
            int bidx = q * H + nh0 + hc;
            gv[q] = gtile[m * 68 + hc * 4 + q] + bias1[bidx] + bias2[bidx];
        }
        size_t idx = (size_t)(m0 + m) * H + nh0 + hc;
        float cp = cbuf[idx];
        float si = 1.f / (1.f + __expf(-gv[0]));
        float sf = 1.f / (1.f + __expf(-gv[1]));
        float so = 1.f / (1.f + __expf(-gv[3]));
        float c = sf * cp + si * tanhf(gv[2]);
        float hn = so * tanhf(c);
        cbuf[idx] = c;
        hf[idx] = hn;
        h16[idx] = f16of(hn);
    }
}

// ---------------------------------------------------------------------------
// Batched score MFMA (bf16 3-term): scores[t*R+l*64+b][s] = gamma . ctx.
__global__ __launch_bounds__(256) void k_smfma(
    const ushort_t* __restrict__ gah, const ushort_t* __restrict__ gal,
    const ushort_t* __restrict__ cxh, const ushort_t* __restrict__ cxl,
    float* __restrict__ scores) {
    __shared__ __align__(16) unsigned char lds[65536];
    const int tid = threadIdx.x;
    const int lane = tid & 63;
    const int wv = tid >> 6;
    const int wm = wv & 1, wn = wv >> 1;
    const int b = blockIdx.z;
    const int m0 = blockIdx.y * 64;
    const int colbase = blockIdx.x * 64;
    const int NT = 16;

    f32x4_v zero = {0.f, 0.f, 0.f, 0.f};
    f32x4_v acc[2][2] = {{zero, zero}, {zero, zero}};
    const int xorc = ((lane & 7) * 16) ^ ((lane >> 3) << 4);
    const int rsub = lane >> 3;

    auto stage = [&](int t, int buf) {
        unsigned char* dstA = lds + buf * 16384;
        unsigned char* dstB = lds + 32768 + buf * 16384;
        int k0 = t << 6;
#pragma unroll
        for (int cc = 0; cc < 4; ++cc) {
            int c = wv * 4 + cc;
            int p = c >> 3, s = c & 7;
            int rr = m0 + 8 * s + rsub;
            int tt = rr >> 2; if (tt > 30) tt = 30;
            size_t row = (size_t)tt * R + (rr & 3) * 64 + b;
            const ushort_t* plane = p ? gal : gah;
            gl_lds16((const unsigned char*)(plane + row * H + k0) + xorc,
                     dstA + c * 1024);
        }
#pragma unroll
        for (int cc = 0; cc < 4; ++cc) {
            int c = wv * 4 + cc;
            int p = c >> 3, s = c & 7;
            int rr = colbase + 8 * s + rsub;
            const ushort_t* plane = p ? cxl : cxh;
            gl_lds16((const unsigned char*)(plane + ((size_t)b * SRC + rr) * H + k0) + xorc,
                     dstB + c * 1024);
        }
    };
    auto compute = [&](int buf) {
        const unsigned char* Ab = lds + buf * 16384;
        const unsigned char* Bb = lds + 32768 + buf * 16384;
#pragma unroll
        for (int kf = 0; kf < 2; ++kf) {
            int colA = (kf * 64 + ((lane >> 4) * 16)) ^ ((lane & 7) << 4);
            bf16x8_v ah[2], al[2], bh[2], bl[2];
#pragma unroll
            for (int i = 0; i < 2; ++i) {
                int rowm = (wm * 2 + i) * 16 + (lane & 15);
                ah[i] = *(const bf16x8_v*)(Ab + rowm * 128 + colA);
                al[i] = *(const bf16x8_v*)(Ab + 8192 + rowm * 128 + colA);
                int rj = (wn * 2 + i) * 16 + (lane & 15);
                bh[i] = *(const bf16x8_v*)(Bb + rj * 128 + colA);
                bl[i] = *(const bf16x8_v*)(Bb + 8192 + rj * 128 + colA);
            }
            __builtin_amdgcn_s_setprio(1);
#pragma unroll
            for (int i = 0; i < 2; ++i)
#pragma unroll
                for (int j = 0; j < 2; ++j) {
                    acc[i][j] = __builtin_amdgcn_mfma_f32_16x16x32_bf16(al[i], bh[j], acc[i][j], 0, 0, 0);
                    acc[i][j] = __builtin_amdgcn_mfma_f32_16x16x32_bf16(ah[i], bl[j], acc[i][j], 0, 0, 0);
                    acc[i][j] = __builtin_amdgcn_mfma_f32_16x16x32_bf16(ah[i], bh[j], acc[i][j], 0, 0, 0);
                }
            __builtin_amdgcn_s_setprio(0);
        }
    };

    stage(0, 0);
    int cur = 0;
    for (int tt = 0; tt < NT; ++tt) {
        if (tt + 1 < NT) {
            stage(tt + 1, cur ^ 1);
            asm volatile("s_waitcnt vmcnt(8)" ::: "memory");
        } else {
            asm volatile("s_waitcnt vmcnt(0)" ::: "memory");
        }
        __builtin_amdgcn_s_barrier();
        __builtin_amdgcn_sched_barrier(0);
        compute(cur);
        __builtin_amdgcn_sched_barrier(0);
        __builtin_amdgcn_s_barrier();
        cur ^= 1;
    }

    const int l16 = lane & 15, g4 = (lane >> 4) * 4;
#pragma unroll
    for (int i = 0; i < 2; ++i) {
#pragma unroll
        for (int jj = 0; jj < 2; ++jj) {
#pragma unroll
            for (int r = 0; r < 4; ++r) {
                int m = m0 + wm * 32 + i * 16 + g4 + r;
                int t = m >> 2;
                if (t < 31) {
                    size_t row = (size_t)t * R + (m & 3) * 64 + b;
                    int n = colbase + wn * 32 + jj * 16 + l16;
                    scores[row * SRC + n] = acc[i][jj][r];
                }
            }
        }
    }
}

// ---------------------------------------------------------------------------
// Softmax -> fp16 weights.
__global__ __launch_bounds__(256) void k_smax(const float* __restrict__ scores,
                                              ushort_t* __restrict__ w16) {
    int t = blockIdx.x, b = blockIdx.y;
    int l = threadIdx.x >> 6, lane = threadIdx.x & 63;
    size_t row = (size_t)t * R + l * 64 + b;
    const float* sr = scores + row * SRC;
    float v0 = sr[lane];
    float v1 = sr[lane + 64];
    float v2 = sr[lane + 128];
    float v3 = sr[lane + 192];
    float m = fmaxf(fmaxf(v0, v1), fmaxf(v2, v3));
#pragma unroll
    for (int off = 32; off >= 1; off >>= 1) m = fmaxf(m, __shfl_xor(m, off));
    float e0 = expf(v0 - m), e1 = expf(v1 - m), e2 = expf(v2 - m), e3 = expf(v3 - m);
    float sum = e0 + e1 + e2 + e3;
#pragma unroll
    for (int off = 32; off >= 1; off >>= 1) sum += __shfl_xor(sum, off);
    float inv = 1.f / sum;
    ushort_t* wr = w16 + row * SRC;
    wr[lane] = f16of(e0 * inv);
    wr[lane + 64] = f16of(e1 * inv);
    wr[lane + 128] = f16of(e2 * inv);
    wr[lane + 192] = f16of(e3 * inv);
}

// ---------------------------------------------------------------------------
// MFMA ct: ct16[row][h] = sum_s w16[row][s] * ctxT[b][h][s].
// grid (16 hblk, 2 mblk, B), 256 thr, K=256 (NT=4), fp16 single x single.
__global__ __launch_bounds__(256) void k_ctmm(
    const ushort_t* __restrict__ w16, const ushort_t* __restrict__ ctxT,
    ushort_t* __restrict__ ct16) {
    __shared__ __align__(16) unsigned char lds[32768];
    const int tid = threadIdx.x;
    const int lane = tid & 63;
    const int wv = tid >> 6;
    const int wm = wv & 1, wn = wv >> 1;
    const int b = blockIdx.z;
    const int m0 = blockIdx.y * 64;
    const int colbase = blockIdx.x * 64;
    const int NT = 4;

    f32x4_v zero = {0.f, 0.f, 0.f, 0.f};
    f32x4_v acc[2][2] = {{zero, zero}, {zero, zero}};
    const int xorc = ((lane & 7) * 16) ^ ((lane >> 3) << 4);
    const int rsub = lane >> 3;

    auto stage = [&](int t, int buf) {
        unsigned char* base = lds + buf * 16384;
        int k0 = t << 6;
#pragma unroll
        for (int cc = 0; cc < 4; ++cc) {
            int c = wv * 4 + cc;           // 0..15
            if (c < 8) {                   // A = w16, rows mapped like smfma
                int rr = m0 + 8 * c + rsub;
                int tt = rr >> 2; if (tt > 30) tt = 30;
                size_t row = (size_t)tt * R + (rr & 3) * 64 + b;
                gl_lds16((const unsigned char*)(w16 + row * SRC + k0) + xorc,
                         base + c * 1024);
            } else {                       // B = ctxT rows (h)
                int hr = colbase + 8 * (c - 8) + rsub;
                gl_lds16((const unsigned char*)(ctxT + ((size_t)b * H + hr) * SRC + k0) + xorc,
                         base + 8192 + (c - 8) * 1024);
            }
        }
    };
    auto compute = [&](int buf) {
        const unsigned char* Ab = lds + buf * 16384;
        const unsigned char* Bb = Ab + 8192;
#pragma unroll
        for (int kf = 0; kf < 2; ++kf) {
            int colA = (kf * 64 + ((lane >> 4) * 16)) ^ ((lane & 7) << 4);
            f16x8_v a[2], bv[2];
#pragma unroll
            for (int i = 0; i < 2; ++i) {
                int rowm = (wm * 2 + i) * 16 + (lane & 15);
                a[i] = *(const f16x8_v*)(Ab + rowm * 128 + colA);
                int rj = (wn * 2 + i) * 16 + (lane & 15);
                bv[i] = *(const f16x8_v*)(Bb + rj * 128 + colA);
            }
            __builtin_amdgcn_s_setprio(1);
#pragma unroll
            for (int i = 0; i < 2; ++i)
#pragma unroll
                for (int j = 0; j < 2; ++j)
                    acc[i][j] = __builtin_amdgcn_mfma_f32_16x16x32_f16(a[i], bv[j], acc[i][j], 0, 0, 0);
            __builtin_amdgcn_s_setprio(0);
        }
    };

    stage(0, 0);
    int cur = 0;
    for (int tt = 0; tt < NT; ++tt) {
        if (tt + 1 < NT) {
            stage(tt + 1, cur ^ 1);
            asm volatile("s_waitcnt vmcnt(4)" ::: "memory");
        } else {
            asm volatile("s_waitcnt vmcnt(0)" ::: "memory");
        }
        __builtin_amdgcn_s_barrier();
        __builtin_amdgcn_sched_barrier(0);
        compute(cur);
        __builtin_amdgcn_sched_barrier(0);
        __builtin_amdgcn_s_barrier();
        cur ^= 1;
    }

    const int l16 = lane & 15, g4 = (lane >> 4) * 4;
#pragma unroll
    for (int i = 0; i < 2; ++i) {
#pragma unroll
        for (int r = 0; r < 4; ++r) {
            int m = m0 + wm * 32 + i * 16 + g4 + r;
            int t = m >> 2;
            if (t < 31) {
                size_t row = (size_t)t * R + (m & 3) * 64 + b;
#pragma unroll
                for (int jj = 0; jj < 2; ++jj) {
                    int n = colbase + wn * 32 + jj * 16 + l16;
                    ct16[row * H + n] = f16of(acc[i][jj][r]);
                }
            }
        }
    }
}

// ---------------------------------------------------------------------------
__global__ __launch_bounds__(256) void k_init_split(const float* __restrict__ h0f,
                                                    const float* __restrict__ c0f,
                                                    float* __restrict__ h1f,
                                                    float* __restrict__ c1f,
                                                    ushort_t* __restrict__ h0_16,
                                                    ushort_t* __restrict__ h1i_16) {
    int idx = blockIdx.x * 256 + threadIdx.x;
    float h = h0f[idx], c = c0f[idx];
    h1f[idx] = h; c1f[idx] = c;
    ushort_t hv = f16of(h);
    h0_16[idx] = hv;
    h1i_16[idx] = hv;
}

// ---------------------------------------------------------------------------
extern "C" void kernel_launch(void* const* d_in, const int* in_sizes, int n_in,
                              void* d_out, int out_size, void* d_ws, size_t ws_size,
                              hipStream_t stream) {
    const int*   inputs     = (const int*)d_in[0];
    const int*   input_lens = (const int*)d_in[1];
    const float* contexts   = (const float*)d_in[2];
    const float* emb_W      = (const float*)d_in[3];
    const float* W_ih0      = (const float*)d_in[4];
    const float* W_hh0      = (const float*)d_in[5];
    const float* b_ih0      = (const float*)d_in[6];
    const float* b_hh0      = (const float*)d_in[7];
    const float* W_ih1      = (const float*)d_in[8];
    const float* W_hh1      = (const float*)d_in[9];
    const float* b_ih1      = (const float*)d_in[10];
    const float* b_hh1      = (const float*)d_in[11];
    const float* att_in_W   = (const float*)d_in[12];
    const float* att_in_b   = (const float*)d_in[13];
    const float* att_out_W  = (const float*)d_in[14];
    const float* att_out_b  = (const float*)d_in[15];
    const float* isl_in_W   = (const float*)d_in[16];
    const float* isl_in_b   = (const float*)d_in[17];
    const float* isl_out_W  = (const float*)d_in[18];
    const float* isl_out_b  = (const float*)d_in[19];

    float* out = (float*)d_out;

    // workspace carve (256B-aligned)
    char* p = (char*)d_ws;
    auto alloc = [&](size_t bytes) { char* r = p; p += (bytes + 255) & ~(size_t)255; return r; };
    ushort_t* xs16 = (ushort_t*)alloc((size_t)T * R * E * 2);     // fp16 x
    ushort_t* h016[2];
    h016[0] = (ushort_t*)alloc((size_t)R * H * 2);
    h016[1] = (ushort_t*)alloc((size_t)R * H * 2);
    ushort_t* h1i16 = (ushort_t*)alloc((size_t)R * H * 2);
    ushort_t* h116all = (ushort_t*)alloc((size_t)T * R * H * 2);  // fp16 h1 per t
    ushort_t* gamh = (ushort_t*)alloc((size_t)T * R * H * 2);     // gamma bf16 pair
    ushort_t* gaml = (ushort_t*)alloc((size_t)T * R * H * 2);
    ushort_t* pehi = (ushort_t*)alloc((size_t)R * E * 2);
    ushort_t* pelo = (ushort_t*)alloc((size_t)R * E * 2);
    ushort_t* cmhi = (ushort_t*)alloc((size_t)B * H * 2);
    ushort_t* cmlo = (ushort_t*)alloc((size_t)B * H * 2);
    // gate weight panels: fp16 single tiled (8KB/tile)
    unsigned char* wg0p = (unsigned char*)alloc((size_t)64 * 24 * 8192);
    unsigned char* wg1p = (unsigned char*)alloc((size_t)64 * 32 * 8192);
    // fp16 hi/lo panels: att_in (gamma), att_out
    unsigned char* wgip = (unsigned char*)alloc((size_t)16 * 16 * 16384);
    unsigned char* wotp = (unsigned char*)alloc((size_t)16 * 32 * 16384);
    // bf16 panels for init
    unsigned char* wiip = (unsigned char*)alloc((size_t)16 * 24 * 16384);
    unsigned char* wiop = (unsigned char*)alloc((size_t)16 * 24 * 16384);
    // ctx planes: bf16 pair (score pass) + fp16 + fp16 transposed (ct pass)
    ushort_t* cxh = (ushort_t*)alloc((size_t)B * SRC * H * 2);
    ushort_t* cxl = (ushort_t*)alloc((size_t)B * SRC * H * 2);
    ushort_t* ctx16 = (ushort_t*)alloc((size_t)B * SRC * H * 2);
    ushort_t* ctxT16 = (ushort_t*)alloc((size_t)B * SRC * H * 2);
    float* h0f = (float*)alloc((size_t)R * H * 4);
    float* h1f = (float*)alloc((size_t)R * H * 4);
    float* c0f = (float*)alloc((size_t)R * H * 4);
    float* c1f = (float*)alloc((size_t)R * H * 4);
    // post buffers
    float* scores = (float*)alloc((size_t)T * R * SRC * 4);
    ushort_t* w16 = (ushort_t*)alloc((size_t)T * R * SRC * 2);
    ushort_t* ct16 = (ushort_t*)alloc((size_t)T * R * H * 2);

    // ---- setup ----
    k_embed<<<L4 * T * B, 128, 0, stream>>>(inputs, emb_W, xs16);
    k_pe<<<R, 128, 0, stream>>>(inputs, input_lens, emb_W, pehi, pelo);
    k_cm<<<B, 256, 0, stream>>>(contexts, cmhi, cmlo);
    k_wtile16s<<<dim3(64, 24), 256, 0, stream>>>(W_ih0, 512, 512, W_hh0, 1024, 1024, wg0p);
    k_wtile16s<<<dim3(64, 32), 256, 0, stream>>>(W_ih1, 1024, 1024, W_hh1, 1024, 1024, wg1p);
    k_wtile16<<<dim3(16, 16), 256, 0, stream>>>(att_in_W, 1024, 1024, nullptr, 0, 0, 0, wgip);
    k_wtile16<<<dim3(16, 32), 256, 0, stream>>>(att_out_W, 2048, 2048, nullptr, 0, 0, 0, wotp);
    k_wtile<<<dim3(16, 24), 256, 0, stream>>>(isl_in_W, 1536, 0, 1536, nullptr, 0, 0, 0, 0, wiip);
    k_wtile<<<dim3(16, 24), 256, 0, stream>>>(isl_out_W, 1536, 1024, 512, isl_out_W, 1536, 0, 1024, 0, wiop);
    k_wsplit<<<B * SRC, 256, 0, stream>>>(contexts, 1024, 0, 1024, nullptr, 0, 0, 0, 0, cxh, cxl, ctx16);
    k_ctxT<<<dim3(B, 16, 4), 256, 0, stream>>>(ctx16, ctxT16);

    // init projections (bf16 path, unchanged)
    k_g2<<<dim3(16, 4), 256, 0, stream>>>(pehi, pelo, 512, cmhi, cmlo, 1024, 64,
                                          wiip, isl_in_b, nullptr, 0,
                                          h0f, 0, 64LL * H, (long long)H, 1,
                                          nullptr, nullptr);
    k_g2<<<dim3(16, 4), 256, 0, stream>>>(pehi, pelo, 512, cmhi, cmlo, 1024, 64,
                                          wiop, isl_out_b, nullptr, 0,
                                          c0f, 0, 64LL * H, (long long)H, 1,
                                          nullptr, nullptr);
    k_init_split<<<R * H / 256, 256, 0, stream>>>(h0f, c0f, h1f, c1f, h016[0], h1i16);

    // ---- recurrence: dual-job fp16-single launches, 4-deep prefetch ----
    int cur = 0;
    for (int L = 0; L <= T; ++L) {
        bool has0 = (L < T), has1 = (L > 0);
        GateJob g0 = {}, g1 = {};
        if (has0) {
            g0.A1 = xs16 + (size_t)L * R * E;
            g0.A2 = h016[cur];
            g0.Bp = wg0p;
            g0.bias1 = b_ih0;  g0.bias2 = b_hh0;
            g0.cbuf = c0f;  g0.hf = h0f;
            g0.h16 = h016[cur ^ 1];
            g0.K1 = E;  g0.K2 = H;
        }
        if (has1) {
            g1.A1 = h016[cur];
            g1.A2 = (L == 1) ? h1i16 : h116all + (size_t)(L - 2) * R * H;
            g1.Bp = wg1p;
            g1.bias1 = b_ih1;  g1.bias2 = b_hh1;
            g1.cbuf = c1f;  g1.hf = h1f;
            g1.h16 = h116all + (size_t)(L - 1) * R * H;
            g1.K1 = H;  g1.K2 = H;
        }
        if (has0 && has1)
            k_gatepair<<<dim3(64, 8), 256, 0, stream>>>(g0, g1);
        else if (has0)
            k_gatepair<<<dim3(64, 4), 256, 0, stream>>>(g0, g0);
        else
            k_gatepair<<<dim3(64, 4), 256, 0, stream>>>(g1, g1);
        if (has0) cur ^= 1;
    }

    // ---- batched attention + output over all t ----
    // gamma_all = h1_all @ att_in_W^T + b  -> bf16 pair planes (mode 2)
    k_g2h<<<dim3(16, 62), 512, 0, stream>>>(h116all, 1024, h116all, 0,
                                            wgip, att_in_b, 2,
                                            nullptr, 256LL * H, 64LL * H, (long long)H,
                                            gamh, gaml);
    k_smfma<<<dim3(4, 2, B), 256, 0, stream>>>(gamh, gaml, cxh, cxl, scores);
    k_smax<<<dim3(T, B), 256, 0, stream>>>(scores, w16);
    k_ctmm<<<dim3(16, 2, B), 256, 0, stream>>>(w16, ctxT16, ct16);
    // out[t,l,b,:] = tanh([ct|h1] @ att_out_W^T + b)  (fp16 path)
    k_g2h<<<dim3(16, 62), 512, 0, stream>>>(ct16, 1024, h116all, 1024,
                                            wotp, att_out_b, 0,
                                            out, (long long)B * H,
                                            (long long)T * B * H, (long long)H,
                                            nullptr, nullptr);

    // ---- finals ----
    size_t OUTS = (size_t)L4 * T * B * H;
    size_t seg = (size_t)B * H;
    hipMemcpyAsync(out + OUTS,           h0f + 192 * H, seg * 4, hipMemcpyDeviceToDevice, stream);
    hipMemcpyAsync(out + OUTS + seg,     h1f + 192 * H, seg * 4, hipMemcpyDeviceToDevice, stream);
    hipMemcpyAsync(out + OUTS + 2 * seg, c0f + 192 * H, seg * 4, hipMemcpyDeviceToDevice, stream);
    hipMemcpyAsync(out + OUTS + 3 * seg, c1f + 192 * H, seg * 4, hipMemcpyDeviceToDevice, stream);
}

// Round 17
// 1134.968 us; speedup vs baseline: 1.0338x; 1.0012x over previous
//
#include <hip/hip_runtime.h>
#include <math.h>

#define E 512
#define H 1024
#define B 64
#define S 32
#define SRC 256
#define L4 4      // NLEV-1 levels actually processed
#define T 31      // S-1 timesteps
#define R 256     // L4*B rows (effective batch)

typedef unsigned int uint_t;
typedef unsigned short ushort_t;
typedef float f32x4_v __attribute__((ext_vector_type(4)));
typedef short bf16x8_v __attribute__((ext_vector_type(8)));
typedef _Float16 f16x8_v __attribute__((ext_vector_type(8)));

// ---------------------------------------------------------------------------
__device__ __forceinline__ void split1(float x, uint_t& h, uint_t& l) {
    uint_t u = __float_as_uint(x);
    h = u >> 16;
    float hf = __uint_as_float(u & 0xFFFF0000u);
    l = __float_as_uint(x - hf) >> 16;
}

__device__ __forceinline__ void split_quad(float4 v, uint2& hi, uint2& lo) {
    uint_t h0, h1, h2, h3, l0, l1, l2, l3;
    split1(v.x, h0, l0); split1(v.y, h1, l1);
    split1(v.z, h2, l2); split1(v.w, h3, l3);
    hi.x = h0 | (h1 << 16); hi.y = h2 | (h3 << 16);
    lo.x = l0 | (l1 << 16); lo.y = l2 | (l3 << 16);
}

__device__ __forceinline__ ushort_t f16of(float x) {
    _Float16 h = (_Float16)x;
    return *(ushort_t*)&h;
}

__device__ __forceinline__ void splitf16(float x, ushort_t& h, ushort_t& l) {
    _Float16 hh = (_Float16)x;
    float hf = (float)hh;
    _Float16 hl = (_Float16)(x - hf);
    h = *(ushort_t*)&hh;
    l = *(ushort_t*)&hl;
}

__device__ __forceinline__ void gl_lds16(const void* g, void* l) {
    __builtin_amdgcn_global_load_lds(
        (const __attribute__((address_space(1))) void*)g,
        (__attribute__((address_space(3))) void*)l, 16, 0, 0);
}

// ---------------------------------------------------------------------------
// Embeddings -> single fp16 plane: xs[t*R + l*B+b][e]
__global__ __launch_bounds__(128) void k_embed(const int* __restrict__ inputs,
                                               const float* __restrict__ embW,
                                               ushort_t* __restrict__ x16) {
    int blk = blockIdx.x;              // l*T*B + t*B + b
    int b = blk % B;
    int t = (blk / B) % T;
    int l = blk / (B * T);
    int tok = inputs[(l + 1) * B * S + b * S + t];
    const float4* src = (const float4*)(embW + (long long)tok * E);
    float4 v = src[threadIdx.x];
    uint_t w0 = f16of(v.x) | ((uint_t)f16of(v.y) << 16);
    uint_t w1 = f16of(v.z) | ((uint_t)f16of(v.w) << 16);
    size_t base = ((size_t)t * R + (size_t)l * B + b) * E + threadIdx.x * 4;
    uint2 pk = {w0, w1};
    *(uint2*)(x16 + base) = pk;
}

// ---------------------------------------------------------------------------
__global__ __launch_bounds__(128) void k_pe(const int* __restrict__ inputs,
                                            const int* __restrict__ lens,
                                            const float* __restrict__ embW,
                                            ushort_t* __restrict__ phi,
                                            ushort_t* __restrict__ plo) {
    int r = blockIdx.x;
    int l = r >> 6, b = r & 63;
    int plen = lens[l * B + b];
    int send = plen - 1;
    if (send > S) send = S;
    const int* toks = inputs + l * B * S + b * S;
    float4 acc = {0.f, 0.f, 0.f, 0.f};
    for (int s = 1; s < send; ++s) {
        int tok = toks[s];
        float4 v = ((const float4*)(embW + (long long)tok * E))[threadIdx.x];
        acc.x += v.x; acc.y += v.y; acc.z += v.z; acc.w += v.w;
    }
    const float inv = 1.f / 32.f;
    acc.x *= inv; acc.y *= inv; acc.z *= inv; acc.w *= inv;
    uint2 hi, lo; split_quad(acc, hi, lo);
    size_t base = (size_t)r * E + threadIdx.x * 4;
    *(uint2*)(phi + base) = hi;
    *(uint2*)(plo + base) = lo;
}

// ---------------------------------------------------------------------------
__global__ __launch_bounds__(256) void k_cm(const float* __restrict__ ctx,
                                            ushort_t* __restrict__ chi,
                                            ushort_t* __restrict__ clo) {
    int b = blockIdx.x;
    int j = threadIdx.x;
    const float4* c4 = (const float4*)(ctx + (size_t)b * SRC * H);
    float4 acc = {0.f, 0.f, 0.f, 0.f};
    for (int s = 0; s < SRC; ++s) {
        float4 v = c4[(size_t)s * (H / 4) + j];
        acc.x += v.x; acc.y += v.y; acc.z += v.z; acc.w += v.w;
    }
    const float inv = 1.f / (float)SRC;
    acc.x *= inv; acc.y *= inv; acc.z *= inv; acc.w *= inv;
    uint2 hi, lo; split_quad(acc, hi, lo);
    size_t base = (size_t)b * H + j * 4;
    *(uint2*)(chi + base) = hi;
    *(uint2*)(clo + base) = lo;
}

// ---------------------------------------------------------------------------
// Row-major plane splitter (contexts): bf16 hi/lo planes.
__global__ __launch_bounds__(256) void k_wsplit(
    const float* __restrict__ src1, int ld1, int o1, int Ka,
    const float* __restrict__ src2, int ld2, int o2, int Kb,
    int rowmap, ushort_t* __restrict__ dhi, ushort_t* __restrict__ dlo) {
    int n = blockIdx.x;
    int KT = Ka + Kb;
    long long r = rowmap ? ((long long)(n & 3) * H + (n >> 2)) : (long long)n;
    for (int k4 = threadIdx.x; k4 < (KT >> 2); k4 += 256) {
        int k = k4 << 2;
        float4 v = (k < Ka) ? *(const float4*)(src1 + r * ld1 + o1 + k)
                            : *(const float4*)(src2 + r * ld2 + o2 + (k - Ka));
        uint2 hi, lo; split_quad(v, hi, lo);
        size_t base = (size_t)n * KT + k;
        *(uint2*)(dhi + base) = hi;
        *(uint2*)(dlo + base) = lo;
    }
}

// ---------------------------------------------------------------------------
// Transpose + f32->fp16: ctxT[b][h][s] = f16(ctx[b][s][h]). LDS-tiled.
// grid (B, H/64, SRC/64), 256 thr.
__global__ __launch_bounds__(256) void k_ctxT(const float* __restrict__ src,
                                              ushort_t* __restrict__ dst) {
    __shared__ ushort_t tile[64][72];
    const int b = blockIdx.x, h0 = blockIdx.y * 64, s0 = blockIdx.z * 64;
    const int tid = threadIdx.x;
    for (int it = tid; it < 1024; it += 256) {      // 64 s-rows x 16 h-quads
        int s = it >> 4, ho = (it & 15) * 4;
        float4 v = *(const float4*)(src + ((size_t)b * SRC + s0 + s) * H + h0 + ho);
        ushort_t q[4] = {f16of(v.x), f16of(v.y), f16of(v.z), f16of(v.w)};
        *(uint2*)&tile[s][ho] = *(uint2*)q;
    }
    __syncthreads();
    for (int it = tid; it < 512; it += 256) {       // 64 h-rows x 8 s-octets
        int h = it >> 3, so = (it & 7) * 8;
        ushort_t vals[8];
#pragma unroll
        for (int i = 0; i < 8; ++i) vals[i] = tile[so + i][h];
        *(uint4*)(dst + ((size_t)b * H + h0 + h) * SRC + s0 + so) = *(uint4*)vals;
    }
}

// ---------------------------------------------------------------------------
// bf16 tiled split panel (init weights) — 16KB/tile.
__global__ __launch_bounds__(256) void k_wtile(
    const float* __restrict__ src1, int ld1, int o1, int Ka,
    const float* __restrict__ src2, int ld2, int o2, int Kb,
    int rowmap, unsigned char* __restrict__ panel) {
    int cb = blockIdx.x, t = blockIdx.y;
    int KT = Ka + Kb;
    int NT = KT >> 6;
    size_t obase = ((size_t)cb * NT + t) * 16384;
    int k0 = t << 6;
    for (int q = threadIdx.x; q < 512; q += 256) {
        int s = q >> 6, l = q & 63;
        int n = cb * 64 + 8 * s + (l >> 3);
        long long r = rowmap ? ((long long)(n & 3) * H + (n >> 2)) : (long long)n;
        int xorc = ((l & 7) * 16) ^ ((l >> 3) << 4);
        int ke = k0 + (xorc >> 1);
        const float* sp = (ke < Ka) ? (src1 + r * ld1 + o1 + ke)
                                    : (src2 + r * ld2 + o2 + (ke - Ka));
        float4 v01 = *(const float4*)sp;
        float4 v23 = *(const float4*)(sp + 4);
        uint2 h0, l0, h1, l1;
        split_quad(v01, h0, l0);
        split_quad(v23, h1, l1);
        uint4 hi = {h0.x, h0.y, h1.x, h1.y};
        uint4 lo = {l0.x, l0.y, l1.x, l1.y};
        *(uint4*)(panel + obase + s * 1024 + l * 16) = hi;
        *(uint4*)(panel + obase + 8192 + s * 1024 + l * 16) = lo;
    }
}

// ---------------------------------------------------------------------------
// fp16 hi/lo tiled panel — 16KB/tile.
__global__ __launch_bounds__(256) void k_wtile16(
    const float* __restrict__ src1, int ld1, int Ka,
    const float* __restrict__ src2, int ld2, int Kb,
    int rowmap, unsigned char* __restrict__ panel) {
    int cb = blockIdx.x, t = blockIdx.y;
    int KT = Ka + Kb;
    int NT = KT >> 6;
    size_t obase = ((size_t)cb * NT + t) * 16384;
    int k0 = t << 6;
    for (int q = threadIdx.x; q < 512; q += 256) {
        int s = q >> 6, l = q & 63;
        int n = cb * 64 + 8 * s + (l >> 3);
        long long r = rowmap ? ((long long)(n & 3) * H + (n >> 2)) : (long long)n;
        int xorc = ((l & 7) * 16) ^ ((l >> 3) << 4);
        int ke = k0 + (xorc >> 1);
        const float* sp = (ke < Ka) ? (src1 + r * ld1 + ke)
                                    : (src2 + r * ld2 + (ke - Ka));
        ushort_t hh[8], ll[8];
#pragma unroll
        for (int e = 0; e < 8; ++e) splitf16(sp[e], hh[e], ll[e]);
        uint4 hi = {(uint_t)hh[0] | ((uint_t)hh[1] << 16),
                    (uint_t)hh[2] | ((uint_t)hh[3] << 16),
                    (uint_t)hh[4] | ((uint_t)hh[5] << 16),
                    (uint_t)hh[6] | ((uint_t)hh[7] << 16)};
        uint4 lo = {(uint_t)ll[0] | ((uint_t)ll[1] << 16),
                    (uint_t)ll[2] | ((uint_t)ll[3] << 16),
                    (uint_t)ll[4] | ((uint_t)ll[5] << 16),
                    (uint_t)ll[6] | ((uint_t)ll[7] << 16)};
        *(uint4*)(panel + obase + s * 1024 + l * 16) = hi;
        *(uint4*)(panel + obase + 8192 + s * 1024 + l * 16) = lo;
    }
}

// ---------------------------------------------------------------------------
// fp16 SINGLE tiled panel (gate weights) — 8KB/tile, gate interleave.
__global__ __launch_bounds__(256) void k_wtile16s(
    const float* __restrict__ src1, int ld1, int Ka,
    const float* __restrict__ src2, int ld2, int Kb,
    unsigned char* __restrict__ panel) {
    int cb = blockIdx.x, t = blockIdx.y;
    int KT = Ka + Kb;
    int NT = KT >> 6;
    size_t obase = ((size_t)cb * NT + t) * 8192;
    int k0 = t << 6;
    for (int q = threadIdx.x; q < 512; q += 256) {
        int s = q >> 6, l = q & 63;
        int n = cb * 64 + 8 * s + (l >> 3);
        long long r = (long long)(n & 3) * H + (n >> 2);   // gate interleave
        int xorc = ((l & 7) * 16) ^ ((l >> 3) << 4);
        int ke = k0 + (xorc >> 1);
        const float* sp = (ke < Ka) ? (src1 + r * ld1 + ke)
                                    : (src2 + r * ld2 + (ke - Ka));
        ushort_t hh[8];
#pragma unroll
        for (int e = 0; e < 8; ++e) hh[e] = f16of(sp[e]);
        uint4 hi = {(uint_t)hh[0] | ((uint_t)hh[1] << 16),
                    (uint_t)hh[2] | ((uint_t)hh[3] << 16),
                    (uint_t)hh[4] | ((uint_t)hh[5] << 16),
                    (uint_t)hh[6] | ((uint_t)hh[7] << 16)};
        *(uint4*)(panel + obase + s * 1024 + l * 16) = hi;
    }
}

// ---------------------------------------------------------------------------
// bf16 split MFMA GEMM (init projections) — unchanged.
__global__ __launch_bounds__(256) void k_g2(
    const ushort_t* __restrict__ Ah1, const ushort_t* __restrict__ Al1, int K1,
    const ushort_t* __restrict__ Ah2, const ushort_t* __restrict__ Al2, int K2,
    int a2mod,
    const unsigned char* __restrict__ Bp,
    const float* __restrict__ bias1, const float* __restrict__ bias2,
    int mode, float* __restrict__ C,
    long long strideT, long long strideL, long long strideB, int act,
    ushort_t* __restrict__ ohi, ushort_t* __restrict__ olo) {
    __shared__ __align__(16) unsigned char lds[65536];
    const int tid = threadIdx.x;
    const int lane = tid & 63;
    const int wv = tid >> 6;
    const int wm = wv & 1, wn = wv >> 1;
    const int cblk = blockIdx.x;
    const int mblk = blockIdx.y;
    const int m0 = mblk * 64;
    const int colbase = cblk * 64;
    const int KT = K1 + K2;
    const int NT = KT >> 6;
    const int n1steps = K1 >> 6;
    const size_t pbase = (size_t)cblk * NT * 16384;

    f32x4_v zero = {0.f, 0.f, 0.f, 0.f};
    f32x4_v acc[2][2] = {{zero, zero}, {zero, zero}};
    const int xorc = ((lane & 7) * 16) ^ ((lane >> 3) << 4);
    const int rsub = lane >> 3;

    auto stage = [&](int t, int buf) {
        unsigned char* dstA = lds + buf * 16384;
        unsigned char* dstB = lds + 32768 + buf * 16384;
        {
            const ushort_t *Ph, *Pl; int lda, k0, mod;
            if (t < n1steps) { Ph = Ah1; Pl = Al1; lda = K1; k0 = t << 6; mod = 0; }
            else { Ph = Ah2; Pl = Al2; lda = K2; k0 = (t - n1steps) << 6; mod = a2mod; }
#pragma unroll
            for (int cc = 0; cc < 4; ++cc) {
                int c = wv * 4 + cc;
                int p = c >> 3, s = c & 7;
                int rr = m0 + 8 * s + rsub;
                if (mod) rr &= (mod - 1);
                const ushort_t* plane = p ? Pl : Ph;
                gl_lds16((const unsigned char*)(plane + (size_t)rr * lda + k0) + xorc,
                         dstA + c * 1024);
            }
        }
        {
            const unsigned char* tb = Bp + pbase + (size_t)t * 16384;
#pragma unroll
            for (int cc = 0; cc < 4; ++cc) {
                int c = wv * 4 + cc;
                gl_lds16(tb + c * 1024 + lane * 16, dstB + c * 1024);
            }
        }
    };
    auto compute = [&](int buf) {
        const unsigned char* Ab = lds + buf * 16384;
        const unsigned char* Bb = lds + 32768 + buf * 16384;
#pragma unroll
        for (int kf = 0; kf < 2; ++kf) {
            int colA = (kf * 64 + ((lane >> 4) * 16)) ^ ((lane & 7) << 4);
            bf16x8_v ah[2], al[2], bh[2], bl[2];
#pragma unroll
            for (int i = 0; i < 2; ++i) {
                int rowm = (wm * 2 + i) * 16 + (lane & 15);
                ah[i] = *(const bf16x8_v*)(Ab + rowm * 128 + colA);
                al[i] = *(const bf16x8_v*)(Ab + 8192 + rowm * 128 + colA);
                int rj = (wn * 2 + i) * 16 + (lane & 15);
                bh[i] = *(const bf16x8_v*)(Bb + rj * 128 + colA);
                bl[i] = *(const bf16x8_v*)(Bb + 8192 + rj * 128 + colA);
            }
            __builtin_amdgcn_s_setprio(1);
#pragma unroll
            for (int i = 0; i < 2; ++i)
#pragma unroll
                for (int j = 0; j < 2; ++j) {
                    acc[i][j] = __builtin_amdgcn_mfma_f32_16x16x32_bf16(al[i], bh[j], acc[i][j], 0, 0, 0);
                    acc[i][j] = __builtin_amdgcn_mfma_f32_16x16x32_bf16(ah[i], bl[j], acc[i][j], 0, 0, 0);
                    acc[i][j] = __builtin_amdgcn_mfma_f32_16x16x32_bf16(ah[i], bh[j], acc[i][j], 0, 0, 0);
                }
            __builtin_amdgcn_s_setprio(0);
        }
    };

    stage(0, 0);
    int cur = 0;
    for (int tt = 0; tt < NT; ++tt) {
        if (tt + 1 < NT) {
            stage(tt + 1, cur ^ 1);
            asm volatile("s_waitcnt vmcnt(8)" ::: "memory");
        } else {
            asm volatile("s_waitcnt vmcnt(0)" ::: "memory");
        }
        __builtin_amdgcn_s_barrier();
        __builtin_amdgcn_sched_barrier(0);
        compute(cur);
        __builtin_amdgcn_sched_barrier(0);
        __builtin_amdgcn_s_barrier();
        cur ^= 1;
    }

    const int l16 = lane & 15, g4 = (lane >> 4) * 4;
#pragma unroll
    for (int i = 0; i < 2; ++i) {
#pragma unroll
        for (int r = 0; r < 4; ++r) {
            int m = m0 + wm * 32 + i * 16 + g4 + r;
            long long rowoff = (long long)(m >> 8) * strideT
                             + (long long)((m >> 6) & 3) * strideL
                             + (long long)(m & 63) * strideB;
#pragma unroll
            for (int jj = 0; jj < 2; ++jj) {
                int n = colbase + wn * 32 + jj * 16 + l16;
                float v = acc[i][jj][r];
                if (mode == 0) {
                    if (bias1) v += bias1[n];
                    if (bias2) v += bias2[n];
                    if (act) v = tanhf(v);
                    C[rowoff + n] = v;
                } else {
                    uint_t hu, lu; split1(v, hu, lu);
                    ohi[rowoff + n] = (ushort_t)hu;
                    olo[rowoff + n] = (ushort_t)lu;
                }
            }
        }
    }
}

// ---------------------------------------------------------------------------
// fp16 GEMM v2: 512 thr (8 waves = 4m x 2n), tile 128m x 64n.
// A = concat fp16 single planes, B = fp16 hi/lo panel (16KB/tile).
// mode 0: C = tanh(acc + bias1), scattered. mode 2: bias + bf16 split -> ohi/olo.
__global__ __launch_bounds__(512) void k_g2h(
    const ushort_t* __restrict__ A1, int K1,
    const ushort_t* __restrict__ A2, int K2,
    const unsigned char* __restrict__ Bp,
    const float* __restrict__ bias1,
    int mode, float* __restrict__ C,
    long long strideT, long long strideL, long long strideB,
    ushort_t* __restrict__ ohi, ushort_t* __restrict__ olo) {
    __shared__ __align__(16) unsigned char lds[65536];
    const int tid = threadIdx.x;
    const int lane = tid & 63;
    const int wv = tid >> 6;            // 0..7
    const int wm = wv & 3, wn = wv >> 2;
    const int cblk = blockIdx.x;
    const int m0 = blockIdx.y * 128;
    const int colbase = cblk * 64;
    const int KT = K1 + K2;
    const int NT = KT >> 6;
    const int n1steps = K1 >> 6;
    const size_t pbase = (size_t)cblk * NT * 16384;

    f32x4_v zero = {0.f, 0.f, 0.f, 0.f};
    f32x4_v acc[2][2] = {{zero, zero}, {zero, zero}};
    const int xorc = ((lane & 7) * 16) ^ ((lane >> 3) << 4);
    const int rsub = lane >> 3;

    auto stage = [&](int t, int buf) {
        unsigned char* base = lds + buf * 32768;
        const ushort_t* Ap; int lda, k0;
        if (t < n1steps) { Ap = A1; lda = K1; k0 = t << 6; }
        else             { Ap = A2; lda = K2; k0 = (t - n1steps) << 6; }
        const unsigned char* tb = Bp + pbase + (size_t)t * 16384;
#pragma unroll
        for (int cc = 0; cc < 4; ++cc) {
            int c = wv * 4 + cc;           // 0..31
            if (c < 16) {                  // A: 16 chunks, rows m0..m0+127
                int rr = m0 + 8 * c + rsub;
                gl_lds16((const unsigned char*)(Ap + (size_t)rr * lda + k0) + xorc,
                         base + c * 1024);
            } else {                       // B hi/lo: 16 chunks, sequential panel
                int cb = c - 16;
                gl_lds16(tb + cb * 1024 + lane * 16, base + 16384 + cb * 1024);
            }
        }
    };
    auto compute = [&](int buf) {
        const unsigned char* Ab = lds + buf * 32768;
        const unsigned char* Bb = Ab + 16384;
#pragma unroll
        for (int kf = 0; kf < 2; ++kf) {
            int colA = (kf * 64 + ((lane >> 4) * 16)) ^ ((lane & 7) << 4);
            f16x8_v a[2], bh[2], bl[2];
#pragma unroll
            for (int i = 0; i < 2; ++i) {
                int rowm = wm * 32 + i * 16 + (lane & 15);     // 0..127
                a[i] = *(const f16x8_v*)(Ab + rowm * 128 + colA);
                int rj = wn * 32 + i * 16 + (lane & 15);       // 0..63
                bh[i] = *(const f16x8_v*)(Bb + rj * 128 + colA);
                bl[i] = *(const f16x8_v*)(Bb + 8192 + rj * 128 + colA);
            }
            __builtin_amdgcn_s_setprio(1);
#pragma unroll
            for (int i = 0; i < 2; ++i)
#pragma unroll
                for (int j = 0; j < 2; ++j) {
                    acc[i][j] = __builtin_amdgcn_mfma_f32_16x16x32_f16(a[i], bl[j], acc[i][j], 0, 0, 0);
                    acc[i][j] = __builtin_amdgcn_mfma_f32_16x16x32_f16(a[i], bh[j], acc[i][j], 0, 0, 0);
                }
            __builtin_amdgcn_s_setprio(0);
        }
    };

    stage(0, 0);
    int cur = 0;
    for (int tt = 0; tt < NT; ++tt) {
        if (tt + 1 < NT) {
            stage(tt + 1, cur ^ 1);
            asm volatile("s_waitcnt vmcnt(4)" ::: "memory");
        } else {
            asm volatile("s_waitcnt vmcnt(0)" ::: "memory");
        }
        __builtin_amdgcn_s_barrier();
        __builtin_amdgcn_sched_barrier(0);
        compute(cur);
        __builtin_amdgcn_sched_barrier(0);
        __builtin_amdgcn_s_barrier();
        cur ^= 1;
    }

    const int l16 = lane & 15, g4 = (lane >> 4) * 4;
#pragma unroll
    for (int i = 0; i < 2; ++i) {
#pragma unroll
        for (int r = 0; r < 4; ++r) {
            int m = m0 + wm * 32 + i * 16 + g4 + r;
            long long rowoff = (long long)(m >> 8) * strideT
                             + (long long)((m >> 6) & 3) * strideL
                             + (long long)(m & 63) * strideB;
#pragma unroll
            for (int jj = 0; jj < 2; ++jj) {
                int n = colbase + wn * 32 + jj * 16 + l16;
                float v = acc[i][jj][r] + bias1[n];
                if (mode == 0) {
                    C[rowoff + n] = tanhf(v);
                } else {
                    uint_t hu, lu; split1(v, hu, lu);
                    ohi[rowoff + n] = (ushort_t)hu;
                    olo[rowoff + n] = (ushort_t)lu;
                }
            }
        }
    }
}

// ---------------------------------------------------------------------------
// Dual-job gate GEMM + fused LSTM, fp16 single x single, 4-deep prefetch.
struct GateJob {
    const ushort_t *A1, *A2;          // fp16 planes
    const unsigned char* Bp;          // fp16 single panel
    const float *bias1, *bias2;
    float *cbuf, *hf;
    ushort_t *h16;                    // fp16 h out
    int K1, K2;
};

__global__ __launch_bounds__(256) void k_gatepair(GateJob j0, GateJob j1) {
    __shared__ __align__(16) unsigned char lds[65536];
    const bool sec = blockIdx.y >= 4;
    const ushort_t* A1v = sec ? j1.A1 : j0.A1;
    const ushort_t* A2v = sec ? j1.A2 : j0.A2;
    const unsigned char* Bp = sec ? j1.Bp : j0.Bp;
    const float* bias1  = sec ? j1.bias1 : j0.bias1;
    const float* bias2  = sec ? j1.bias2 : j0.bias2;
    float* cbuf         = sec ? j1.cbuf : j0.cbuf;
    float* hf           = sec ? j1.hf   : j0.hf;
    ushort_t* h16       = sec ? j1.h16  : j0.h16;
    const int K1        = sec ? j1.K1   : j0.K1;
    const int K2        = sec ? j1.K2   : j0.K2;

    const int tid = threadIdx.x;
    const int lane = tid & 63;
    const int wv = tid >> 6;
    const int wm = wv & 1, wn = wv >> 1;
    const int mblk = blockIdx.y & 3;
    const int cblk = blockIdx.x;
    const int m0 = mblk * 64;
    const int KT = K1 + K2;
    const int NT = KT >> 6;
    const int n1steps = K1 >> 6;
    const size_t pbase = (size_t)cblk * NT * 8192;

    f32x4_v zero = {0.f, 0.f, 0.f, 0.f};
    f32x4_v acc[2][2] = {{zero, zero}, {zero, zero}};
    const int xorc = ((lane & 7) * 16) ^ ((lane >> 3) << 4);
    const int rsub = lane >> 3;

    auto stage = [&](int t, int buf) {
        unsigned char* base = lds + buf * 16384;
        const ushort_t* Ap; int lda, k0;
        if (t < n1steps) { Ap = A1v; lda = K1; k0 = t << 6; }
        else             { Ap = A2v; lda = K2; k0 = (t - n1steps) << 6; }
        const unsigned char* tb = Bp + pbase + (size_t)t * 8192;
#pragma unroll
        for (int cc = 0; cc < 4; ++cc) {
            int c = wv * 4 + cc;           // 0..15
            if (c < 8) {
                int rr = m0 + 8 * c + rsub;
                gl_lds16((const unsigned char*)(Ap + (size_t)rr * lda + k0) + xorc,
                         base + c * 1024);
            } else {
                gl_lds16(tb + (c - 8) * 1024 + lane * 16, base + c * 1024);
            }
        }
    };
    auto compute = [&](int buf) {
        const unsigned char* Ab = lds + buf * 16384;
        const unsigned char* Bb = Ab + 8192;
#pragma unroll
        for (int kf = 0; kf < 2; ++kf) {
            int colA = (kf * 64 + ((lane >> 4) * 16)) ^ ((lane & 7) << 4);
            f16x8_v a[2], bv[2];
#pragma unroll
            for (int i = 0; i < 2; ++i) {
                int rowm = (wm * 2 + i) * 16 + (lane & 15);
                a[i] = *(const f16x8_v*)(Ab + rowm * 128 + colA);
                int rj = (wn * 2 + i) * 16 + (lane & 15);
                bv[i] = *(const f16x8_v*)(Bb + rj * 128 + colA);
            }
            __builtin_amdgcn_s_setprio(1);
#pragma unroll
            for (int i = 0; i < 2; ++i)
#pragma unroll
                for (int j = 0; j < 2; ++j)
                    acc[i][j] = __builtin_amdgcn_mfma_f32_16x16x32_f16(a[i], bv[j], acc[i][j], 0, 0, 0);
            __builtin_amdgcn_s_setprio(0);
        }
    };

    stage(0, 0);
    stage(1, 1);
    stage(2, 2);
    for (int tt = 0; tt < NT; ++tt) {
        if (tt + 3 < NT) {
            stage(tt + 3, (tt + 3) & 3);
            asm volatile("s_waitcnt vmcnt(12)" ::: "memory");
        } else if (tt + 2 < NT) {
            asm volatile("s_waitcnt vmcnt(8)" ::: "memory");
        } else if (tt + 1 < NT) {
            asm volatile("s_waitcnt vmcnt(4)" ::: "memory");
        } else {
            asm volatile("s_waitcnt vmcnt(0)" ::: "memory");
        }
        __builtin_amdgcn_s_barrier();
        __builtin_amdgcn_sched_barrier(0);
        compute(tt & 3);
        __builtin_amdgcn_sched_barrier(0);
        __builtin_amdgcn_s_barrier();
    }

    // gate tile -> LDS [64][68] f32 (overlays staging; drained)
    float* gtile = (float*)lds;
    const int l16 = lane & 15, g4 = (lane >> 4) * 4;
#pragma unroll
    for (int i = 0; i < 2; ++i)
#pragma unroll
        for (int jj = 0; jj < 2; ++jj)
#pragma unroll
            for (int r = 0; r < 4; ++r)
                gtile[(wm * 32 + i * 16 + g4 + r) * 68 + wn * 32 + jj * 16 + l16] = acc[i][jj][r];
    __syncthreads();

    int m = tid >> 2;
    int hcb = (tid & 3) * 4;
    int nh0 = cblk * 16;
#pragma unroll
    for (int e = 0; e < 4; ++e) {
        int hc = hcb + e;
        float gv[4];
#pragma unroll
        for (int q = 0; q < 4; ++q) {
            int bidx = q * H + nh0 + hc;
            gv[q] = gtile[m * 68 + hc * 4 + q] + bias1[bidx] + bias2[bidx];
        }
        size_t idx = (size_t)(m0 + m) * H + nh0 + hc;
        float cp = cbuf[idx];
        float si = 1.f / (1.f + __expf(-gv[0]));
        float sf = 1.f / (1.f + __expf(-gv[1]));
        float so = 1.f / (1.f + __expf(-gv[3]));
        float c = sf * cp + si * tanhf(gv[2]);
        float hn = so * tanhf(c);
        cbuf[idx] = c;
        hf[idx] = hn;
        h16[idx] = f16of(hn);
    }
}

// ---------------------------------------------------------------------------
// Batched score MFMA (bf16 3-term): scores[t*R+l*64+b][s] = gamma . ctx.
__global__ __launch_bounds__(256) void k_smfma(
    const ushort_t* __restrict__ gah, const ushort_t* __restrict__ gal,
    const ushort_t* __restrict__ cxh, const ushort_t* __restrict__ cxl,
    float* __restrict__ scores) {
    __shared__ __align__(16) unsigned char lds[65536];
    const int tid = threadIdx.x;
    const int lane = tid & 63;
    const int wv = tid >> 6;
    const int wm = wv & 1, wn = wv >> 1;
    const int b = blockIdx.z;
    const int m0 = blockIdx.y * 64;
    const int colbase = blockIdx.x * 64;
    const int NT = 16;

    f32x4_v zero = {0.f, 0.f, 0.f, 0.f};
    f32x4_v acc[2][2] = {{zero, zero}, {zero, zero}};
    const int xorc = ((lane & 7) * 16) ^ ((lane >> 3) << 4);
    const int rsub = lane >> 3;

    auto stage = [&](int t, int buf) {
        unsigned char* dstA = lds + buf * 16384;
        unsigned char* dstB = lds + 32768 + buf * 16384;
        int k0 = t << 6;
#pragma unroll
        for (int cc = 0; cc < 4; ++cc) {
            int c = wv * 4 + cc;
            int p = c >> 3, s = c & 7;
            int rr = m0 + 8 * s + rsub;
            int tt = rr >> 2; if (tt > 30) tt = 30;
            size_t row = (size_t)tt * R + (rr & 3) * 64 + b;
            const ushort_t* plane = p ? gal : gah;
            gl_lds16((const unsigned char*)(plane + row * H + k0) + xorc,
                     dstA + c * 1024);
        }
#pragma unroll
        for (int cc = 0; cc < 4; ++cc) {
            int c = wv * 4 + cc;
            int p = c >> 3, s = c & 7;
            int rr = colbase + 8 * s + rsub;
            const ushort_t* plane = p ? cxl : cxh;
            gl_lds16((const unsigned char*)(plane + ((size_t)b * SRC + rr) * H + k0) + xorc,
                     dstB + c * 1024);
        }
    };
    auto compute = [&](int buf) {
        const unsigned char* Ab = lds + buf * 16384;
        const unsigned char* Bb = lds + 32768 + buf * 16384;
#pragma unroll
        for (int kf = 0; kf < 2; ++kf) {
            int colA = (kf * 64 + ((lane >> 4) * 16)) ^ ((lane & 7) << 4);
            bf16x8_v ah[2], al[2], bh[2], bl[2];
#pragma unroll
            for (int i = 0; i < 2; ++i) {
                int rowm = (wm * 2 + i) * 16 + (lane & 15);
                ah[i] = *(const bf16x8_v*)(Ab + rowm * 128 + colA);
                al[i] = *(const bf16x8_v*)(Ab + 8192 + rowm * 128 + colA);
                int rj = (wn * 2 + i) * 16 + (lane & 15);
                bh[i] = *(const bf16x8_v*)(Bb + rj * 128 + colA);
                bl[i] = *(const bf16x8_v*)(Bb + 8192 + rj * 128 + colA);
            }
            __builtin_amdgcn_s_setprio(1);
#pragma unroll
            for (int i = 0; i < 2; ++i)
#pragma unroll
                for (int j = 0; j < 2; ++j) {
                    acc[i][j] = __builtin_amdgcn_mfma_f32_16x16x32_bf16(al[i], bh[j], acc[i][j], 0, 0, 0);
                    acc[i][j] = __builtin_amdgcn_mfma_f32_16x16x32_bf16(ah[i], bl[j], acc[i][j], 0, 0, 0);
                    acc[i][j] = __builtin_amdgcn_mfma_f32_16x16x32_bf16(ah[i], bh[j], acc[i][j], 0, 0, 0);
                }
            __builtin_amdgcn_s_setprio(0);
        }
    };

    stage(0, 0);
    int cur = 0;
    for (int tt = 0; tt < NT; ++tt) {
        if (tt + 1 < NT) {
            stage(tt + 1, cur ^ 1);
            asm volatile("s_waitcnt vmcnt(8)" ::: "memory");
        } else {
            asm volatile("s_waitcnt vmcnt(0)" ::: "memory");
        }
        __builtin_amdgcn_s_barrier();
        __builtin_amdgcn_sched_barrier(0);
        compute(cur);
        __builtin_amdgcn_sched_barrier(0);
        __builtin_amdgcn_s_barrier();
        cur ^= 1;
    }

    const int l16 = lane & 15, g4 = (lane >> 4) * 4;
#pragma unroll
    for (int i = 0; i < 2; ++i) {
#pragma unroll
        for (int jj = 0; jj < 2; ++jj) {
#pragma unroll
            for (int r = 0; r < 4; ++r) {
                int m = m0 + wm * 32 + i * 16 + g4 + r;
                int t = m >> 2;
                if (t < 31) {
                    size_t row = (size_t)t * R + (m & 3) * 64 + b;
                    int n = colbase + wn * 32 + jj * 16 + l16;
                    scores[row * SRC + n] = acc[i][jj][r];
                }
            }
        }
    }
}

// ---------------------------------------------------------------------------
// Softmax -> fp16 weights.
__global__ __launch_bounds__(256) void k_smax(const float* __restrict__ scores,
                                              ushort_t* __restrict__ w16) {
    int t = blockIdx.x, b = blockIdx.y;
    int l = threadIdx.x >> 6, lane = threadIdx.x & 63;
    size_t row = (size_t)t * R + l * 64 + b;
    const float* sr = scores + row * SRC;
    float v0 = sr[lane];
    float v1 = sr[lane + 64];
    float v2 = sr[lane + 128];
    float v3 = sr[lane + 192];
    float m = fmaxf(fmaxf(v0, v1), fmaxf(v2, v3));
#pragma unroll
    for (int off = 32; off >= 1; off >>= 1) m = fmaxf(m, __shfl_xor(m, off));
    float e0 = expf(v0 - m), e1 = expf(v1 - m), e2 = expf(v2 - m), e3 = expf(v3 - m);
    float sum = e0 + e1 + e2 + e3;
#pragma unroll
    for (int off = 32; off >= 1; off >>= 1) sum += __shfl_xor(sum, off);
    float inv = 1.f / sum;
    ushort_t* wr = w16 + row * SRC;
    wr[lane] = f16of(e0 * inv);
    wr[lane + 64] = f16of(e1 * inv);
    wr[lane + 128] = f16of(e2 * inv);
    wr[lane + 192] = f16of(e3 * inv);
}

// ---------------------------------------------------------------------------
// MFMA ct: ct16[row][h] = sum_s w16[row][s] * ctxT[b][h][s].
// grid (16 hblk, 2 mblk, B), 256 thr, K=256 (NT=4), fp16 single x single.
__global__ __launch_bounds__(256) void k_ctmm(
    const ushort_t* __restrict__ w16, const ushort_t* __restrict__ ctxT,
    ushort_t* __restrict__ ct16) {
    __shared__ __align__(16) unsigned char lds[32768];
    const int tid = threadIdx.x;
    const int lane = tid & 63;
    const int wv = tid >> 6;
    const int wm = wv & 1, wn = wv >> 1;
    const int b = blockIdx.z;
    const int m0 = blockIdx.y * 64;
    const int colbase = blockIdx.x * 64;
    const int NT = 4;

    f32x4_v zero = {0.f, 0.f, 0.f, 0.f};
    f32x4_v acc[2][2] = {{zero, zero}, {zero, zero}};
    const int xorc = ((lane & 7) * 16) ^ ((lane >> 3) << 4);
    const int rsub = lane >> 3;

    auto stage = [&](int t, int buf) {
        unsigned char* base = lds + buf * 16384;
        int k0 = t << 6;
#pragma unroll
        for (int cc = 0; cc < 4; ++cc) {
            int c = wv * 4 + cc;           // 0..15
            if (c < 8) {                   // A = w16, rows mapped like smfma
                int rr = m0 + 8 * c + rsub;
                int tt = rr >> 2; if (tt > 30) tt = 30;
                size_t row = (size_t)tt * R + (rr & 3) * 64 + b;
                gl_lds16((const unsigned char*)(w16 + row * SRC + k0) + xorc,
                         base + c * 1024);
            } else {                       // B = ctxT rows (h)
                int hr = colbase + 8 * (c - 8) + rsub;
                gl_lds16((const unsigned char*)(ctxT + ((size_t)b * H + hr) * SRC + k0) + xorc,
                         base + 8192 + (c - 8) * 1024);
            }
        }
    };
    auto compute = [&](int buf) {
        const unsigned char* Ab = lds + buf * 16384;
        const unsigned char* Bb = Ab + 8192;
#pragma unroll
        for (int kf = 0; kf < 2; ++kf) {
            int colA = (kf * 64 + ((lane >> 4) * 16)) ^ ((lane & 7) << 4);
            f16x8_v a[2], bv[2];
#pragma unroll
            for (int i = 0; i < 2; ++i) {
                int rowm = (wm * 2 + i) * 16 + (lane & 15);
                a[i] = *(const f16x8_v*)(Ab + rowm * 128 + colA);
                int rj = (wn * 2 + i) * 16 + (lane & 15);
                bv[i] = *(const f16x8_v*)(Bb + rj * 128 + colA);
            }
            __builtin_amdgcn_s_setprio(1);
#pragma unroll
            for (int i = 0; i < 2; ++i)
#pragma unroll
                for (int j = 0; j < 2; ++j)
                    acc[i][j] = __builtin_amdgcn_mfma_f32_16x16x32_f16(a[i], bv[j], acc[i][j], 0, 0, 0);
            __builtin_amdgcn_s_setprio(0);
        }
    };

    stage(0, 0);
    int cur = 0;
    for (int tt = 0; tt < NT; ++tt) {
        if (tt + 1 < NT) {
            stage(tt + 1, cur ^ 1);
            asm volatile("s_waitcnt vmcnt(4)" ::: "memory");
        } else {
            asm volatile("s_waitcnt vmcnt(0)" ::: "memory");
        }
        __builtin_amdgcn_s_barrier();
        __builtin_amdgcn_sched_barrier(0);
        compute(cur);
        __builtin_amdgcn_sched_barrier(0);
        __builtin_amdgcn_s_barrier();
        cur ^= 1;
    }

    const int l16 = lane & 15, g4 = (lane >> 4) * 4;
#pragma unroll
    for (int i = 0; i < 2; ++i) {
#pragma unroll
        for (int r = 0; r < 4; ++r) {
            int m = m0 + wm * 32 + i * 16 + g4 + r;
            int t = m >> 2;
            if (t < 31) {
                size_t row = (size_t)t * R + (m & 3) * 64 + b;
#pragma unroll
                for (int jj = 0; jj < 2; ++jj) {
                    int n = colbase + wn * 32 + jj * 16 + l16;
                    ct16[row * H + n] = f16of(acc[i][jj][r]);
                }
            }
        }
    }
}

// ---------------------------------------------------------------------------
__global__ __launch_bounds__(256) void k_init_split(const float* __restrict__ h0f,
                                                    const float* __restrict__ c0f,
                                                    float* __restrict__ h1f,
                                                    float* __restrict__ c1f,
                                                    ushort_t* __restrict__ h0_16,
                                                    ushort_t* __restrict__ h1i_16) {
    int idx = blockIdx.x * 256 + threadIdx.x;
    float h = h0f[idx], c = c0f[idx];
    h1f[idx] = h; c1f[idx] = c;
    ushort_t hv = f16of(h);
    h0_16[idx] = hv;
    h1i_16[idx] = hv;
}

// ---------------------------------------------------------------------------
extern "C" void kernel_launch(void* const* d_in, const int* in_sizes, int n_in,
                              void* d_out, int out_size, void* d_ws, size_t ws_size,
                              hipStream_t stream) {
    const int*   inputs     = (const int*)d_in[0];
    const int*   input_lens = (const int*)d_in[1];
    const float* contexts   = (const float*)d_in[2];
    const float* emb_W      = (const float*)d_in[3];
    const float* W_ih0      = (const float*)d_in[4];
    const float* W_hh0      = (const float*)d_in[5];
    const float* b_ih0      = (const float*)d_in[6];
    const float* b_hh0      = (const float*)d_in[7];
    const float* W_ih1      = (const float*)d_in[8];
    const float* W_hh1      = (const float*)d_in[9];
    const float* b_ih1      = (const float*)d_in[10];
    const float* b_hh1      = (const float*)d_in[11];
    const float* att_in_W   = (const float*)d_in[12];
    const float* att_in_b   = (const float*)d_in[13];
    const float* att_out_W  = (const float*)d_in[14];
    const float* att_out_b  = (const float*)d_in[15];
    const float* isl_in_W   = (const float*)d_in[16];
    const float* isl_in_b   = (const float*)d_in[17];
    const float* isl_out_W  = (const float*)d_in[18];
    const float* isl_out_b  = (const float*)d_in[19];

    float* out = (float*)d_out;

    // workspace carve (256B-aligned)
    char* p = (char*)d_ws;
    auto alloc = [&](size_t bytes) { char* r = p; p += (bytes + 255) & ~(size_t)255; return r; };
    ushort_t* xs16 = (ushort_t*)alloc((size_t)T * R * E * 2);     // fp16 x
    ushort_t* h016[2];
    h016[0] = (ushort_t*)alloc((size_t)R * H * 2);
    h016[1] = (ushort_t*)alloc((size_t)R * H * 2);
    ushort_t* h1i16 = (ushort_t*)alloc((size_t)R * H * 2);
    ushort_t* h116all = (ushort_t*)alloc((size_t)T * R * H * 2);  // fp16 h1 per t
    ushort_t* gamh = (ushort_t*)alloc((size_t)T * R * H * 2);     // gamma bf16 pair
    ushort_t* gaml = (ushort_t*)alloc((size_t)T * R * H * 2);
    ushort_t* pehi = (ushort_t*)alloc((size_t)R * E * 2);
    ushort_t* pelo = (ushort_t*)alloc((size_t)R * E * 2);
    ushort_t* cmhi = (ushort_t*)alloc((size_t)B * H * 2);
    ushort_t* cmlo = (ushort_t*)alloc((size_t)B * H * 2);
    // gate weight panels: fp16 single tiled (8KB/tile)
    unsigned char* wg0p = (unsigned char*)alloc((size_t)64 * 24 * 8192);
    unsigned char* wg1p = (unsigned char*)alloc((size_t)64 * 32 * 8192);
    // fp16 hi/lo panels: att_in (gamma), att_out
    unsigned char* wgip = (unsigned char*)alloc((size_t)16 * 16 * 16384);
    unsigned char* wotp = (unsigned char*)alloc((size_t)16 * 32 * 16384);
    // bf16 panels for init
    unsigned char* wiip = (unsigned char*)alloc((size_t)16 * 24 * 16384);
    unsigned char* wiop = (unsigned char*)alloc((size_t)16 * 24 * 16384);
    // ctx planes: bf16 pair (score pass) + fp16 transposed (ct pass)
    ushort_t* cxh = (ushort_t*)alloc((size_t)B * SRC * H * 2);
    ushort_t* cxl = (ushort_t*)alloc((size_t)B * SRC * H * 2);
    ushort_t* ctxT16 = (ushort_t*)alloc((size_t)B * SRC * H * 2);
    float* h0f = (float*)alloc((size_t)R * H * 4);
    float* h1f = (float*)alloc((size_t)R * H * 4);
    float* c0f = (float*)alloc((size_t)R * H * 4);
    float* c1f = (float*)alloc((size_t)R * H * 4);
    // post buffers
    float* scores = (float*)alloc((size_t)T * R * SRC * 4);
    ushort_t* w16 = (ushort_t*)alloc((size_t)T * R * SRC * 2);
    ushort_t* ct16 = (ushort_t*)alloc((size_t)T * R * H * 2);

    // ---- setup ----
    k_embed<<<L4 * T * B, 128, 0, stream>>>(inputs, emb_W, xs16);
    k_pe<<<R, 128, 0, stream>>>(inputs, input_lens, emb_W, pehi, pelo);
    k_cm<<<B, 256, 0, stream>>>(contexts, cmhi, cmlo);
    k_wtile16s<<<dim3(64, 24), 256, 0, stream>>>(W_ih0, 512, 512, W_hh0, 1024, 1024, wg0p);
    k_wtile16s<<<dim3(64, 32), 256, 0, stream>>>(W_ih1, 1024, 1024, W_hh1, 1024, 1024, wg1p);
    k_wtile16<<<dim3(16, 16), 256, 0, stream>>>(att_in_W, 1024, 1024, nullptr, 0, 0, 0, wgip);
    k_wtile16<<<dim3(16, 32), 256, 0, stream>>>(att_out_W, 2048, 2048, nullptr, 0, 0, 0, wotp);
    k_wtile<<<dim3(16, 24), 256, 0, stream>>>(isl_in_W, 1536, 0, 1536, nullptr, 0, 0, 0, 0, wiip);
    k_wtile<<<dim3(16, 24), 256, 0, stream>>>(isl_out_W, 1536, 1024, 512, isl_out_W, 1536, 0, 1024, 0, wiop);
    k_wsplit<<<B * SRC, 256, 0, stream>>>(contexts, 1024, 0, 1024, nullptr, 0, 0, 0, 0, cxh, cxl);
    k_ctxT<<<dim3(B, 16, 4), 256, 0, stream>>>(contexts, ctxT16);

    // init projections (bf16 path, unchanged)
    k_g2<<<dim3(16, 4), 256, 0, stream>>>(pehi, pelo, 512, cmhi, cmlo, 1024, 64,
                                          wiip, isl_in_b, nullptr, 0,
                                          h0f, 0, 64LL * H, (long long)H, 1,
                                          nullptr, nullptr);
    k_g2<<<dim3(16, 4), 256, 0, stream>>>(pehi, pelo, 512, cmhi, cmlo, 1024, 64,
                                          wiop, isl_out_b, nullptr, 0,
                                          c0f, 0, 64LL * H, (long long)H, 1,
                                          nullptr, nullptr);
    k_init_split<<<R * H / 256, 256, 0, stream>>>(h0f, c0f, h1f, c1f, h016[0], h1i16);

    // ---- recurrence: dual-job fp16-single launches, 4-deep prefetch ----
    int cur = 0;
    for (int L = 0; L <= T; ++L) {
        bool has0 = (L < T), has1 = (L > 0);
        GateJob g0 = {}, g1 = {};
        if (has0) {
            g0.A1 = xs16 + (size_t)L * R * E;
            g0.A2 = h016[cur];
            g0.Bp = wg0p;
            g0.bias1 = b_ih0;  g0.bias2 = b_hh0;
            g0.cbuf = c0f;  g0.hf = h0f;
            g0.h16 = h016[cur ^ 1];
            g0.K1 = E;  g0.K2 = H;
        }
        if (has1) {
            g1.A1 = h016[cur];
            g1.A2 = (L == 1) ? h1i16 : h116all + (size_t)(L - 2) * R * H;
            g1.Bp = wg1p;
            g1.bias1 = b_ih1;  g1.bias2 = b_hh1;
            g1.cbuf = c1f;  g1.hf = h1f;
            g1.h16 = h116all + (size_t)(L - 1) * R * H;
            g1.K1 = H;  g1.K2 = H;
        }
        if (has0 && has1)
            k_gatepair<<<dim3(64, 8), 256, 0, stream>>>(g0, g1);
        else if (has0)
            k_gatepair<<<dim3(64, 4), 256, 0, stream>>>(g0, g0);
        else
            k_gatepair<<<dim3(64, 4), 256, 0, stream>>>(g1, g1);
        if (has0) cur ^= 1;
    }

    // ---- batched attention + output over all t ----
    // gamma_all = h1_all @ att_in_W^T + b  -> bf16 pair planes (mode 2)
    k_g2h<<<dim3(16, 62), 512, 0, stream>>>(h116all, 1024, h116all, 0,
                                            wgip, att_in_b, 2,
                                            nullptr, 256LL * H, 64LL * H, (long long)H,
                                            gamh, gaml);
    k_smfma<<<dim3(4, 2, B), 256, 0, stream>>>(gamh, gaml, cxh, cxl, scores);
    k_smax<<<dim3(T, B), 256, 0, stream>>>(scores, w16);
    k_ctmm<<<dim3(16, 2, B), 256, 0, stream>>>(w16, ctxT16, ct16);
    // out[t,l,b,:] = tanh([ct|h1] @ att_out_W^T + b)  (fp16 path)
    k_g2h<<<dim3(16, 62), 512, 0, stream>>>(ct16, 1024, h116all, 1024,
                                            wotp, att_out_b, 0,
                                            out, (long long)B * H,
                                            (long long)T * B * H, (long long)H,
                                            nullptr, nullptr);

    // ---- finals ----
    size_t OUTS = (size_t)L4 * T * B * H;
    size_t seg = (size_t)B * H;
    hipMemcpyAsync(out + OUTS,           h0f + 192 * H, seg * 4, hipMemcpyDeviceToDevice, stream);
    hipMemcpyAsync(out + OUTS + seg,     h1f + 192 * H, seg * 4, hipMemcpyDeviceToDevice, stream);
    hipMemcpyAsync(out + OUTS + 2 * seg, c0f + 192 * H, seg * 4, hipMemcpyDeviceToDevice, stream);
    hipMemcpyAsync(out + OUTS + 3 * seg, c1f + 192 * H, seg * 4, hipMemcpyDeviceToDevice, stream);
}

// Round 19
// 1133.565 us; speedup vs baseline: 1.0351x; 1.0012x over previous
//
#include <hip/hip_runtime.h>
#include <math.h>

#define E 512
#define H 1024
#define B 64
#define S 32
#define SRC 256
#define L4 4      // NLEV-1 levels actually processed
#define T 31      // S-1 timesteps
#define R 256     // L4*B rows (effective batch)

typedef unsigned int uint_t;
typedef unsigned short ushort_t;
typedef float f32x4_v __attribute__((ext_vector_type(4)));
typedef short bf16x8_v __attribute__((ext_vector_type(8)));
typedef _Float16 f16x8_v __attribute__((ext_vector_type(8)));

// ---------------------------------------------------------------------------
__device__ __forceinline__ void split1(float x, uint_t& h, uint_t& l) {
    uint_t u = __float_as_uint(x);
    h = u >> 16;
    float hf = __uint_as_float(u & 0xFFFF0000u);
    l = __float_as_uint(x - hf) >> 16;
}

__device__ __forceinline__ void split_quad(float4 v, uint2& hi, uint2& lo) {
    uint_t h0, h1, h2, h3, l0, l1, l2, l3;
    split1(v.x, h0, l0); split1(v.y, h1, l1);
    split1(v.z, h2, l2); split1(v.w, h3, l3);
    hi.x = h0 | (h1 << 16); hi.y = h2 | (h3 << 16);
    lo.x = l0 | (l1 << 16); lo.y = l2 | (l3 << 16);
}

__device__ __forceinline__ ushort_t f16of(float x) {
    _Float16 h = (_Float16)x;
    return *(ushort_t*)&h;
}

__device__ __forceinline__ void splitf16(float x, ushort_t& h, ushort_t& l) {
    _Float16 hh = (_Float16)x;
    float hf = (float)hh;
    _Float16 hl = (_Float16)(x - hf);
    h = *(ushort_t*)&hh;
    l = *(ushort_t*)&hl;
}

__device__ __forceinline__ void gl_lds16(const void* g, void* l) {
    __builtin_amdgcn_global_load_lds(
        (const __attribute__((address_space(1))) void*)g,
        (__attribute__((address_space(3))) void*)l, 16, 0, 0);
}

// ---------------------------------------------------------------------------
// Embeddings -> single fp16 plane: xs[t*R + l*B+b][e]
__global__ __launch_bounds__(128) void k_embed(const int* __restrict__ inputs,
                                               const float* __restrict__ embW,
                                               ushort_t* __restrict__ x16) {
    int blk = blockIdx.x;              // l*T*B + t*B + b
    int b = blk % B;
    int t = (blk / B) % T;
    int l = blk / (B * T);
    int tok = inputs[(l + 1) * B * S + b * S + t];
    const float4* src = (const float4*)(embW + (long long)tok * E);
    float4 v = src[threadIdx.x];
    uint_t w0 = f16of(v.x) | ((uint_t)f16of(v.y) << 16);
    uint_t w1 = f16of(v.z) | ((uint_t)f16of(v.w) << 16);
    size_t base = ((size_t)t * R + (size_t)l * B + b) * E + threadIdx.x * 4;
    uint2 pk = {w0, w1};
    *(uint2*)(x16 + base) = pk;
}

// ---------------------------------------------------------------------------
__global__ __launch_bounds__(128) void k_pe(const int* __restrict__ inputs,
                                            const int* __restrict__ lens,
                                            const float* __restrict__ embW,
                                            ushort_t* __restrict__ phi,
                                            ushort_t* __restrict__ plo) {
    int r = blockIdx.x;
    int l = r >> 6, b = r & 63;
    int plen = lens[l * B + b];
    int send = plen - 1;
    if (send > S) send = S;
    const int* toks = inputs + l * B * S + b * S;
    float4 acc = {0.f, 0.f, 0.f, 0.f};
    for (int s = 1; s < send; ++s) {
        int tok = toks[s];
        float4 v = ((const float4*)(embW + (long long)tok * E))[threadIdx.x];
        acc.x += v.x; acc.y += v.y; acc.z += v.z; acc.w += v.w;
    }
    const float inv = 1.f / 32.f;
    acc.x *= inv; acc.y *= inv; acc.z *= inv; acc.w *= inv;
    uint2 hi, lo; split_quad(acc, hi, lo);
    size_t base = (size_t)r * E + threadIdx.x * 4;
    *(uint2*)(phi + base) = hi;
    *(uint2*)(plo + base) = lo;
}

// ---------------------------------------------------------------------------
__global__ __launch_bounds__(256) void k_cm(const float* __restrict__ ctx,
                                            ushort_t* __restrict__ chi,
                                            ushort_t* __restrict__ clo) {
    int b = blockIdx.x;
    int j = threadIdx.x;
    const float4* c4 = (const float4*)(ctx + (size_t)b * SRC * H);
    float4 acc = {0.f, 0.f, 0.f, 0.f};
    for (int s = 0; s < SRC; ++s) {
        float4 v = c4[(size_t)s * (H / 4) + j];
        acc.x += v.x; acc.y += v.y; acc.z += v.z; acc.w += v.w;
    }
    const float inv = 1.f / (float)SRC;
    acc.x *= inv; acc.y *= inv; acc.z *= inv; acc.w *= inv;
    uint2 hi, lo; split_quad(acc, hi, lo);
    size_t base = (size_t)b * H + j * 4;
    *(uint2*)(chi + base) = hi;
    *(uint2*)(clo + base) = lo;
}

// ---------------------------------------------------------------------------
// Row-major plane splitter (contexts): bf16 hi/lo planes.
__global__ __launch_bounds__(256) void k_wsplit(
    const float* __restrict__ src1, int ld1, int o1, int Ka,
    const float* __restrict__ src2, int ld2, int o2, int Kb,
    int rowmap, ushort_t* __restrict__ dhi, ushort_t* __restrict__ dlo) {
    int n = blockIdx.x;
    int KT = Ka + Kb;
    long long r = rowmap ? ((long long)(n & 3) * H + (n >> 2)) : (long long)n;
    for (int k4 = threadIdx.x; k4 < (KT >> 2); k4 += 256) {
        int k = k4 << 2;
        float4 v = (k < Ka) ? *(const float4*)(src1 + r * ld1 + o1 + k)
                            : *(const float4*)(src2 + r * ld2 + o2 + (k - Ka));
        uint2 hi, lo; split_quad(v, hi, lo);
        size_t base = (size_t)n * KT + k;
        *(uint2*)(dhi + base) = hi;
        *(uint2*)(dlo + base) = lo;
    }
}

// ---------------------------------------------------------------------------
// Transpose + f32->fp16: ctxT[b][h][s] = f16(ctx[b][s][h]). LDS-tiled.
// grid (B, H/64, SRC/64), 256 thr.
__global__ __launch_bounds__(256) void k_ctxT(const float* __restrict__ src,
                                              ushort_t* __restrict__ dst) {
    __shared__ ushort_t tile[64][72];
    const int b = blockIdx.x, h0 = blockIdx.y * 64, s0 = blockIdx.z * 64;
    const int tid = threadIdx.x;
    for (int it = tid; it < 1024; it += 256) {      // 64 s-rows x 16 h-quads
        int s = it >> 4, ho = (it & 15) * 4;
        float4 v = *(const float4*)(src + ((size_t)b * SRC + s0 + s) * H + h0 + ho);
        ushort_t q[4] = {f16of(v.x), f16of(v.y), f16of(v.z), f16of(v.w)};
        *(uint2*)&tile[s][ho] = *(uint2*)q;
    }
    __syncthreads();
    for (int it = tid; it < 512; it += 256) {       // 64 h-rows x 8 s-octets
        int h = it >> 3, so = (it & 7) * 8;
        ushort_t vals[8];
#pragma unroll
        for (int i = 0; i < 8; ++i) vals[i] = tile[so + i][h];
        *(uint4*)(dst + ((size_t)b * H + h0 + h) * SRC + s0 + so) = *(uint4*)vals;
    }
}

// ---------------------------------------------------------------------------
// bf16 tiled split panel (init weights) — 16KB/tile.
__global__ __launch_bounds__(256) void k_wtile(
    const float* __restrict__ src1, int ld1, int o1, int Ka,
    const float* __restrict__ src2, int ld2, int o2, int Kb,
    int rowmap, unsigned char* __restrict__ panel) {
    int cb = blockIdx.x, t = blockIdx.y;
    int KT = Ka + Kb;
    int NT = KT >> 6;
    size_t obase = ((size_t)cb * NT + t) * 16384;
    int k0 = t << 6;
    for (int q = threadIdx.x; q < 512; q += 256) {
        int s = q >> 6, l = q & 63;
        int n = cb * 64 + 8 * s + (l >> 3);
        long long r = rowmap ? ((long long)(n & 3) * H + (n >> 2)) : (long long)n;
        int xorc = ((l & 7) * 16) ^ ((l >> 3) << 4);
        int ke = k0 + (xorc >> 1);
        const float* sp = (ke < Ka) ? (src1 + r * ld1 + o1 + ke)
                                    : (src2 + r * ld2 + o2 + (ke - Ka));
        float4 v01 = *(const float4*)sp;
        float4 v23 = *(const float4*)(sp + 4);
        uint2 h0, l0, h1, l1;
        split_quad(v01, h0, l0);
        split_quad(v23, h1, l1);
        uint4 hi = {h0.x, h0.y, h1.x, h1.y};
        uint4 lo = {l0.x, l0.y, l1.x, l1.y};
        *(uint4*)(panel + obase + s * 1024 + l * 16) = hi;
        *(uint4*)(panel + obase + 8192 + s * 1024 + l * 16) = lo;
    }
}

// ---------------------------------------------------------------------------
// fp16 hi/lo tiled panel — 16KB/tile.
__global__ __launch_bounds__(256) void k_wtile16(
    const float* __restrict__ src1, int ld1, int Ka,
    const float* __restrict__ src2, int ld2, int Kb,
    int rowmap, unsigned char* __restrict__ panel) {
    int cb = blockIdx.x, t = blockIdx.y;
    int KT = Ka + Kb;
    int NT = KT >> 6;
    size_t obase = ((size_t)cb * NT + t) * 16384;
    int k0 = t << 6;
    for (int q = threadIdx.x; q < 512; q += 256) {
        int s = q >> 6, l = q & 63;
        int n = cb * 64 + 8 * s + (l >> 3);
        long long r = rowmap ? ((long long)(n & 3) * H + (n >> 2)) : (long long)n;
        int xorc = ((l & 7) * 16) ^ ((l >> 3) << 4);
        int ke = k0 + (xorc >> 1);
        const float* sp = (ke < Ka) ? (src1 + r * ld1 + ke)
                                    : (src2 + r * ld2 + (ke - Ka));
        ushort_t hh[8], ll[8];
#pragma unroll
        for (int e = 0; e < 8; ++e) splitf16(sp[e], hh[e], ll[e]);
        uint4 hi = {(uint_t)hh[0] | ((uint_t)hh[1] << 16),
                    (uint_t)hh[2] | ((uint_t)hh[3] << 16),
                    (uint_t)hh[4] | ((uint_t)hh[5] << 16),
                    (uint_t)hh[6] | ((uint_t)hh[7] << 16)};
        uint4 lo = {(uint_t)ll[0] | ((uint_t)ll[1] << 16),
                    (uint_t)ll[2] | ((uint_t)ll[3] << 16),
                    (uint_t)ll[4] | ((uint_t)ll[5] << 16),
                    (uint_t)ll[6] | ((uint_t)ll[7] << 16)};
        *(uint4*)(panel + obase + s * 1024 + l * 16) = hi;
        *(uint4*)(panel + obase + 8192 + s * 1024 + l * 16) = lo;
    }
}

// ---------------------------------------------------------------------------
// fp16 SINGLE tiled panel (gate weights) — 8KB/tile, gate interleave.
__global__ __launch_bounds__(256) void k_wtile16s(
    const float* __restrict__ src1, int ld1, int Ka,
    const float* __restrict__ src2, int ld2, int Kb,
    unsigned char* __restrict__ panel) {
    int cb = blockIdx.x, t = blockIdx.y;
    int KT = Ka + Kb;
    int NT = KT >> 6;
    size_t obase = ((size_t)cb * NT + t) * 8192;
    int k0 = t << 6;
    for (int q = threadIdx.x; q < 512; q += 256) {
        int s = q >> 6, l = q & 63;
        int n = cb * 64 + 8 * s + (l >> 3);
        long long r = (long long)(n & 3) * H + (n >> 2);   // gate interleave
        int xorc = ((l & 7) * 16) ^ ((l >> 3) << 4);
        int ke = k0 + (xorc >> 1);
        const float* sp = (ke < Ka) ? (src1 + r * ld1 + ke)
                                    : (src2 + r * ld2 + (ke - Ka));
        ushort_t hh[8];
#pragma unroll
        for (int e = 0; e < 8; ++e) hh[e] = f16of(sp[e]);
        uint4 hi = {(uint_t)hh[0] | ((uint_t)hh[1] << 16),
                    (uint_t)hh[2] | ((uint_t)hh[3] << 16),
                    (uint_t)hh[4] | ((uint_t)hh[5] << 16),
                    (uint_t)hh[6] | ((uint_t)hh[7] << 16)};
        *(uint4*)(panel + obase + s * 1024 + l * 16) = hi;
    }
}

// ---------------------------------------------------------------------------
// bf16 split MFMA GEMM (init projections) — unchanged.
__global__ __launch_bounds__(256) void k_g2(
    const ushort_t* __restrict__ Ah1, const ushort_t* __restrict__ Al1, int K1,
    const ushort_t* __restrict__ Ah2, const ushort_t* __restrict__ Al2, int K2,
    int a2mod,
    const unsigned char* __restrict__ Bp,
    const float* __restrict__ bias1, const float* __restrict__ bias2,
    int mode, float* __restrict__ C,
    long long strideT, long long strideL, long long strideB, int act,
    ushort_t* __restrict__ ohi, ushort_t* __restrict__ olo) {
    __shared__ __align__(16) unsigned char lds[65536];
    const int tid = threadIdx.x;
    const int lane = tid & 63;
    const int wv = tid >> 6;
    const int wm = wv & 1, wn = wv >> 1;
    const int cblk = blockIdx.x;
    const int mblk = blockIdx.y;
    const int m0 = mblk * 64;
    const int colbase = cblk * 64;
    const int KT = K1 + K2;
    const int NT = KT >> 6;
    const int n1steps = K1 >> 6;
    const size_t pbase = (size_t)cblk * NT * 16384;

    f32x4_v zero = {0.f, 0.f, 0.f, 0.f};
    f32x4_v acc[2][2] = {{zero, zero}, {zero, zero}};
    const int xorc = ((lane & 7) * 16) ^ ((lane >> 3) << 4);
    const int rsub = lane >> 3;

    auto stage = [&](int t, int buf) {
        unsigned char* dstA = lds + buf * 16384;
        unsigned char* dstB = lds + 32768 + buf * 16384;
        {
            const ushort_t *Ph, *Pl; int lda, k0, mod;
            if (t < n1steps) { Ph = Ah1; Pl = Al1; lda = K1; k0 = t << 6; mod = 0; }
            else { Ph = Ah2; Pl = Al2; lda = K2; k0 = (t - n1steps) << 6; mod = a2mod; }
#pragma unroll
            for (int cc = 0; cc < 4; ++cc) {
                int c = wv * 4 + cc;
                int p = c >> 3, s = c & 7;
                int rr = m0 + 8 * s + rsub;
                if (mod) rr &= (mod - 1);
                const ushort_t* plane = p ? Pl : Ph;
                gl_lds16((const unsigned char*)(plane + (size_t)rr * lda + k0) + xorc,
                         dstA + c * 1024);
            }
        }
        {
            const unsigned char* tb = Bp + pbase + (size_t)t * 16384;
#pragma unroll
            for (int cc = 0; cc < 4; ++cc) {
                int c = wv * 4 + cc;
                gl_lds16(tb + c * 1024 + lane * 16, dstB + c * 1024);
            }
        }
    };
    auto compute = [&](int buf) {
        const unsigned char* Ab = lds + buf * 16384;
        const unsigned char* Bb = lds + 32768 + buf * 16384;
#pragma unroll
        for (int kf = 0; kf < 2; ++kf) {
            int colA = (kf * 64 + ((lane >> 4) * 16)) ^ ((lane & 7) << 4);
            bf16x8_v ah[2], al[2], bh[2], bl[2];
#pragma unroll
            for (int i = 0; i < 2; ++i) {
                int rowm = (wm * 2 + i) * 16 + (lane & 15);
                ah[i] = *(const bf16x8_v*)(Ab + rowm * 128 + colA);
                al[i] = *(const bf16x8_v*)(Ab + 8192 + rowm * 128 + colA);
                int rj = (wn * 2 + i) * 16 + (lane & 15);
                bh[i] = *(const bf16x8_v*)(Bb + rj * 128 + colA);
                bl[i] = *(const bf16x8_v*)(Bb + 8192 + rj * 128 + colA);
            }
            __builtin_amdgcn_s_setprio(1);
#pragma unroll
            for (int i = 0; i < 2; ++i)
#pragma unroll
                for (int j = 0; j < 2; ++j) {
                    acc[i][j] = __builtin_amdgcn_mfma_f32_16x16x32_bf16(al[i], bh[j], acc[i][j], 0, 0, 0);
                    acc[i][j] = __builtin_amdgcn_mfma_f32_16x16x32_bf16(ah[i], bl[j], acc[i][j], 0, 0, 0);
                    acc[i][j] = __builtin_amdgcn_mfma_f32_16x16x32_bf16(ah[i], bh[j], acc[i][j], 0, 0, 0);
                }
            __builtin_amdgcn_s_setprio(0);
        }
    };

    stage(0, 0);
    int cur = 0;
    for (int tt = 0; tt < NT; ++tt) {
        if (tt + 1 < NT) {
            stage(tt + 1, cur ^ 1);
            asm volatile("s_waitcnt vmcnt(8)" ::: "memory");
        } else {
            asm volatile("s_waitcnt vmcnt(0)" ::: "memory");
        }
        __builtin_amdgcn_s_barrier();
        __builtin_amdgcn_sched_barrier(0);
        compute(cur);
        __builtin_amdgcn_sched_barrier(0);
        __builtin_amdgcn_s_barrier();
        cur ^= 1;
    }

    const int l16 = lane & 15, g4 = (lane >> 4) * 4;
#pragma unroll
    for (int i = 0; i < 2; ++i) {
#pragma unroll
        for (int r = 0; r < 4; ++r) {
            int m = m0 + wm * 32 + i * 16 + g4 + r;
            long long rowoff = (long long)(m >> 8) * strideT
                             + (long long)((m >> 6) & 3) * strideL
                             + (long long)(m & 63) * strideB;
#pragma unroll
            for (int jj = 0; jj < 2; ++jj) {
                int n = colbase + wn * 32 + jj * 16 + l16;
                float v = acc[i][jj][r];
                if (mode == 0) {
                    if (bias1) v += bias1[n];
                    if (bias2) v += bias2[n];
                    if (act) v = tanhf(v);
                    C[rowoff + n] = v;
                } else {
                    uint_t hu, lu; split1(v, hu, lu);
                    ohi[rowoff + n] = (ushort_t)hu;
                    olo[rowoff + n] = (ushort_t)lu;
                }
            }
        }
    }
}

// ---------------------------------------------------------------------------
// fp16 GEMM v2: 512 thr (8 waves = 4m x 2n), tile 128m x 64n.
// A = concat fp16 single planes, B = fp16 hi/lo panel (16KB/tile).
// mode 0: C = tanh(acc + bias1), scattered. mode 2: bias + bf16 split -> ohi/olo.
__global__ __launch_bounds__(512) void k_g2h(
    const ushort_t* __restrict__ A1, int K1,
    const ushort_t* __restrict__ A2, int K2,
    const unsigned char* __restrict__ Bp,
    const float* __restrict__ bias1,
    int mode, float* __restrict__ C,
    long long strideT, long long strideL, long long strideB,
    ushort_t* __restrict__ ohi, ushort_t* __restrict__ olo) {
    __shared__ __align__(16) unsigned char lds[65536];
    const int tid = threadIdx.x;
    const int lane = tid & 63;
    const int wv = tid >> 6;            // 0..7
    const int wm = wv & 3, wn = wv >> 2;
    const int cblk = blockIdx.x;
    const int m0 = blockIdx.y * 128;
    const int colbase = cblk * 64;
    const int KT = K1 + K2;
    const int NT = KT >> 6;
    const int n1steps = K1 >> 6;
    const size_t pbase = (size_t)cblk * NT * 16384;

    f32x4_v zero = {0.f, 0.f, 0.f, 0.f};
    f32x4_v acc[2][2] = {{zero, zero}, {zero, zero}};
    const int xorc = ((lane & 7) * 16) ^ ((lane >> 3) << 4);
    const int rsub = lane >> 3;

    auto stage = [&](int t, int buf) {
        unsigned char* base = lds + buf * 32768;
        const ushort_t* Ap; int lda, k0;
        if (t < n1steps) { Ap = A1; lda = K1; k0 = t << 6; }
        else             { Ap = A2; lda = K2; k0 = (t - n1steps) << 6; }
        const unsigned char* tb = Bp + pbase + (size_t)t * 16384;
#pragma unroll
        for (int cc = 0; cc < 4; ++cc) {
            int c = wv * 4 + cc;           // 0..31
            if (c < 16) {                  // A: 16 chunks, rows m0..m0+127
                int rr = m0 + 8 * c + rsub;
                gl_lds16((const unsigned char*)(Ap + (size_t)rr * lda + k0) + xorc,
                         base + c * 1024);
            } else {                       // B hi/lo: 16 chunks, sequential panel
                int cb = c - 16;
                gl_lds16(tb + cb * 1024 + lane * 16, base + 16384 + cb * 1024);
            }
        }
    };
    auto compute = [&](int buf) {
        const unsigned char* Ab = lds + buf * 32768;
        const unsigned char* Bb = Ab + 16384;
#pragma unroll
        for (int kf = 0; kf < 2; ++kf) {
            int colA = (kf * 64 + ((lane >> 4) * 16)) ^ ((lane & 7) << 4);
            f16x8_v a[2], bh[2], bl[2];
#pragma unroll
            for (int i = 0; i < 2; ++i) {
                int rowm = wm * 32 + i * 16 + (lane & 15);     // 0..127
                a[i] = *(const f16x8_v*)(Ab + rowm * 128 + colA);
                int rj = wn * 32 + i * 16 + (lane & 15);       // 0..63
                bh[i] = *(const f16x8_v*)(Bb + rj * 128 + colA);
                bl[i] = *(const f16x8_v*)(Bb + 8192 + rj * 128 + colA);
            }
            __builtin_amdgcn_s_setprio(1);
#pragma unroll
            for (int i = 0; i < 2; ++i)
#pragma unroll
                for (int j = 0; j < 2; ++j) {
                    acc[i][j] = __builtin_amdgcn_mfma_f32_16x16x32_f16(a[i], bl[j], acc[i][j], 0, 0, 0);
                    acc[i][j] = __builtin_amdgcn_mfma_f32_16x16x32_f16(a[i], bh[j], acc[i][j], 0, 0, 0);
                }
            __builtin_amdgcn_s_setprio(0);
        }
    };

    stage(0, 0);
    int cur = 0;
    for (int tt = 0; tt < NT; ++tt) {
        if (tt + 1 < NT) {
            stage(tt + 1, cur ^ 1);
            asm volatile("s_waitcnt vmcnt(4)" ::: "memory");
        } else {
            asm volatile("s_waitcnt vmcnt(0)" ::: "memory");
        }
        __builtin_amdgcn_s_barrier();
        __builtin_amdgcn_sched_barrier(0);
        compute(cur);
        __builtin_amdgcn_sched_barrier(0);
        __builtin_amdgcn_s_barrier();
        cur ^= 1;
    }

    const int l16 = lane & 15, g4 = (lane >> 4) * 4;
#pragma unroll
    for (int i = 0; i < 2; ++i) {
#pragma unroll
        for (int r = 0; r < 4; ++r) {
            int m = m0 + wm * 32 + i * 16 + g4 + r;
            long long rowoff = (long long)(m >> 8) * strideT
                             + (long long)((m >> 6) & 3) * strideL
                             + (long long)(m & 63) * strideB;
#pragma unroll
            for (int jj = 0; jj < 2; ++jj) {
                int n = colbase + wn * 32 + jj * 16 + l16;
                float v = acc[i][jj][r] + bias1[n];
                if (mode == 0) {
                    C[rowoff + n] = tanhf(v);
                } else {
                    uint_t hu, lu; split1(v, hu, lu);
                    ohi[rowoff + n] = (ushort_t)hu;
                    olo[rowoff + n] = (ushort_t)lu;
                }
            }
        }
    }
}

// ---------------------------------------------------------------------------
// Dual-job gate GEMM + fused LSTM, fp16 single x single, 4-deep prefetch.
struct GateJob {
    const ushort_t *A1, *A2;          // fp16 planes
    const unsigned char* Bp;          // fp16 single panel
    const float *bias1, *bias2;
    float *cbuf, *hf;
    ushort_t *h16;                    // fp16 h out
    int K1, K2;
};

__global__ __launch_bounds__(256) void k_gatepair(GateJob j0, GateJob j1) {
    __shared__ __align__(16) unsigned char lds[65536];
    const bool sec = blockIdx.y >= 4;
    const ushort_t* A1v = sec ? j1.A1 : j0.A1;
    const ushort_t* A2v = sec ? j1.A2 : j0.A2;
    const unsigned char* Bp = sec ? j1.Bp : j0.Bp;
    const float* bias1  = sec ? j1.bias1 : j0.bias1;
    const float* bias2  = sec ? j1.bias2 : j0.bias2;
    float* cbuf         = sec ? j1.cbuf : j0.cbuf;
    float* hf           = sec ? j1.hf   : j0.hf;
    ushort_t* h16       = sec ? j1.h16  : j0.h16;
    const int K1        = sec ? j1.K1   : j0.K1;
    const int K2        = sec ? j1.K2   : j0.K2;

    const int tid = threadIdx.x;
    const int lane = tid & 63;
    const int wv = tid >> 6;
    const int wm = wv & 1, wn = wv >> 1;
    const int mblk = blockIdx.y & 3;
    const int cblk = blockIdx.x;
    const int m0 = mblk * 64;
    const int KT = K1 + K2;
    const int NT = KT >> 6;
    const int n1steps = K1 >> 6;
    const size_t pbase = (size_t)cblk * NT * 8192;

    f32x4_v zero = {0.f, 0.f, 0.f, 0.f};
    f32x4_v acc[2][2] = {{zero, zero}, {zero, zero}};
    const int xorc = ((lane & 7) * 16) ^ ((lane >> 3) << 4);
    const int rsub = lane >> 3;

    auto stage = [&](int t, int buf) {
        unsigned char* base = lds + buf * 16384;
        const ushort_t* Ap; int lda, k0;
        if (t < n1steps) { Ap = A1v; lda = K1; k0 = t << 6; }
        else             { Ap = A2v; lda = K2; k0 = (t - n1steps) << 6; }
        const unsigned char* tb = Bp + pbase + (size_t)t * 8192;
#pragma unroll
        for (int cc = 0; cc < 4; ++cc) {
            int c = wv * 4 + cc;           // 0..15
            if (c < 8) {
                int rr = m0 + 8 * c + rsub;
                gl_lds16((const unsigned char*)(Ap + (size_t)rr * lda + k0) + xorc,
                         base + c * 1024);
            } else {
                gl_lds16(tb + (c - 8) * 1024 + lane * 16, base + c * 1024);
            }
        }
    };
    auto compute = [&](int buf) {
        const unsigned char* Ab = lds + buf * 16384;
        const unsigned char* Bb = Ab + 8192;
#pragma unroll
        for (int kf = 0; kf < 2; ++kf) {
            int colA = (kf * 64 + ((lane >> 4) * 16)) ^ ((lane & 7) << 4);
            f16x8_v a[2], bv[2];
#pragma unroll
            for (int i = 0; i < 2; ++i) {
                int rowm = (wm * 2 + i) * 16 + (lane & 15);
                a[i] = *(const f16x8_v*)(Ab + rowm * 128 + colA);
                int rj = (wn * 2 + i) * 16 + (lane & 15);
                bv[i] = *(const f16x8_v*)(Bb + rj * 128 + colA);
            }
            __builtin_amdgcn_s_setprio(1);
#pragma unroll
            for (int i = 0; i < 2; ++i)
#pragma unroll
                for (int j = 0; j < 2; ++j)
                    acc[i][j] = __builtin_amdgcn_mfma_f32_16x16x32_f16(a[i], bv[j], acc[i][j], 0, 0, 0);
            __builtin_amdgcn_s_setprio(0);
        }
    };

    stage(0, 0);
    stage(1, 1);
    stage(2, 2);
    for (int tt = 0; tt < NT; ++tt) {
        if (tt + 3 < NT) {
            stage(tt + 3, (tt + 3) & 3);
            asm volatile("s_waitcnt vmcnt(12)" ::: "memory");
        } else if (tt + 2 < NT) {
            asm volatile("s_waitcnt vmcnt(8)" ::: "memory");
        } else if (tt + 1 < NT) {
            asm volatile("s_waitcnt vmcnt(4)" ::: "memory");
        } else {
            asm volatile("s_waitcnt vmcnt(0)" ::: "memory");
        }
        __builtin_amdgcn_s_barrier();
        __builtin_amdgcn_sched_barrier(0);
        compute(tt & 3);
        __builtin_amdgcn_sched_barrier(0);
        __builtin_amdgcn_s_barrier();
    }

    // gate tile -> LDS [64][68] f32 (overlays staging; drained)
    float* gtile = (float*)lds;
    const int l16 = lane & 15, g4 = (lane >> 4) * 4;
#pragma unroll
    for (int i = 0; i < 2; ++i)
#pragma unroll
        for (int jj = 0; jj < 2; ++jj)
#pragma unroll
            for (int r = 0; r < 4; ++r)
                gtile[(wm * 32 + i * 16 + g4 + r) * 68 + wn * 32 + jj * 16 + l16] = acc[i][jj][r];
    __syncthreads();

    int m = tid >> 2;
    int hcb = (tid & 3) * 4;
    int nh0 = cblk * 16;
#pragma unroll
    for (int e = 0; e < 4; ++e) {
        int hc = hcb + e;
        float gv[4];
#pragma unroll
        for (int q = 0; q < 4; ++q) {
            int bidx = q * H + nh0 + hc;
            gv[q] = gtile[m * 68 + hc * 4 + q] + bias1[bidx] + bias2[bidx];
        }
        size_t idx = (size_t)(m0 + m) * H + nh0 + hc;
        float cp = cbuf[idx];
        float si = 1.f / (1.f + __expf(-gv[0]));
        float sf = 1.f / (1.f + __expf(-gv[1]));
        float so = 1.f / (1.f + __expf(-gv[3]));
        float c = sf * cp + si * tanhf(gv[2]);
        float hn = so * tanhf(c);
        cbuf[idx] = c;
        hf[idx] = hn;
        h16[idx] = f16of(hn);
    }
}

// ---------------------------------------------------------------------------
// Batched score MFMA (bf16 3-term): scores[t*R+l*64+b][s] = gamma . ctx.
__global__ __launch_bounds__(256) void k_smfma(
    const ushort_t* __restrict__ gah, const ushort_t* __restrict__ gal,
    const ushort_t* __restrict__ cxh, const ushort_t* __restrict__ cxl,
    float* __restrict__ scores) {
    __shared__ __align__(16) unsigned char lds[65536];
    const int tid = threadIdx.x;
    const int lane = tid & 63;
    const int wv = tid >> 6;
    const int wm = wv & 1, wn = wv >> 1;
    const int b = blockIdx.z;
    const int m0 = blockIdx.y * 64;
    const int colbase = blockIdx.x * 64;
    const int NT = 16;

    f32x4_v zero = {0.f, 0.f, 0.f, 0.f};
    f32x4_v acc[2][2] = {{zero, zero}, {zero, zero}};
    const int xorc = ((lane & 7) * 16) ^ ((lane >> 3) << 4);
    const int rsub = lane >> 3;

    auto stage = [&](int t, int buf) {
        unsigned char* dstA = lds + buf * 16384;
        unsigned char* dstB = lds + 32768 + buf * 16384;
        int k0 = t << 6;
#pragma unroll
        for (int cc = 0; cc < 4; ++cc) {
            int c = wv * 4 + cc;
            int p = c >> 3, s = c & 7;
            int rr = m0 + 8 * s + rsub;
            int tt = rr >> 2; if (tt > 30) tt = 30;
            size_t row = (size_t)tt * R + (rr & 3) * 64 + b;
            const ushort_t* plane = p ? gal : gah;
            gl_lds16((const unsigned char*)(plane + row * H + k0) + xorc,
                     dstA + c * 1024);
        }
#pragma unroll
        for (int cc = 0; cc < 4; ++cc) {
            int c = wv * 4 + cc;
            int p = c >> 3, s = c & 7;
            int rr = colbase + 8 * s + rsub;
            const ushort_t* plane = p ? cxl : cxh;
            gl_lds16((const unsigned char*)(plane + ((size_t)b * SRC + rr) * H + k0) + xorc,
                     dstB + c * 1024);
        }
    };
    auto compute = [&](int buf) {
        const unsigned char* Ab = lds + buf * 16384;
        const unsigned char* Bb = lds + 32768 + buf * 16384;
#pragma unroll
        for (int kf = 0; kf < 2; ++kf) {
            int colA = (kf * 64 + ((lane >> 4) * 16)) ^ ((lane & 7) << 4);
            bf16x8_v ah[2], al[2], bh[2], bl[2];
#pragma unroll
            for (int i = 0; i < 2; ++i) {
                int rowm = (wm * 2 + i) * 16 + (lane & 15);
                ah[i] = *(const bf16x8_v*)(Ab + rowm * 128 + colA);
                al[i] = *(const bf16x8_v*)(Ab + 8192 + rowm * 128 + colA);
                int rj = (wn * 2 + i) * 16 + (lane & 15);
                bh[i] = *(const bf16x8_v*)(Bb + rj * 128 + colA);
                bl[i] = *(const bf16x8_v*)(Bb + 8192 + rj * 128 + colA);
            }
            __builtin_amdgcn_s_setprio(1);
#pragma unroll
            for (int i = 0; i < 2; ++i)
#pragma unroll
                for (int j = 0; j < 2; ++j) {
                    acc[i][j] = __builtin_amdgcn_mfma_f32_16x16x32_bf16(al[i], bh[j], acc[i][j], 0, 0, 0);
                    acc[i][j] = __builtin_amdgcn_mfma_f32_16x16x32_bf16(ah[i], bl[j], acc[i][j], 0, 0, 0);
                    acc[i][j] = __builtin_amdgcn_mfma_f32_16x16x32_bf16(ah[i], bh[j], acc[i][j], 0, 0, 0);
                }
            __builtin_amdgcn_s_setprio(0);
        }
    };

    stage(0, 0);
    int cur = 0;
    for (int tt = 0; tt < NT; ++tt) {
        if (tt + 1 < NT) {
            stage(tt + 1, cur ^ 1);
            asm volatile("s_waitcnt vmcnt(8)" ::: "memory");
        } else {
            asm volatile("s_waitcnt vmcnt(0)" ::: "memory");
        }
        __builtin_amdgcn_s_barrier();
        __builtin_amdgcn_sched_barrier(0);
        compute(cur);
        __builtin_amdgcn_sched_barrier(0);
        __builtin_amdgcn_s_barrier();
        cur ^= 1;
    }

    const int l16 = lane & 15, g4 = (lane >> 4) * 4;
#pragma unroll
    for (int i = 0; i < 2; ++i) {
#pragma unroll
        for (int jj = 0; jj < 2; ++jj) {
#pragma unroll
            for (int r = 0; r < 4; ++r) {
                int m = m0 + wm * 32 + i * 16 + g4 + r;
                int t = m >> 2;
                if (t < 31) {
                    size_t row = (size_t)t * R + (m & 3) * 64 + b;
                    int n = colbase + wn * 32 + jj * 16 + l16;
                    scores[row * SRC + n] = acc[i][jj][r];
                }
            }
        }
    }
}

// ---------------------------------------------------------------------------
// Softmax -> fp16 weights.
__global__ __launch_bounds__(256) void k_smax(const float* __restrict__ scores,
                                              ushort_t* __restrict__ w16) {
    int t = blockIdx.x, b = blockIdx.y;
    int l = threadIdx.x >> 6, lane = threadIdx.x & 63;
    size_t row = (size_t)t * R + l * 64 + b;
    const float* sr = scores + row * SRC;
    float v0 = sr[lane];
    float v1 = sr[lane + 64];
    float v2 = sr[lane + 128];
    float v3 = sr[lane + 192];
    float m = fmaxf(fmaxf(v0, v1), fmaxf(v2, v3));
#pragma unroll
    for (int off = 32; off >= 1; off >>= 1) m = fmaxf(m, __shfl_xor(m, off));
    float e0 = expf(v0 - m), e1 = expf(v1 - m), e2 = expf(v2 - m), e3 = expf(v3 - m);
    float sum = e0 + e1 + e2 + e3;
#pragma unroll
    for (int off = 32; off >= 1; off >>= 1) sum += __shfl_xor(sum, off);
    float inv = 1.f / sum;
    ushort_t* wr = w16 + row * SRC;
    wr[lane] = f16of(e0 * inv);
    wr[lane + 64] = f16of(e1 * inv);
    wr[lane + 128] = f16of(e2 * inv);
    wr[lane + 192] = f16of(e3 * inv);
}

// ---------------------------------------------------------------------------
// MFMA ct: ct16[row][h] = sum_s w16[row][s] * ctxT[b][h][s].
// grid (16 hblk, 2 mblk, B), 256 thr, K=256 (NT=4), fp16 single x single.
__global__ __launch_bounds__(256) void k_ctmm(
    const ushort_t* __restrict__ w16, const ushort_t* __restrict__ ctxT,
    ushort_t* __restrict__ ct16) {
    __shared__ __align__(16) unsigned char lds[32768];
    const int tid = threadIdx.x;
    const int lane = tid & 63;
    const int wv = tid >> 6;
    const int wm = wv & 1, wn = wv >> 1;
    const int b = blockIdx.z;
    const int m0 = blockIdx.y * 64;
    const int colbase = blockIdx.x * 64;
    const int NT = 4;

    f32x4_v zero = {0.f, 0.f, 0.f, 0.f};
    f32x4_v acc[2][2] = {{zero, zero}, {zero, zero}};
    const int xorc = ((lane & 7) * 16) ^ ((lane >> 3) << 4);
    const int rsub = lane >> 3;

    auto stage = [&](int t, int buf) {
        unsigned char* base = lds + buf * 16384;
        int k0 = t << 6;
#pragma unroll
        for (int cc = 0; cc < 4; ++cc) {
            int c = wv * 4 + cc;           // 0..15
            if (c < 8) {                   // A = w16, rows mapped like smfma
                int rr = m0 + 8 * c + rsub;
                int tt = rr >> 2; if (tt > 30) tt = 30;
                size_t row = (size_t)tt * R + (rr & 3) * 64 + b;
                gl_lds16((const unsigned char*)(w16 + row * SRC + k0) + xorc,
                         base + c * 1024);
            } else {                       // B = ctxT rows (h)
                int hr = colbase + 8 * (c - 8) + rsub;
                gl_lds16((const unsigned char*)(ctxT + ((size_t)b * H + hr) * SRC + k0) + xorc,
                         base + 8192 + (c - 8) * 1024);
            }
        }
    };
    auto compute = [&](int buf) {
        const unsigned char* Ab = lds + buf * 16384;
        const unsigned char* Bb = Ab + 8192;
#pragma unroll
        for (int kf = 0; kf < 2; ++kf) {
            int colA = (kf * 64 + ((lane >> 4) * 16)) ^ ((lane & 7) << 4);
            f16x8_v a[2], bv[2];
#pragma unroll
            for (int i = 0; i < 2; ++i) {
                int rowm = (wm * 2 + i) * 16 + (lane & 15);
                a[i] = *(const f16x8_v*)(Ab + rowm * 128 + colA);
                int rj = (wn * 2 + i) * 16 + (lane & 15);
                bv[i] = *(const f16x8_v*)(Bb + rj * 128 + colA);
            }
            __builtin_amdgcn_s_setprio(1);
#pragma unroll
            for (int i = 0; i < 2; ++i)
#pragma unroll
                for (int j = 0; j < 2; ++j)
                    acc[i][j] = __builtin_amdgcn_mfma_f32_16x16x32_f16(a[i], bv[j], acc[i][j], 0, 0, 0);
            __builtin_amdgcn_s_setprio(0);
        }
    };

    stage(0, 0);
    int cur = 0;
    for (int tt = 0; tt < NT; ++tt) {
        if (tt + 1 < NT) {
            stage(tt + 1, cur ^ 1);
            asm volatile("s_waitcnt vmcnt(4)" ::: "memory");
        } else {
            asm volatile("s_waitcnt vmcnt(0)" ::: "memory");
        }
        __builtin_amdgcn_s_barrier();
        __builtin_amdgcn_sched_barrier(0);
        compute(cur);
        __builtin_amdgcn_sched_barrier(0);
        __builtin_amdgcn_s_barrier();
        cur ^= 1;
    }

    const int l16 = lane & 15, g4 = (lane >> 4) * 4;
#pragma unroll
    for (int i = 0; i < 2; ++i) {
#pragma unroll
        for (int r = 0; r < 4; ++r) {
            int m = m0 + wm * 32 + i * 16 + g4 + r;
            int t = m >> 2;
            if (t < 31) {
                size_t row = (size_t)t * R + (m & 3) * 64 + b;
#pragma unroll
                for (int jj = 0; jj < 2; ++jj) {
                    int n = colbase + wn * 32 + jj * 16 + l16;
                    ct16[row * H + n] = f16of(acc[i][jj][r]);
                }
            }
        }
    }
}

// ---------------------------------------------------------------------------
__global__ __launch_bounds__(256) void k_init_split(const float* __restrict__ h0f,
                                                    const float* __restrict__ c0f,
                                                    float* __restrict__ h1f,
                                                    float* __restrict__ c1f,
                                                    ushort_t* __restrict__ h0_16,
                                                    ushort_t* __restrict__ h1i_16) {
    int idx = blockIdx.x * 256 + threadIdx.x;
    float h = h0f[idx], c = c0f[idx];
    h1f[idx] = h; c1f[idx] = c;
    ushort_t hv = f16of(h);
    h0_16[idx] = hv;
    h1i_16[idx] = hv;
}

// ---------------------------------------------------------------------------
extern "C" void kernel_launch(void* const* d_in, const int* in_sizes, int n_in,
                              void* d_out, int out_size, void* d_ws, size_t ws_size,
                              hipStream_t stream) {
    const int*   inputs     = (const int*)d_in[0];
    const int*   input_lens = (const int*)d_in[1];
    const float* contexts   = (const float*)d_in[2];
    const float* emb_W      = (const float*)d_in[3];
    const float* W_ih0      = (const float*)d_in[4];
    const float* W_hh0      = (const float*)d_in[5];
    const float* b_ih0      = (const float*)d_in[6];
    const float* b_hh0      = (const float*)d_in[7];
    const float* W_ih1      = (const float*)d_in[8];
    const float* W_hh1      = (const float*)d_in[9];
    const float* b_ih1      = (const float*)d_in[10];
    const float* b_hh1      = (const float*)d_in[11];
    const float* att_in_W   = (const float*)d_in[12];
    const float* att_in_b   = (const float*)d_in[13];
    const float* att_out_W  = (const float*)d_in[14];
    const float* att_out_b  = (const float*)d_in[15];
    const float* isl_in_W   = (const float*)d_in[16];
    const float* isl_in_b   = (const float*)d_in[17];
    const float* isl_out_W  = (const float*)d_in[18];
    const float* isl_out_b  = (const float*)d_in[19];

    float* out = (float*)d_out;

    // workspace carve (256B-aligned)
    char* p = (char*)d_ws;
    auto alloc = [&](size_t bytes) { char* r = p; p += (bytes + 255) & ~(size_t)255; return r; };
    ushort_t* xs16 = (ushort_t*)alloc((size_t)T * R * E * 2);     // fp16 x
    ushort_t* h016[2];
    h016[0] = (ushort_t*)alloc((size_t)R * H * 2);
    h016[1] = (ushort_t*)alloc((size_t)R * H * 2);
    ushort_t* h1i16 = (ushort_t*)alloc((size_t)R * H * 2);
    ushort_t* h116all = (ushort_t*)alloc((size_t)T * R * H * 2);  // fp16 h1 per t
    ushort_t* gamh = (ushort_t*)alloc((size_t)T * R * H * 2);     // gamma bf16 pair
    ushort_t* gaml = (ushort_t*)alloc((size_t)T * R * H * 2);
    ushort_t* pehi = (ushort_t*)alloc((size_t)R * E * 2);
    ushort_t* pelo = (ushort_t*)alloc((size_t)R * E * 2);
    ushort_t* cmhi = (ushort_t*)alloc((size_t)B * H * 2);
    ushort_t* cmlo = (ushort_t*)alloc((size_t)B * H * 2);
    // gate weight panels: fp16 single tiled (8KB/tile)
    unsigned char* wg0p = (unsigned char*)alloc((size_t)64 * 24 * 8192);
    unsigned char* wg1p = (unsigned char*)alloc((size_t)64 * 32 * 8192);
    // fp16 hi/lo panels: att_in (gamma), att_out
    unsigned char* wgip = (unsigned char*)alloc((size_t)16 * 16 * 16384);
    unsigned char* wotp = (unsigned char*)alloc((size_t)16 * 32 * 16384);
    // bf16 panels for init
    unsigned char* wiip = (unsigned char*)alloc((size_t)16 * 24 * 16384);
    unsigned char* wiop = (unsigned char*)alloc((size_t)16 * 24 * 16384);
    // ctx planes: bf16 pair (score pass) + fp16 transposed (ct pass)
    ushort_t* cxh = (ushort_t*)alloc((size_t)B * SRC * H * 2);
    ushort_t* cxl = (ushort_t*)alloc((size_t)B * SRC * H * 2);
    ushort_t* ctxT16 = (ushort_t*)alloc((size_t)B * SRC * H * 2);
    float* h0f = (float*)alloc((size_t)R * H * 4);
    float* h1f = (float*)alloc((size_t)R * H * 4);
    float* c0f = (float*)alloc((size_t)R * H * 4);
    float* c1f = (float*)alloc((size_t)R * H * 4);
    // post buffers
    float* scores = (float*)alloc((size_t)T * R * SRC * 4);
    ushort_t* w16 = (ushort_t*)alloc((size_t)T * R * SRC * 2);
    ushort_t* ct16 = (ushort_t*)alloc((size_t)T * R * H * 2);

    // ---- setup ----
    k_embed<<<L4 * T * B, 128, 0, stream>>>(inputs, emb_W, xs16);
    k_pe<<<R, 128, 0, stream>>>(inputs, input_lens, emb_W, pehi, pelo);
    k_cm<<<B, 256, 0, stream>>>(contexts, cmhi, cmlo);
    k_wtile16s<<<dim3(64, 24), 256, 0, stream>>>(W_ih0, 512, 512, W_hh0, 1024, 1024, wg0p);
    k_wtile16s<<<dim3(64, 32), 256, 0, stream>>>(W_ih1, 1024, 1024, W_hh1, 1024, 1024, wg1p);
    k_wtile16<<<dim3(16, 16), 256, 0, stream>>>(att_in_W, 1024, 1024, nullptr, 0, 0, 0, wgip);
    k_wtile16<<<dim3(16, 32), 256, 0, stream>>>(att_out_W, 2048, 2048, nullptr, 0, 0, 0, wotp);
    k_wtile<<<dim3(16, 24), 256, 0, stream>>>(isl_in_W, 1536, 0, 1536, nullptr, 0, 0, 0, 0, wiip);
    k_wtile<<<dim3(16, 24), 256, 0, stream>>>(isl_out_W, 1536, 1024, 512, isl_out_W, 1536, 0, 1024, 0, wiop);
    k_wsplit<<<B * SRC, 256, 0, stream>>>(contexts, 1024, 0, 1024, nullptr, 0, 0, 0, 0, cxh, cxl);
    k_ctxT<<<dim3(B, 16, 4), 256, 0, stream>>>(contexts, ctxT16);

    // init projections (bf16 path, unchanged)
    k_g2<<<dim3(16, 4), 256, 0, stream>>>(pehi, pelo, 512, cmhi, cmlo, 1024, 64,
                                          wiip, isl_in_b, nullptr, 0,
                                          h0f, 0, 64LL * H, (long long)H, 1,
                                          nullptr, nullptr);
    k_g2<<<dim3(16, 4), 256, 0, stream>>>(pehi, pelo, 512, cmhi, cmlo, 1024, 64,
                                          wiop, isl_out_b, nullptr, 0,
                                          c0f, 0, 64LL * H, (long long)H, 1,
                                          nullptr, nullptr);
    k_init_split<<<R * H / 256, 256, 0, stream>>>(h0f, c0f, h1f, c1f, h016[0], h1i16);

    // ---- recurrence: dual-job fp16-single launches, 4-deep prefetch ----
    int cur = 0;
    for (int L = 0; L <= T; ++L) {
        bool has0 = (L < T), has1 = (L > 0);
        GateJob g0 = {}, g1 = {};
        if (has0) {
            g0.A1 = xs16 + (size_t)L * R * E;
            g0.A2 = h016[cur];
            g0.Bp = wg0p;
            g0.bias1 = b_ih0;  g0.bias2 = b_hh0;
            g0.cbuf = c0f;  g0.hf = h0f;
            g0.h16 = h016[cur ^ 1];
            g0.K1 = E;  g0.K2 = H;
        }
        if (has1) {
            g1.A1 = h016[cur];
            g1.A2 = (L == 1) ? h1i16 : h116all + (size_t)(L - 2) * R * H;
            g1.Bp = wg1p;
            g1.bias1 = b_ih1;  g1.bias2 = b_hh1;
            g1.cbuf = c1f;  g1.hf = h1f;
            g1.h16 = h116all + (size_t)(L - 1) * R * H;
            g1.K1 = H;  g1.K2 = H;
        }
        if (has0 && has1)
            k_gatepair<<<dim3(64, 8), 256, 0, stream>>>(g0, g1);
        else if (has0)
            k_gatepair<<<dim3(64, 4), 256, 0, stream>>>(g0, g0);
        else
            k_gatepair<<<dim3(64, 4), 256, 0, stream>>>(g1, g1);
        if (has0) cur ^= 1;
    }

    // ---- batched attention + output over all t ----
    // gamma_all = h1_all @ att_in_W^T + b  -> bf16 pair planes (mode 2)
    k_g2h<<<dim3(16, 62), 512, 0, stream>>>(h116all, 1024, h116all, 0,
                                            wgip, att_in_b, 2,
                                            nullptr, 256LL * H, 64LL * H, (long long)H,
                                            gamh, gaml);
    k_smfma<<<dim3(4, 2, B), 256, 0, stream>>>(gamh, gaml, cxh, cxl, scores);
    k_smax<<<dim3(T, B), 256, 0, stream>>>(scores, w16);
    k_ctmm<<<dim3(16, 2, B), 256, 0, stream>>>(w16, ctxT16, ct16);
    // out[t,l,b,:] = tanh([ct|h1] @ att_out_W^T + b)  (fp16 path)
    k_g2h<<<dim3(16, 62), 512, 0, stream>>>(ct16, 1024, h116all, 1024,
                                            wotp, att_out_b, 0,
                                            out, (long long)B * H,
                                            (long long)T * B * H, (long long)H,
                                            nullptr, nullptr);

    // ---- finals ----
    size_t OUTS = (size_t)L4 * T * B * H;
    size_t seg = (size_t)B * H;
    hipMemcpyAsync(out + OUTS,           h0f + 192 * H, seg * 4, hipMemcpyDeviceToDevice, stream);
    hipMemcpyAsync(out + OUTS + seg,     h1f + 192 * H, seg * 4, hipMemcpyDeviceToDevice, stream);
    hipMemcpyAsync(out + OUTS + 2 * seg, c0f + 192 * H, seg * 4, hipMemcpyDeviceToDevice, stream);
    hipMemcpyAsync(out + OUTS + 3 * seg, c1f + 192 * H, seg * 4, hipMemcpyDeviceToDevice, stream);
}